// Round 1
// baseline (4253.311 us; speedup 1.0000x reference)
//
#include <hip/hip_runtime.h>
#include <hip/hip_bf16.h>

#define BB 8
#define DD 64
#define NNODE 1024
#define LLL 12
#define EE 128
#define NEGV -9.0e15f

typedef __hip_bfloat16 bf16;

// ---------- xl[b,d,v] = sum_l x[b,d,v,l] ----------
__global__ void k_xl(const float* __restrict__ x, float* __restrict__ xl) {
    int i = blockIdx.x * 256 + threadIdx.x;            // 0 .. B*D*N-1
    const float4* p = reinterpret_cast<const float4*>(x + (size_t)i * 12);
    float4 a = p[0], b = p[1], c = p[2];
    xl[i] = ((a.x + a.y) + (a.z + a.w)) + ((b.x + b.y) + (b.z + b.w)) +
            ((c.x + c.y) + (c.z + c.w));
}

// ---------- keys/query for head h ----------
// keys[h,b,e,n] = sum_{d,l} (x[b,d,n,l]+nv1[n,d]) * kw[h,e,d,l] + kb[h,e]
__global__ __launch_bounds__(256) void k_kq(
    const float* __restrict__ x, const float* __restrict__ nv1, const float* __restrict__ nv2,
    const float* __restrict__ kw, const float* __restrict__ kb,
    const float* __restrict__ qw, const float* __restrict__ qb,
    float* __restrict__ keys, float* __restrict__ query, int h) {
    __shared__ float ki[8][772];
    __shared__ float qi[8][772];
    int b = blockIdx.y, n0 = blockIdx.x * 8, t = threadIdx.x;
    for (int m = t; m < 8 * 768; m += 256) {
        int j = m / 768, r = m - j * 768;
        int d = r / 12, l = r - d * 12;
        int n = n0 + j;
        float v = x[(((size_t)b * DD + d) * NNODE + n) * LLL + l];
        ki[j][r] = v + nv1[(size_t)n * DD + d];
        qi[j][r] = v + nv2[(size_t)d * NNODE + n];
    }
    __syncthreads();
    int j0 = t & 7, e0 = t >> 3;     // e0 in 0..31, j0 in 0..7
    for (int ee = 0; ee < 4; ee++) {
        int e = e0 + ee * 32;
        const float* kwp = kw + ((size_t)h * EE + e) * 768;
        const float* qwp = qw + ((size_t)h * EE + e) * 768;
        float ka = 0.f, qa = 0.f;
#pragma unroll 4
        for (int k = 0; k < 768; k++) {
            ka += kwp[k] * ki[j0][k];
            qa += qwp[k] * qi[j0][k];
        }
        size_t o = (((size_t)h * BB + b) * EE + e) * NNODE + n0 + j0;
        keys[o]  = ka + kb[h * EE + e];
        query[o] = qa + qb[h * EE + e];
    }
}

// ---------- raw scores (per head): sc[b,v,w] = relu(sum_e K[b,e,v]*Q[b,e,w]) ----------
__global__ __launch_bounds__(256) void k_score(
    const float* __restrict__ keys, const float* __restrict__ query,
    float* __restrict__ sc, int h) {
    __shared__ float Kt[32][68];
    __shared__ float Qt[32][68];
    int b = blockIdx.z, v0 = blockIdx.x * 64, w0 = blockIdx.y * 64, t = threadIdx.x;
    const float* Kp = keys  + ((size_t)h * BB + b) * EE * NNODE;
    const float* Qp = query + ((size_t)h * BB + b) * EE * NNODE;
    float acc[4][4] = {};
    int wq = t & 15, vg = t >> 4;    // w = w0+wq*4+j ; v = v0+vg+16*i
    for (int ec = 0; ec < EE; ec += 32) {
        for (int idx = t; idx < 2048; idx += 256) {
            int kk = idx >> 6, i = idx & 63;
            Kt[kk][i] = Kp[(size_t)(ec + kk) * NNODE + v0 + i];
            Qt[kk][i] = Qp[(size_t)(ec + kk) * NNODE + w0 + i];
        }
        __syncthreads();
#pragma unroll 8
        for (int kk = 0; kk < 32; kk++) {
            float4 q4 = *reinterpret_cast<const float4*>(&Qt[kk][wq * 4]);
#pragma unroll
            for (int i = 0; i < 4; i++) {
                float kv = Kt[kk][vg + 16 * i];
                acc[i][0] += kv * q4.x; acc[i][1] += kv * q4.y;
                acc[i][2] += kv * q4.z; acc[i][3] += kv * q4.w;
            }
        }
        __syncthreads();
    }
#pragma unroll
    for (int i = 0; i < 4; i++) {
        float4 o;
        o.x = fmaxf(acc[i][0], 0.f); o.y = fmaxf(acc[i][1], 0.f);
        o.z = fmaxf(acc[i][2], 0.f); o.w = fmaxf(acc[i][3], 0.f);
        *reinterpret_cast<float4*>(
            &sc[((size_t)b * NNODE + v0 + vg + 16 * i) * NNODE + w0 + wq * 4]) = o;
    }
}

// ---------- column softmax stats over v (axis=1), masked by a>0 ----------
__global__ __launch_bounds__(256) void k_colstat(
    const float* __restrict__ sc, const float* __restrict__ a,
    float* __restrict__ cm, float* __restrict__ cs) {
    int gw = blockIdx.x * 32;                 // b*N + w0
    int b = gw >> 10, w0 = gw & 1023;
    int t = threadIdx.x;
    int wl = t & 31, vq = t >> 5;             // 32 w x 8 v-strides
    int w = w0 + wl;
    float m = -INFINITY, ssum = 0.f;
    for (int v = vq; v < NNODE; v += 8) {
        float e  = sc[((size_t)b * NNODE + v) * NNODE + w];
        float av = a[(size_t)v * NNODE + w];
        float xx = av > 0.f ? e : NEGV;
        if (xx > m) { ssum = ssum * __expf(m - xx) + 1.f; m = xx; }
        else if (xx > NEGV || m == NEGV) ssum += __expf(xx - m);
        // else: masked & m finite -> exp underflows to exactly 0
    }
    __shared__ float sm[256], ss[256];
    sm[t] = m; ss[t] = ssum;
    __syncthreads();
    for (int off = 128; off >= 32; off >>= 1) {
        if (t < off) {
            float m1 = sm[t], s1 = ss[t], m2 = sm[t + off], s2 = ss[t + off];
            float mm = fmaxf(m1, m2);
            sm[t] = mm;
            ss[t] = s1 * __expf(m1 - mm) + s2 * __expf(m2 - mm);
        }
        __syncthreads();
    }
    if (t < 32) { cm[gw + t] = sm[t]; cs[gw + t] = ss[t]; }
}

// ---------- att (bf16) = exp(sc - m)/s where masked -> 0 ----------
__global__ void k_attwrite(const float* __restrict__ sc, const float* __restrict__ a,
                           const float* __restrict__ cm, const float* __restrict__ cs,
                           bf16* __restrict__ att) {
    size_t i = (size_t)blockIdx.x * 256 + threadIdx.x;   // (b,v,w)
    int w = (int)(i & 1023);
    size_t bv = i >> 10;
    int v = (int)(bv & 1023);
    int b = (int)(bv >> 10);
    float av = a[(size_t)v * NNODE + w];
    int bw = (b << 10) | w;
    float r = av > 0.f ? __expf(sc[i] - cm[bw]) / cs[bw] : 0.f;
    att[i] = __float2bfloat16(r);
}

// ---------- row sums of M (for feat means) ----------
template <bool MATT>
__global__ void k_rowsum(const void* __restrict__ Mv, float* __restrict__ r) {
    int row = blockIdx.x * 4 + (threadIdx.x >> 6);
    int lane = threadIdx.x & 63;
    float s = 0.f;
    if (MATT) {
        const bf16* p = (const bf16*)Mv + (size_t)row * NNODE;
        for (int k = lane; k < NNODE; k += 64) s += __bfloat162float(p[k]);
    } else {
        const float* p = (const float*)Mv + (size_t)row * NNODE;
        for (int k = lane; k < NNODE; k += 64) s += p[k];
    }
#pragma unroll
    for (int off = 32; off > 0; off >>= 1) s += __shfl_down(s, off);
    if (lane == 0) r[row] = s;
}

// ---------- t1[b,d,w] = sum_v xl[b,d,v] * M[v,w] (L-collapsed propagation) ----------
template <bool MATT>
__global__ __launch_bounds__(256) void k_prop1(
    const float* __restrict__ xl, const void* __restrict__ Mv, float* __restrict__ t1) {
    __shared__ float Mt[32][68];
    __shared__ float Xt[64][33];
    int b = blockIdx.y, w0 = blockIdx.x * 64, t = threadIdx.x;
    const bf16* Ma = (const bf16*)Mv + (MATT ? (size_t)b * NNODE * NNODE : 0);
    const float* Mf = (const float*)Mv;
    float acc[4][4] = {};
    int wq = t & 15, dg = t >> 4;   // w = w0+wq+16j ; d = dg*4+di
    for (int vc = 0; vc < NNODE; vc += 32) {
        for (int idx = t; idx < 2048; idx += 256) {
            int kk = idx >> 6, i = idx & 63;
            Mt[kk][i] = MATT ? __bfloat162float(Ma[(size_t)(vc + kk) * NNODE + w0 + i])
                             : Mf[(size_t)(vc + kk) * NNODE + w0 + i];
        }
        for (int idx = t; idx < 2048; idx += 256) {
            int dd = idx >> 5, kk = idx & 31;
            Xt[dd][kk] = xl[((size_t)b * DD + dd) * NNODE + vc + kk];
        }
        __syncthreads();
#pragma unroll 4
        for (int kk = 0; kk < 32; kk++) {
            float xv[4];
#pragma unroll
            for (int di = 0; di < 4; di++) xv[di] = Xt[dg * 4 + di][kk];
#pragma unroll
            for (int j = 0; j < 4; j++) {
                float mv = Mt[kk][wq + 16 * j];
#pragma unroll
                for (int di = 0; di < 4; di++) acc[di][j] += xv[di] * mv;
            }
        }
        __syncthreads();
    }
#pragma unroll
    for (int di = 0; di < 4; di++)
#pragma unroll
        for (int j = 0; j < 4; j++)
            t1[((size_t)b * DD + dg * 4 + di) * NNODE + w0 + wq + 16 * j] = acc[di][j];
}

// ---------- feat[b,iidx,d] = (1/(N*L)) * sum_v t[b,d,v] * r[v] ----------
template <int RMODE>   // 0: r per-b, 1: r shared, 2: r == 1
__global__ void k_feat(const float* __restrict__ t, const float* __restrict__ r,
                       float* __restrict__ feats, int iidx) {
    int bd = blockIdx.x;
    int b = bd >> 6, d = bd & 63;
    int tid = threadIdx.x;
    const float* tp = t + (size_t)bd * NNODE;
    const float* rp = (RMODE == 0) ? r + (size_t)b * NNODE : r;
    float s = 0.f;
    for (int v = tid; v < NNODE; v += 256)
        s += tp[v] * (RMODE == 2 ? 1.f : rp[v]);
    __shared__ float red[256];
    red[tid] = s; __syncthreads();
    for (int off = 128; off > 0; off >>= 1) {
        if (tid < off) red[tid] += red[tid + off];
        __syncthreads();
    }
    if (tid == 0)
        feats[(size_t)b * 832 + iidx * 64 + d] = red[0] * (1.f / (NNODE * (float)LLL));
}

// ---------- gate: logits -> softmax over 13 ----------
__global__ void k_gate(const float* __restrict__ feats, const float* __restrict__ aw,
                       const float* __restrict__ ab, float* __restrict__ gate) {
    int b = blockIdx.x, t = threadIdx.x;
    __shared__ float lg[13];
    if (t < 13) {
        float s = ab[t];
        const float* f = feats + (size_t)b * 832;
        const float* w = aw + (size_t)t * 832;
        for (int k = 0; k < 832; k++) s += f[k] * w[k];
        lg[t] = s;
    }
    __syncthreads();
    if (t == 0) {
        float m = lg[0];
        for (int j = 1; j < 13; j++) m = fmaxf(m, lg[j]);
        float ss = 0.f;
        for (int j = 0; j < 13; j++) ss += __expf(lg[j] - m);
        float inv = 1.f / ss;
        for (int j = 0; j < 13; j++) gate[b * 13 + j] = __expf(lg[j] - m) * inv;
    }
}

// ---------- h init: h = gate[b,0] * x ----------
__global__ void k_hinit(const float* __restrict__ x, const float* __restrict__ gate,
                        float* __restrict__ h) {
    size_t i4 = (size_t)blockIdx.x * 256 + threadIdx.x;
    int b = (int)(i4 / 196608);           // (B*D*N*L/4)/B
    float g = gate[b * 13];
    float4 v = reinterpret_cast<const float4*>(x)[i4];
    float4 o = {v.x * g, v.y * g, v.z * g, v.w * g};
    reinterpret_cast<float4*>(h)[i4] = o;
}

// ---------- main propagation: Y[b,d,w,l] = sum_v X[b,d,v,l]*M[v,w]; h += gate*Y ----------
template <bool MATT, bool WRITEY, bool ACCH>
__global__ __launch_bounds__(256) void k_prop12(
    const float* __restrict__ X, const void* __restrict__ Mv,
    float* __restrict__ Y, float* __restrict__ h,
    const float* __restrict__ gate, int gidx) {
    __shared__ float Mt[32][68];
    __shared__ float Xt[16 * 388];
    int b = blockIdx.z, w0 = blockIdx.x * 64, d0 = blockIdx.y * 16, t = threadIdx.x;
    const bf16* Ma = (const bf16*)Mv + (MATT ? (size_t)b * NNODE * NNODE : 0);
    const float* Mf = (const float*)Mv;
    float acc[4][12];
#pragma unroll
    for (int i = 0; i < 4; i++)
#pragma unroll
        for (int l = 0; l < 12; l++) acc[i][l] = 0.f;
    int wq = t & 15, g = t >> 4;   // w = w0+wq+16*i ; d = d0+g
    for (int vc = 0; vc < NNODE; vc += 32) {
        for (int idx = t; idx < 2048; idx += 256) {
            int kk = idx >> 6, i = idx & 63;
            Mt[kk][i] = MATT ? __bfloat162float(Ma[(size_t)(vc + kk) * NNODE + w0 + i])
                             : Mf[(size_t)(vc + kk) * NNODE + w0 + i];
        }
        for (int id = t; id < 1536; id += 256) {
            int row = id / 3, q = id - row * 3;
            int dd = row >> 5, kk = row & 31;
            float4 xv = *reinterpret_cast<const float4*>(
                &X[(((size_t)b * DD + d0 + dd) * NNODE + vc + kk) * LLL + q * 4]);
            float* dst = &Xt[dd * 388 + kk * 12 + q * 4];
            dst[0] = xv.x; dst[1] = xv.y; dst[2] = xv.z; dst[3] = xv.w;
        }
        __syncthreads();
#pragma unroll 2
        for (int kk = 0; kk < 32; kk++) {
            float4 xa = *reinterpret_cast<const float4*>(&Xt[g * 388 + kk * 12]);
            float4 xb = *reinterpret_cast<const float4*>(&Xt[g * 388 + kk * 12 + 4]);
            float4 xc = *reinterpret_cast<const float4*>(&Xt[g * 388 + kk * 12 + 8]);
            float xv[12] = {xa.x, xa.y, xa.z, xa.w, xb.x, xb.y, xb.z, xb.w,
                            xc.x, xc.y, xc.z, xc.w};
#pragma unroll
            for (int i = 0; i < 4; i++) {
                float mv = Mt[kk][wq + 16 * i];
#pragma unroll
                for (int l = 0; l < 12; l++) acc[i][l] += mv * xv[l];
            }
        }
        __syncthreads();
    }
    float gs = 0.f;
    if (ACCH) gs = gate[b * 13 + gidx];
#pragma unroll
    for (int i = 0; i < 4; i++) {
        int w = w0 + wq + 16 * i;
        size_t base = (((size_t)b * DD + d0 + g) * NNODE + w) * LLL;
        if (WRITEY) {
#pragma unroll
            for (int qq = 0; qq < 3; qq++) {
                float4 o = {acc[i][qq * 4 + 0], acc[i][qq * 4 + 1],
                            acc[i][qq * 4 + 2], acc[i][qq * 4 + 3]};
                *reinterpret_cast<float4*>(&Y[base + qq * 4]) = o;
            }
        }
        if (ACCH) {
#pragma unroll
            for (int qq = 0; qq < 3; qq++) {
                float4 hv = *reinterpret_cast<float4*>(&h[base + qq * 4]);
                hv.x += gs * acc[i][qq * 4 + 0]; hv.y += gs * acc[i][qq * 4 + 1];
                hv.z += gs * acc[i][qq * 4 + 2]; hv.w += gs * acc[i][qq * 4 + 3];
                *reinterpret_cast<float4*>(&h[base + qq * 4]) = hv;
            }
        }
    }
}

// ---------- final projection, in place on h (=d_out) ----------
__global__ __launch_bounds__(256) void k_final(float* __restrict__ h,
                                               const float* __restrict__ fw,
                                               const float* __restrict__ fb) {
    int col = blockIdx.x * 256 + threadIdx.x;   // (b, n*12+l)
    int b = col / 12288, r = col - b * 12288;
    size_t base = (size_t)b * 786432 + r;
    float hreg[64];
#pragma unroll
    for (int d = 0; d < 64; d++) hreg[d] = h[base + (size_t)d * 12288];
#pragma unroll 4
    for (int o = 0; o < 64; o++) {
        float acc = fb[o];
#pragma unroll
        for (int d = 0; d < 64; d++) acc += fw[o * 64 + d] * hreg[d];
        h[base + (size_t)o * 12288] = acc;
    }
}

extern "C" void kernel_launch(void* const* d_in, const int* in_sizes, int n_in,
                              void* d_out, int out_size, void* d_ws, size_t ws_size,
                              hipStream_t stream) {
    const float* x   = (const float*)d_in[0];
    const float* sup = (const float*)d_in[1];
    const float* nv1 = (const float*)d_in[2];
    const float* nv2 = (const float*)d_in[3];
    const float* kw  = (const float*)d_in[4];
    const float* kb  = (const float*)d_in[5];
    const float* qw  = (const float*)d_in[6];
    const float* qb  = (const float*)d_in[7];
    const float* aw  = (const float*)d_in[8];
    const float* ab  = (const float*)d_in[9];
    const float* fw  = (const float*)d_in[10];
    const float* fb  = (const float*)d_in[11];
    float* hout = (float*)d_out;

    float* wsf = (float*)d_ws;
    size_t o = 0;
    float* xl    = wsf + o; o += 524288;        // B*D*N
    float* keys  = wsf + o; o += 2097152;       // 2*B*E*N
    float* query = wsf + o; o += 2097152;
    float* t1    = wsf + o; o += 524288;
    float* rr    = wsf + o; o += 8192;          // per-b rowsums
    float* ra    = wsf + o; o += 1024;          // shared rowsums (a)
    float* cm    = wsf + o; o += 8192;
    float* cs    = wsf + o; o += 8192;
    float* feats = wsf + o; o += 6656;
    float* gate  = wsf + o; o += 128;
    float* sc    = wsf + o; o += 8388608;       // raw scores; reused as P1 in pass B
    bf16*  att   = (bf16*)(wsf + o);            // 4 * B*N*N bf16
    size_t need = o * 4 + (size_t)4 * 8388608 * 2;
    if (ws_size < need) return;   // workspace too small — cannot run

    const size_t BNN = (size_t)BB * NNODE * NNODE;
    float* P1 = sc;

    k_xl<<<2048, 256, 0, stream>>>(x, xl);
    k_kq<<<dim3(128, 8), 256, 0, stream>>>(x, nv1, nv2, kw, kb, qw, qb, keys, query, 0);
    k_kq<<<dim3(128, 8), 256, 0, stream>>>(x, nv1, nv2, kw, kb, qw, qb, keys, query, 1);

    // attention matrices (scores once per head; mask per support inside softmax)
    for (int h = 0; h < 2; h++) {
        k_score<<<dim3(16, 16, 8), 256, 0, stream>>>(keys, query, sc, h);
        for (int s = 0; s < 2; s++) {
            const float* a = sup + (size_t)s * NNODE * NNODE;
            bf16* A = att + (size_t)(s * 2 + h) * BNN;
            k_colstat<<<256, 256, 0, stream>>>(sc, a, cm, cs);
            k_attwrite<<<32768, 256, 0, stream>>>(sc, a, cm, cs, A);
        }
    }

    // feats (L-collapsed exact means) and gate
    k_feat<2><<<512, 256, 0, stream>>>(xl, nullptr, feats, 0);
    for (int s = 0; s < 2; s++) {
        const float* a = sup + (size_t)s * NNODE * NNODE;
        k_rowsum<false><<<256, 256, 0, stream>>>(a, ra);
        k_prop1<false><<<dim3(16, 8), 256, 0, stream>>>(xl, a, t1);
        k_feat<1><<<512, 256, 0, stream>>>(xl, ra, feats, 1 + s * 6 + 0);
        k_feat<1><<<512, 256, 0, stream>>>(t1, ra, feats, 1 + s * 6 + 1);
        for (int hh = 0; hh < 2; hh++) {
            bf16* A = att + (size_t)(s * 2 + hh) * BNN;
            k_rowsum<true><<<2048, 256, 0, stream>>>(A, rr);
            k_prop1<true><<<dim3(16, 8), 256, 0, stream>>>(xl, A, t1);
            k_feat<0><<<512, 256, 0, stream>>>(xl, rr, feats, 1 + s * 6 + (hh + 1) * 2);
            k_feat<0><<<512, 256, 0, stream>>>(t1, rr, feats, 1 + s * 6 + (hh + 1) * 2 + 1);
        }
    }
    k_gate<<<8, 64, 0, stream>>>(feats, aw, ab, gate);

    // weighted accumulation of all 13 tensors into h (= d_out)
    k_hinit<<<6144, 256, 0, stream>>>(x, gate, hout);
    for (int s = 0; s < 2; s++) {
        const float* a = sup + (size_t)s * NNODE * NNODE;
        k_prop12<false, true, true><<<dim3(16, 4, 8), 256, 0, stream>>>(
            x, a, P1, hout, gate, 1 + s * 6 + 0);
        k_prop12<false, false, true><<<dim3(16, 4, 8), 256, 0, stream>>>(
            P1, a, nullptr, hout, gate, 1 + s * 6 + 1);
        for (int hh = 0; hh < 2; hh++) {
            bf16* A = att + (size_t)(s * 2 + hh) * BNN;
            k_prop12<true, true, true><<<dim3(16, 4, 8), 256, 0, stream>>>(
                x, A, P1, hout, gate, 1 + s * 6 + (hh + 1) * 2);
            k_prop12<true, false, true><<<dim3(16, 4, 8), 256, 0, stream>>>(
                P1, A, nullptr, hout, gate, 1 + s * 6 + (hh + 1) * 2 + 1);
        }
    }
    k_final<<<384, 256, 0, stream>>>(hout, fw, fb);
}

// Round 2
// 1317.149 us; speedup vs baseline: 3.2292x; 3.2292x over previous
//
#include <hip/hip_runtime.h>
#include <hip/hip_bf16.h>

#define BB 8
#define DD 64
#define NNODE 1024
#define LLL 12
#define EE 128
#define NEGV -9.0e15f

typedef _Float16 f16;
typedef _Float16 f16x8 __attribute__((ext_vector_type(8)));
typedef float f32x4 __attribute__((ext_vector_type(4)));

// ================= GEMM core helpers (128x128 tile, BK=64, 4 waves) =========
// LDS tiles: [128 rows][64 k] f16 = 16KB each, linear layout for global_load_lds,
// XOR-swizzled source addresses; ds_read applies the same XOR (involution).

__device__ __forceinline__ void stage_tile(const char* g, int ld, char* lds, int t) {
    int wid = t >> 6, lane = t & 63;
#pragma unroll
    for (int it = 0; it < 4; it++) {
        int cbase = it * 256 + wid * 64;          // wave-uniform chunk base
        int c = cbase + lane;
        int row = c >> 3, p = c & 7;
        int gch = p ^ (row & 7);                  // inverse swizzle on SOURCE
        const char* src = g + (size_t)row * ld + gch * 16;
        char* dst = lds + (size_t)cbase * 16;     // wave-uniform; lane*16 implicit
        __builtin_amdgcn_global_load_lds(
            (const __attribute__((address_space(1))) unsigned int*)src,
            (__attribute__((address_space(3))) unsigned int*)dst, 16, 0, 0);
    }
}

__device__ __forceinline__ void mma_tile(const char* As, const char* Bs, int t,
                                         f32x4 acc[4][4]) {
    int lane = t & 63, wid = t >> 6;
    int wr = (wid >> 1) * 64, wc = (wid & 1) * 64;
    int lrow = lane & 15, lk = lane >> 4;
#pragma unroll
    for (int kk = 0; kk < 2; kk++) {
        f16x8 af[4], bf[4];
#pragma unroll
        for (int m = 0; m < 4; m++) {
            int row = wr + m * 16 + lrow;
            int p = (kk * 4 + lk) ^ (row & 7);    // swizzled read
            af[m] = *(const f16x8*)(As + row * 128 + p * 16);
        }
#pragma unroll
        for (int n = 0; n < 4; n++) {
            int row = wc + n * 16 + lrow;
            int p = (kk * 4 + lk) ^ (row & 7);
            bf[n] = *(const f16x8*)(Bs + row * 128 + p * 16);
        }
#pragma unroll
        for (int m = 0; m < 4; m++)
#pragma unroll
            for (int n = 0; n < 4; n++)
                acc[m][n] = __builtin_amdgcn_mfma_f32_16x16x32_f16(
                    af[m], bf[n], acc[m][n], 0, 0, 0);
    }
}

__device__ __forceinline__ void zero_acc(f32x4 acc[4][4]) {
#pragma unroll
    for (int m = 0; m < 4; m++)
#pragma unroll
        for (int n = 0; n < 4; n++)
#pragma unroll
            for (int q = 0; q < 4; q++) acc[m][n][q] = 0.f;
}

// ================= prep kernels =============================================

// XT[b][(d,l)][v] f16 + xl[b,d,v] = sum_l x
__global__ void k_xt(const float* __restrict__ x, f16* __restrict__ XT,
                     float* __restrict__ xl) {
    int i = blockIdx.x * 256 + threadIdx.x;       // (b,d,v)
    int v = i & 1023, d = (i >> 10) & 63, b = i >> 16;
    const float4* p = reinterpret_cast<const float4*>(x + (size_t)i * 12);
    float4 a = p[0], c = p[1], e = p[2];
    float vv[12] = {a.x, a.y, a.z, a.w, c.x, c.y, c.z, c.w, e.x, e.y, e.z, e.w};
    float ssum = 0.f;
    size_t base = ((size_t)b * 768) * 1024 + v;
    int r0 = d * 12;
#pragma unroll
    for (int l = 0; l < 12; l++) {
        ssum += vv[l];
        XT[base + (size_t)(r0 + l) * 1024] = (f16)vv[l];
    }
    xl[i] = ssum;
}

// xT2[b][n][(d,l)] f16 via LDS transpose of 16d x 64n tiles
__global__ __launch_bounds__(256) void k_xt2(const float* __restrict__ x,
                                             f16* __restrict__ xT2) {
    __shared__ f16 Ls[64][208];
    int b = blockIdx.z, d0 = blockIdx.y * 16, n0 = blockIdx.x * 64, t = threadIdx.x;
    for (int f = t; f < 3072; f += 256) {
        int dd = f / 192, rem = f - dd * 192, j = rem / 3, q = rem - j * 3;
        float4 v = *reinterpret_cast<const float4*>(
            x + (((size_t)(b * 64 + d0 + dd) * 1024) + n0 + j) * 12 + q * 4);
        f16* dst = &Ls[j][dd * 12 + q * 4];
        dst[0] = (f16)v.x; dst[1] = (f16)v.y; dst[2] = (f16)v.z; dst[3] = (f16)v.w;
    }
    __syncthreads();
    for (int c = t; c < 1536; c += 256) {
        int j = c / 24, p = c - j * 24;
        *reinterpret_cast<f16x8*>(
            xT2 + ((size_t)(b * 1024) + n0 + j) * 768 + d0 * 12 + p * 8) =
            *reinterpret_cast<const f16x8*>(&Ls[j][p * 8]);
    }
}

// kwb[var][e][768] f16, kwl[var][e][d] = sum_l w
__global__ void k_wcvt(const float* __restrict__ kw, const float* __restrict__ qw,
                       float* __restrict__ kwl, f16* __restrict__ kwb) {
    int i = blockIdx.x * 256 + threadIdx.x;       // (var,e,d)
    int d = i & 63, e = (i >> 6) & 127, var = i >> 13;
    const float* src = (var < 2 ? kw + (size_t)var * 98304
                                : qw + (size_t)(var - 2) * 98304) +
                       ((size_t)e * 64 + d) * 12;
    f16* dst = kwb + ((size_t)var * 128 + e) * 768 + d * 12;
    float ssum = 0.f;
#pragma unroll
    for (int l = 0; l < 12; l++) {
        float v = src[l];
        ssum += v;
        dst[l] = (f16)v;
    }
    kwl[i] = ssum;
}

// tkq[var][n][e] = sum_d kwl[var][e][d]*nv + bias[var][e]
__global__ void k_tkq(const float* __restrict__ kwl, const float* __restrict__ nv1,
                      const float* __restrict__ nv2, const float* __restrict__ kb,
                      const float* __restrict__ qb, float* __restrict__ tkq) {
    int i = blockIdx.x * 256 + threadIdx.x;       // (var,n,e)
    int e = i & 127, n = (i >> 7) & 1023, var = i >> 17;
    float ssum = (var < 2) ? kb[var * 128 + e] : qb[(var - 2) * 128 + e];
    const float* wl = kwl + ((size_t)var * 128 + e) * 64;
    if (var < 2) {
        const float* nvp = nv1 + (size_t)n * 64;
#pragma unroll 8
        for (int d = 0; d < 64; d++) ssum += wl[d] * nvp[d];
    } else {
#pragma unroll 8
        for (int d = 0; d < 64; d++) ssum += wl[d] * nv2[(size_t)d * 1024 + n];
    }
    tkq[i] = ssum;
}

// aT[s][w][v] f16 (transpose of support)
__global__ void k_acvt(const float* __restrict__ sup, f16* __restrict__ aT) {
    __shared__ float Ls[64][65];
    int s = blockIdx.z, v0 = blockIdx.y * 64, w0 = blockIdx.x * 64, t = threadIdx.x;
    int j = t & 63, i0 = t >> 6;
    for (int i = i0; i < 64; i += 4)
        Ls[i][j] = sup[((size_t)s * 1024 + v0 + i) * 1024 + w0 + j];
    __syncthreads();
    for (int i = i0; i < 64; i += 4)
        aT[((size_t)s * 1024 + w0 + i) * 1024 + v0 + j] = (f16)Ls[j][i];
}

// ================= MFMA GEMM kernels ========================================

// keysT[var][b][n][e] = sum_dl xT2[b][n][dl]*kwb[var][e][dl] + tkq[var][n][e]
__global__ __launch_bounds__(256) void k_kqgemm(const f16* __restrict__ xT2,
                                                const f16* __restrict__ kwb,
                                                const float* __restrict__ tkq,
                                                f16* __restrict__ keysT) {
    __shared__ char As[16384], Bs[16384];
    int z = blockIdx.z, var = z >> 3, b = z & 7;
    int nt = blockIdx.x, t = threadIdx.x;
    const char* Ag = (const char*)(xT2 + ((size_t)b * 1024 + nt * 128) * 768);
    const char* Bg = (const char*)(kwb + (size_t)var * 128 * 768);
    f32x4 acc[4][4];
    zero_acc(acc);
    for (int kt = 0; kt < 12; kt++) {
        stage_tile(Ag + kt * 128, 1536, As, t);
        stage_tile(Bg + kt * 128, 1536, Bs, t);
        __syncthreads();
        mma_tile(As, Bs, t, acc);
        __syncthreads();
    }
    int lane = t & 63, wid = t >> 6;
    int wr = (wid >> 1) * 64, wc = (wid & 1) * 64;
    int cn = lane & 15, rq = (lane >> 4) * 4;
#pragma unroll
    for (int m = 0; m < 4; m++)
#pragma unroll
        for (int q = 0; q < 4; q++) {
            int n_g = nt * 128 + wr + m * 16 + rq + q;
#pragma unroll
            for (int nn = 0; nn < 4; nn++) {
                int e = wc + nn * 16 + cn;
                float v = acc[m][nn][q] + tkq[((size_t)var * 1024 + n_g) * 128 + e];
                keysT[(((size_t)var * 8 + b) * 1024 + n_g) * 128 + e] = (f16)v;
            }
        }
}

// scT[bl][w][v] = relu(sum_e query[w,e]*keys[v,e]) for b = bh*4+bl
__global__ __launch_bounds__(256) void k_scoregemm(const f16* __restrict__ keysT,
                                                   float* __restrict__ scT,
                                                   int h, int bh) {
    __shared__ char As[16384], Bs[16384];
    int bl = blockIdx.z, b = bh * 4 + bl;
    int wt = blockIdx.y, vt = blockIdx.x, t = threadIdx.x;
    const char* Ag = (const char*)(keysT + (((size_t)(2 + h) * 8 + b) * 1024 + wt * 128) * 128);
    const char* Bg = (const char*)(keysT + (((size_t)h * 8 + b) * 1024 + vt * 128) * 128);
    f32x4 acc[4][4];
    zero_acc(acc);
    for (int kt = 0; kt < 2; kt++) {
        stage_tile(Ag + kt * 128, 256, As, t);
        stage_tile(Bg + kt * 128, 256, Bs, t);
        __syncthreads();
        mma_tile(As, Bs, t, acc);
        __syncthreads();
    }
    int lane = t & 63, wid = t >> 6;
    int wr = (wid >> 1) * 64, wc = (wid & 1) * 64;
    int cn = lane & 15, rq = (lane >> 4) * 4;
#pragma unroll
    for (int m = 0; m < 4; m++)
#pragma unroll
        for (int q = 0; q < 4; q++) {
            int w = wt * 128 + wr + m * 16 + rq + q;
#pragma unroll
            for (int nn = 0; nn < 4; nn++) {
                int v = vt * 128 + wc + nn * 16 + cn;
                scT[((size_t)bl * 1024 + w) * 1024 + v] = fmaxf(acc[m][nn][q], 0.f);
            }
        }
}

// out[r][w] = sum_v A[r][v] * MT[w][v];   h += gate*out;  optionally P1 = f16(out)
template <bool WP1>
__global__ __launch_bounds__(256) void k_prop(const f16* __restrict__ A0,
                                              const f16* __restrict__ B0, size_t bsB,
                                              f16* __restrict__ P1,
                                              float* __restrict__ h,
                                              const float* __restrict__ gate, int gidx) {
    __shared__ char As[16384], Bs[16384];
    int b = blockIdx.z, rt = blockIdx.y, wt = blockIdx.x, t = threadIdx.x;
    const char* Ag = (const char*)(A0 + ((size_t)b * 768 + rt * 128) * 1024);
    const char* Bg = (const char*)(B0 + (size_t)b * bsB + (size_t)wt * 128 * 1024);
    f32x4 acc[4][4];
    zero_acc(acc);
    for (int kt = 0; kt < 16; kt++) {
        stage_tile(Ag + kt * 128, 2048, As, t);
        stage_tile(Bg + kt * 128, 2048, Bs, t);
        __syncthreads();
        mma_tile(As, Bs, t, acc);
        __syncthreads();
    }
    float gs = gate[b * 13 + gidx];
    int lane = t & 63, wid = t >> 6;
    int wr = (wid >> 1) * 64, wc = (wid & 1) * 64;
    int cn = lane & 15, rq = (lane >> 4) * 4;
#pragma unroll
    for (int m = 0; m < 4; m++)
#pragma unroll
        for (int q = 0; q < 4; q++) {
            int r = rt * 128 + wr + m * 16 + rq + q;
            int d = r / 12, l = r - d * 12;
            size_t hbase = ((size_t)(b * 64 + d) * 1024) * 12 + l;
            size_t pbase = ((size_t)b * 768 + r) * 1024;
#pragma unroll
            for (int nn = 0; nn < 4; nn++) {
                int w = wt * 128 + wc + nn * 16 + cn;
                float val = acc[m][nn][q];
                if (WP1) P1[pbase + w] = (f16)val;
                h[hbase + (size_t)w * 12] += gs * val;
            }
        }
}

// ================= softmax / stats / gate ===================================

__global__ void k_softmax(const float* __restrict__ scT, const f16* __restrict__ aT,
                          f16* __restrict__ attM, int s, int bh) {
    int gw = blockIdx.x * 4 + (threadIdx.x >> 6);  // bl*1024 + w
    int bl = gw >> 10, w = gw & 1023;
    int lane = threadIdx.x & 63;
    const float* sp = scT + (size_t)gw * 1024;
    const f16* ap = aT + ((size_t)s * 1024 + w) * 1024;
    float xx[16];
    float m = NEGV;
#pragma unroll
    for (int k = 0; k < 16; k++) {
        int v = k * 64 + lane;
        float e = sp[v];
        xx[k] = ((float)ap[v] > 0.f) ? e : NEGV;
        m = fmaxf(m, xx[k]);
    }
#pragma unroll
    for (int off = 1; off < 64; off <<= 1) m = fmaxf(m, __shfl_xor(m, off));
    float ssum = 0.f;
#pragma unroll
    for (int k = 0; k < 16; k++) {
        xx[k] = __expf(xx[k] - m);
        ssum += xx[k];
    }
#pragma unroll
    for (int off = 1; off < 64; off <<= 1) ssum += __shfl_xor(ssum, off);
    float inv = 1.f / ssum;
    f16* op = attM + (((size_t)(bh * 4 + bl)) * 1024 + w) * 1024;
#pragma unroll
    for (int k = 0; k < 16; k++) op[k * 64 + lane] = (f16)(xx[k] * inv);
}

// r[v] = sum_row M[row][v] * (order? rin[row] : 1)
__global__ void k_colsum(const f16* __restrict__ aT, const f16* __restrict__ attT,
                         float* __restrict__ ra, float* __restrict__ ratt, int order) {
    int u = blockIdx.y;
    int v = blockIdx.x * 256 + threadIdx.x;
    const f16* M;
    const float* rin = nullptr;
    float* out;
    if (u < 2) {
        M = aT + (size_t)u * 1048576;
        float* base = ra + (size_t)u * 2048;
        if (order) rin = base;
        out = base + order * 1024;
    } else {
        int q = u - 2;
        M = attT + (size_t)q * 1048576;
        float* base = ratt + (size_t)q * 2048;
        if (order) rin = base;
        out = base + order * 1024;
    }
    float ssum = 0.f;
    for (int row = 0; row < 1024; row++) {
        float mv = (float)M[(size_t)row * 1024 + v];
        ssum += order ? mv * rin[row] : mv;
    }
    out[v] = ssum;
}

__global__ void k_feat13(const float* __restrict__ xl, const float* __restrict__ ra,
                         const float* __restrict__ ratt, float* __restrict__ feats) {
    int bd = blockIdx.x;
    int b = bd >> 6, d = bd & 63;
    const float* xp = xl + (size_t)bd * 1024;
    int t = threadIdx.x;
    float s[13];
#pragma unroll
    for (int i = 0; i < 13; i++) s[i] = 0.f;
    for (int v = t; v < 1024; v += 256) {
        float xv = xp[v];
        s[0] += xv;
#pragma unroll
        for (int ss = 0; ss < 2; ss++) {
            s[1 + ss * 6 + 0] += xv * ra[ss * 2048 + v];
            s[1 + ss * 6 + 1] += xv * ra[ss * 2048 + 1024 + v];
#pragma unroll
            for (int hh = 0; hh < 2; hh++) {
                const float* rb = ratt + (((size_t)(ss * 2 + hh) * 8 + b)) * 2048;
                s[1 + ss * 6 + 2 + hh * 2] += xv * rb[v];
                s[1 + ss * 6 + 3 + hh * 2] += xv * rb[1024 + v];
            }
        }
    }
    int wid = t >> 6, lane = t & 63;
#pragma unroll
    for (int i = 0; i < 13; i++)
#pragma unroll
        for (int off = 1; off < 64; off <<= 1) s[i] += __shfl_xor(s[i], off);
    __shared__ float red[13][4];
    if (lane == 0)
#pragma unroll
        for (int i = 0; i < 13; i++) red[i][wid] = s[i];
    __syncthreads();
    if (t < 13) {
        float tot = red[t][0] + red[t][1] + red[t][2] + red[t][3];
        feats[(size_t)b * 832 + t * 64 + d] = tot * (1.f / (1024.f * 12.f));
    }
}

__global__ void k_gate(const float* __restrict__ feats, const float* __restrict__ aw,
                       const float* __restrict__ ab, float* __restrict__ gate) {
    int b = blockIdx.x, t = threadIdx.x;
    __shared__ float lg[13];
    if (t < 13) {
        float s = ab[t];
        const float* f = feats + (size_t)b * 832;
        const float* w = aw + (size_t)t * 832;
        for (int k = 0; k < 832; k++) s += f[k] * w[k];
        lg[t] = s;
    }
    __syncthreads();
    if (t == 0) {
        float m = lg[0];
        for (int j = 1; j < 13; j++) m = fmaxf(m, lg[j]);
        float ss = 0.f;
        for (int j = 0; j < 13; j++) ss += __expf(lg[j] - m);
        float inv = 1.f / ss;
        for (int j = 0; j < 13; j++) gate[b * 13 + j] = __expf(lg[j] - m) * inv;
    }
}

__global__ void k_hinit(const float* __restrict__ x, const float* __restrict__ gate,
                        float* __restrict__ h) {
    size_t i4 = (size_t)blockIdx.x * 256 + threadIdx.x;
    int b = (int)(i4 / 196608);
    float g = gate[b * 13];
    float4 v = reinterpret_cast<const float4*>(x)[i4];
    float4 o = {v.x * g, v.y * g, v.z * g, v.w * g};
    reinterpret_cast<float4*>(h)[i4] = o;
}

__global__ __launch_bounds__(256) void k_final(float* __restrict__ h,
                                               const float* __restrict__ fw,
                                               const float* __restrict__ fb) {
    int col = blockIdx.x * 256 + threadIdx.x;
    int b = col / 12288, r = col - b * 12288;
    size_t base = (size_t)b * 786432 + r;
    float hreg[64];
#pragma unroll
    for (int d = 0; d < 64; d++) hreg[d] = h[base + (size_t)d * 12288];
#pragma unroll 4
    for (int o = 0; o < 64; o++) {
        float acc = fb[o];
#pragma unroll
        for (int d = 0; d < 64; d++) acc += fw[o * 64 + d] * hreg[d];
        h[base + (size_t)o * 12288] = acc;
    }
}

// ================= launch ===================================================

extern "C" void kernel_launch(void* const* d_in, const int* in_sizes, int n_in,
                              void* d_out, int out_size, void* d_ws, size_t ws_size,
                              hipStream_t stream) {
    const float* x   = (const float*)d_in[0];
    const float* sup = (const float*)d_in[1];
    const float* nv1 = (const float*)d_in[2];
    const float* nv2 = (const float*)d_in[3];
    const float* kw  = (const float*)d_in[4];
    const float* kb  = (const float*)d_in[5];
    const float* qw  = (const float*)d_in[6];
    const float* qb  = (const float*)d_in[7];
    const float* aw  = (const float*)d_in[8];
    const float* ab  = (const float*)d_in[9];
    const float* fw  = (const float*)d_in[10];
    const float* fb  = (const float*)d_in[11];
    float* hout = (float*)d_out;

    float* wsf = (float*)d_ws;
    size_t o = 0;
    f16*   XT     = (f16*)(wsf + o);  o += 3145728;   // [8][768][1024] f16
    float* attReg = wsf + o;          o += 16777216;  // attT [4][8][1024][1024] f16
    f16*   attT   = (f16*)attReg;
    f16*   xT2    = (f16*)attReg;                     // overlay (dead before attT)
    f16*   aT     = (f16*)(wsf + o);  o += 1048576;   // [2][1024][1024] f16
    float* scT    = wsf + o;          o += 4194304;   // [4][1024][1024] f32
    f16*   P1     = (f16*)scT;                        // overlay (after softmax)
    f16*   keysT  = (f16*)(wsf + o);  o += 2097152;   // [4][8][1024][128] f16
    f16*   kwb    = (f16*)(wsf + o);  o += 196608;    // [4][128][768] f16
    float* kwl    = wsf + o;          o += 32768;     // [4][128][64]
    float* tkq    = wsf + o;          o += 524288;    // [4][1024][128]
    float* xl     = wsf + o;          o += 524288;    // [8][64][1024]
    float* ra     = wsf + o;          o += 4096;      // [2][2][1024]
    float* ratt   = wsf + o;          o += 65536;     // [4][8][2][1024]
    float* feats  = wsf + o;          o += 6656;
    float* gate   = wsf + o;          o += 128;
    if (ws_size < o * 4) return;

    k_xt<<<2048, 256, 0, stream>>>(x, XT, xl);
    k_xt2<<<dim3(16, 4, 8), 256, 0, stream>>>(x, xT2);
    k_wcvt<<<128, 256, 0, stream>>>(kw, qw, kwl, kwb);
    k_tkq<<<2048, 256, 0, stream>>>(kwl, nv1, nv2, kb, qb, tkq);
    k_acvt<<<dim3(16, 16, 2), 256, 0, stream>>>(sup, aT);

    k_kqgemm<<<dim3(8, 1, 32), 256, 0, stream>>>(xT2, kwb, tkq, keysT);

    for (int h = 0; h < 2; h++)
        for (int bh = 0; bh < 2; bh++) {
            k_scoregemm<<<dim3(8, 8, 4), 256, 0, stream>>>(keysT, scT, h, bh);
            for (int s = 0; s < 2; s++) {
                f16* attM = attT + (size_t)(s * 2 + h) * 8 * 1048576;
                k_softmax<<<1024, 256, 0, stream>>>(scT, aT, attM, s, bh);
            }
        }

    k_colsum<<<dim3(4, 34), 256, 0, stream>>>(aT, attT, ra, ratt, 0);
    k_colsum<<<dim3(4, 34), 256, 0, stream>>>(aT, attT, ra, ratt, 1);
    k_feat13<<<512, 256, 0, stream>>>(xl, ra, ratt, feats);
    k_gate<<<8, 64, 0, stream>>>(feats, aw, ab, gate);
    k_hinit<<<6144, 256, 0, stream>>>(x, gate, hout);

    for (int s = 0; s < 2; s++)
        for (int kind = 0; kind < 3; kind++) {
            const f16* B0;
            size_t bsB;
            if (kind == 0) { B0 = aT + (size_t)s * 1048576; bsB = 0; }
            else { B0 = attT + (size_t)((s * 2 + kind - 1) * 8) * 1048576; bsB = 1048576; }
            int g1 = 1 + s * 6 + 2 * kind;
            k_prop<true><<<dim3(8, 6, 8), 256, 0, stream>>>(XT, B0, bsB, P1, hout, gate, g1);
            k_prop<false><<<dim3(8, 6, 8), 256, 0, stream>>>(P1, B0, bsB, (f16*)nullptr, hout, gate, g1 + 1);
        }

    k_final<<<384, 256, 0, stream>>>(hout, fw, fb);
}

// Round 3
// 811.616 us; speedup vs baseline: 5.2405x; 1.6229x over previous
//
#include <hip/hip_runtime.h>
#include <hip/hip_bf16.h>

#define BB 8
#define DD 64
#define NNODE 1024
#define LLL 12
#define EE 128
#define NEGV -9.0e15f

typedef _Float16 f16;
typedef _Float16 f16x8 __attribute__((ext_vector_type(8)));
typedef float f32x4 __attribute__((ext_vector_type(4)));

// ================= GEMM core helpers (128x128 tile, BK=64, 4 waves) =========
// LDS tiles: [128 rows][64 k] f16 = 16KB each, linear layout for global_load_lds,
// XOR-swizzled source addresses; ds_read applies the same XOR (involution).

__device__ __forceinline__ void stage_tile(const char* g, int ld, char* lds, int t) {
    int wid = t >> 6, lane = t & 63;
#pragma unroll
    for (int it = 0; it < 4; it++) {
        int cbase = it * 256 + wid * 64;          // wave-uniform chunk base
        int c = cbase + lane;
        int row = c >> 3, p = c & 7;
        int gch = p ^ (row & 7);                  // inverse swizzle on SOURCE
        const char* src = g + (size_t)row * ld + gch * 16;
        char* dst = lds + (size_t)cbase * 16;     // wave-uniform; lane*16 implicit
        __builtin_amdgcn_global_load_lds(
            (const __attribute__((address_space(1))) unsigned int*)src,
            (__attribute__((address_space(3))) unsigned int*)dst, 16, 0, 0);
    }
}

__device__ __forceinline__ void mma_tile(const char* As, const char* Bs, int t,
                                         f32x4 acc[4][4]) {
    int lane = t & 63, wid = t >> 6;
    int wr = (wid >> 1) * 64, wc = (wid & 1) * 64;
    int lrow = lane & 15, lk = lane >> 4;
#pragma unroll
    for (int kk = 0; kk < 2; kk++) {
        f16x8 af[4], bf[4];
#pragma unroll
        for (int m = 0; m < 4; m++) {
            int row = wr + m * 16 + lrow;
            int p = (kk * 4 + lk) ^ (row & 7);    // swizzled read
            af[m] = *(const f16x8*)(As + row * 128 + p * 16);
        }
#pragma unroll
        for (int n = 0; n < 4; n++) {
            int row = wc + n * 16 + lrow;
            int p = (kk * 4 + lk) ^ (row & 7);
            bf[n] = *(const f16x8*)(Bs + row * 128 + p * 16);
        }
#pragma unroll
        for (int m = 0; m < 4; m++)
#pragma unroll
            for (int n = 0; n < 4; n++)
                acc[m][n] = __builtin_amdgcn_mfma_f32_16x16x32_f16(
                    af[m], bf[n], acc[m][n], 0, 0, 0);
    }
}

__device__ __forceinline__ void zero_acc(f32x4 acc[4][4]) {
#pragma unroll
    for (int m = 0; m < 4; m++)
#pragma unroll
        for (int n = 0; n < 4; n++)
#pragma unroll
            for (int q = 0; q < 4; q++) acc[m][n][q] = 0.f;
}

// ================= prep kernels =============================================

// XT[b][(d,l)][v] f16 + xl[b,d,v] = sum_l x
__global__ void k_xt(const float* __restrict__ x, f16* __restrict__ XT,
                     float* __restrict__ xl) {
    int i = blockIdx.x * 256 + threadIdx.x;       // (b,d,v)
    int v = i & 1023, d = (i >> 10) & 63, b = i >> 16;
    const float4* p = reinterpret_cast<const float4*>(x + (size_t)i * 12);
    float4 a = p[0], c = p[1], e = p[2];
    float vv[12] = {a.x, a.y, a.z, a.w, c.x, c.y, c.z, c.w, e.x, e.y, e.z, e.w};
    float ssum = 0.f;
    size_t base = ((size_t)b * 768) * 1024 + v;
    int r0 = d * 12;
#pragma unroll
    for (int l = 0; l < 12; l++) {
        ssum += vv[l];
        XT[base + (size_t)(r0 + l) * 1024] = (f16)vv[l];
    }
    xl[i] = ssum;
}

// xT2[b][n][(d,l)] f16 via LDS transpose of 16d x 64n tiles
__global__ __launch_bounds__(256) void k_xt2(const float* __restrict__ x,
                                             f16* __restrict__ xT2) {
    __shared__ f16 Ls[64][208];
    int b = blockIdx.z, d0 = blockIdx.y * 16, n0 = blockIdx.x * 64, t = threadIdx.x;
    for (int f = t; f < 3072; f += 256) {
        int dd = f / 192, rem = f - dd * 192, j = rem / 3, q = rem - j * 3;
        float4 v = *reinterpret_cast<const float4*>(
            x + (((size_t)(b * 64 + d0 + dd) * 1024) + n0 + j) * 12 + q * 4);
        f16* dst = &Ls[j][dd * 12 + q * 4];
        dst[0] = (f16)v.x; dst[1] = (f16)v.y; dst[2] = (f16)v.z; dst[3] = (f16)v.w;
    }
    __syncthreads();
    for (int c = t; c < 1536; c += 256) {
        int j = c / 24, p = c - j * 24;
        *reinterpret_cast<f16x8*>(
            xT2 + ((size_t)(b * 1024) + n0 + j) * 768 + d0 * 12 + p * 8) =
            *reinterpret_cast<const f16x8*>(&Ls[j][p * 8]);
    }
}

// kwb[var][e][768] f16, kwl[var][e][d] = sum_l w
__global__ void k_wcvt(const float* __restrict__ kw, const float* __restrict__ qw,
                       float* __restrict__ kwl, f16* __restrict__ kwb) {
    int i = blockIdx.x * 256 + threadIdx.x;       // (var,e,d)
    int d = i & 63, e = (i >> 6) & 127, var = i >> 13;
    const float* src = (var < 2 ? kw + (size_t)var * 98304
                                : qw + (size_t)(var - 2) * 98304) +
                       ((size_t)e * 64 + d) * 12;
    f16* dst = kwb + ((size_t)var * 128 + e) * 768 + d * 12;
    float ssum = 0.f;
#pragma unroll
    for (int l = 0; l < 12; l++) {
        float v = src[l];
        ssum += v;
        dst[l] = (f16)v;
    }
    kwl[i] = ssum;
}

// tkq[var][n][e] = sum_d kwl[var][e][d]*nv + bias[var][e]
__global__ void k_tkq(const float* __restrict__ kwl, const float* __restrict__ nv1,
                      const float* __restrict__ nv2, const float* __restrict__ kb,
                      const float* __restrict__ qb, float* __restrict__ tkq) {
    int i = blockIdx.x * 256 + threadIdx.x;       // (var,n,e)
    int e = i & 127, n = (i >> 7) & 1023, var = i >> 17;
    float ssum = (var < 2) ? kb[var * 128 + e] : qb[(var - 2) * 128 + e];
    const float* wl = kwl + ((size_t)var * 128 + e) * 64;
    if (var < 2) {
        const float* nvp = nv1 + (size_t)n * 64;
#pragma unroll 8
        for (int d = 0; d < 64; d++) ssum += wl[d] * nvp[d];
    } else {
#pragma unroll 8
        for (int d = 0; d < 64; d++) ssum += wl[d] * nv2[(size_t)d * 1024 + n];
    }
    tkq[i] = ssum;
}

// aT[s][w][v] f16 (transpose of support)
__global__ void k_acvt(const float* __restrict__ sup, f16* __restrict__ aT) {
    __shared__ float Ls[64][65];
    int s = blockIdx.z, v0 = blockIdx.y * 64, w0 = blockIdx.x * 64, t = threadIdx.x;
    int j = t & 63, i0 = t >> 6;
    for (int i = i0; i < 64; i += 4)
        Ls[i][j] = sup[((size_t)s * 1024 + v0 + i) * 1024 + w0 + j];
    __syncthreads();
    for (int i = i0; i < 64; i += 4)
        aT[((size_t)s * 1024 + w0 + i) * 1024 + v0 + j] = (f16)Ls[j][i];
}

// ================= MFMA GEMM kernels ========================================

// keysT[var][b][n][e] = sum_dl xT2[b][n][dl]*kwb[var][e][dl] + tkq[var][n][e]
__global__ __launch_bounds__(256) void k_kqgemm(const f16* __restrict__ xT2,
                                                const f16* __restrict__ kwb,
                                                const float* __restrict__ tkq,
                                                f16* __restrict__ keysT) {
    __shared__ char As[16384], Bs[16384];
    int z = blockIdx.z, var = z >> 3, b = z & 7;
    int nt = blockIdx.x, t = threadIdx.x;
    const char* Ag = (const char*)(xT2 + ((size_t)b * 1024 + nt * 128) * 768);
    const char* Bg = (const char*)(kwb + (size_t)var * 128 * 768);
    f32x4 acc[4][4];
    zero_acc(acc);
    for (int kt = 0; kt < 12; kt++) {
        stage_tile(Ag + kt * 128, 1536, As, t);
        stage_tile(Bg + kt * 128, 1536, Bs, t);
        __syncthreads();
        mma_tile(As, Bs, t, acc);
        __syncthreads();
    }
    int lane = t & 63, wid = t >> 6;
    int wr = (wid >> 1) * 64, wc = (wid & 1) * 64;
    int cn = lane & 15, rq = (lane >> 4) * 4;
#pragma unroll
    for (int m = 0; m < 4; m++)
#pragma unroll
        for (int q = 0; q < 4; q++) {
            int n_g = nt * 128 + wr + m * 16 + rq + q;
#pragma unroll
            for (int nn = 0; nn < 4; nn++) {
                int e = wc + nn * 16 + cn;
                float v = acc[m][nn][q] + tkq[((size_t)var * 1024 + n_g) * 128 + e];
                keysT[(((size_t)var * 8 + b) * 1024 + n_g) * 128 + e] = (f16)v;
            }
        }
}

// scT[bl][w][v] = relu(sum_e query[w,e]*keys[v,e]) for b = bh*4+bl
__global__ __launch_bounds__(256) void k_scoregemm(const f16* __restrict__ keysT,
                                                   float* __restrict__ scT,
                                                   int h, int bh) {
    __shared__ char As[16384], Bs[16384];
    int bl = blockIdx.z, b = bh * 4 + bl;
    int wt = blockIdx.y, vt = blockIdx.x, t = threadIdx.x;
    const char* Ag = (const char*)(keysT + (((size_t)(2 + h) * 8 + b) * 1024 + wt * 128) * 128);
    const char* Bg = (const char*)(keysT + (((size_t)h * 8 + b) * 1024 + vt * 128) * 128);
    f32x4 acc[4][4];
    zero_acc(acc);
    for (int kt = 0; kt < 2; kt++) {
        stage_tile(Ag + kt * 128, 256, As, t);
        stage_tile(Bg + kt * 128, 256, Bs, t);
        __syncthreads();
        mma_tile(As, Bs, t, acc);
        __syncthreads();
    }
    int lane = t & 63, wid = t >> 6;
    int wr = (wid >> 1) * 64, wc = (wid & 1) * 64;
    int cn = lane & 15, rq = (lane >> 4) * 4;
#pragma unroll
    for (int m = 0; m < 4; m++)
#pragma unroll
        for (int q = 0; q < 4; q++) {
            int w = wt * 128 + wr + m * 16 + rq + q;
#pragma unroll
            for (int nn = 0; nn < 4; nn++) {
                int v = vt * 128 + wc + nn * 16 + cn;
                scT[((size_t)bl * 1024 + w) * 1024 + v] = fmaxf(acc[m][nn][q], 0.f);
            }
        }
}

// out[r][w] = sum_v A[r][v] * MT[w][v];   h += gate*out;  optionally P1 = f16(out)
template <bool WP1>
__global__ __launch_bounds__(256) void k_prop(const f16* __restrict__ A0,
                                              const f16* __restrict__ B0, size_t bsB,
                                              f16* __restrict__ P1,
                                              float* __restrict__ h,
                                              const float* __restrict__ gate, int gidx) {
    __shared__ char As[16384], Bs[16384];
    int b = blockIdx.z, rt = blockIdx.y, wt = blockIdx.x, t = threadIdx.x;
    const char* Ag = (const char*)(A0 + ((size_t)b * 768 + rt * 128) * 1024);
    const char* Bg = (const char*)(B0 + (size_t)b * bsB + (size_t)wt * 128 * 1024);
    f32x4 acc[4][4];
    zero_acc(acc);
    for (int kt = 0; kt < 16; kt++) {
        stage_tile(Ag + kt * 128, 2048, As, t);
        stage_tile(Bg + kt * 128, 2048, Bs, t);
        __syncthreads();
        mma_tile(As, Bs, t, acc);
        __syncthreads();
    }
    float gs = gate[b * 13 + gidx];
    int lane = t & 63, wid = t >> 6;
    int wr = (wid >> 1) * 64, wc = (wid & 1) * 64;
    int cn = lane & 15, rq = (lane >> 4) * 4;
#pragma unroll
    for (int m = 0; m < 4; m++)
#pragma unroll
        for (int q = 0; q < 4; q++) {
            int r = rt * 128 + wr + m * 16 + rq + q;
            int d = r / 12, l = r - d * 12;
            size_t hbase = ((size_t)(b * 64 + d) * 1024) * 12 + l;
            size_t pbase = ((size_t)b * 768 + r) * 1024;
#pragma unroll
            for (int nn = 0; nn < 4; nn++) {
                int w = wt * 128 + wc + nn * 16 + cn;
                float val = acc[m][nn][q];
                if (WP1) P1[pbase + w] = (f16)val;
                h[hbase + (size_t)w * 12] += gs * val;
            }
        }
}

// ================= softmax / stats / gate ===================================

__global__ void k_softmax(const float* __restrict__ scT, const f16* __restrict__ aT,
                          f16* __restrict__ attM, int s, int bh) {
    int gw = blockIdx.x * 4 + (threadIdx.x >> 6);  // bl*1024 + w
    int bl = gw >> 10, w = gw & 1023;
    int lane = threadIdx.x & 63;
    const float* sp = scT + (size_t)gw * 1024;
    const f16* ap = aT + ((size_t)s * 1024 + w) * 1024;
    float xx[16];
    float m = NEGV;
#pragma unroll
    for (int k = 0; k < 16; k++) {
        int v = k * 64 + lane;
        float e = sp[v];
        xx[k] = ((float)ap[v] > 0.f) ? e : NEGV;
        m = fmaxf(m, xx[k]);
    }
#pragma unroll
    for (int off = 1; off < 64; off <<= 1) m = fmaxf(m, __shfl_xor(m, off));
    float ssum = 0.f;
#pragma unroll
    for (int k = 0; k < 16; k++) {
        xx[k] = __expf(xx[k] - m);
        ssum += xx[k];
    }
#pragma unroll
    for (int off = 1; off < 64; off <<= 1) ssum += __shfl_xor(ssum, off);
    float inv = 1.f / ssum;
    f16* op = attM + (((size_t)(bh * 4 + bl)) * 1024 + w) * 1024;
#pragma unroll
    for (int k = 0; k < 16; k++) op[k * 64 + lane] = (f16)(xx[k] * inv);
}

// ---------- colsum stage 1: partial[u][rc*2+rh][v] = sum over 32 rows ----------
// u<2: M = aT[u]; else M = attT[u-2].  ORDER=1 weights rows by r1 (order-0 result).
template <int ORDER>
__global__ __launch_bounds__(256) void k_colsum1(
    const f16* __restrict__ aT, const f16* __restrict__ attT,
    const float* __restrict__ ra, const float* __restrict__ ratt,
    float* __restrict__ partial) {
    int u = blockIdx.y, rc = blockIdx.x;          // rc 0..15
    int t = threadIdx.x;
    int lane7 = t & 127, rh = t >> 7;
    int v0 = lane7 * 8;
    const f16* M = (u < 2) ? aT + (size_t)u * 1048576
                           : attT + (size_t)(u - 2) * 1048576;
    const float* rin = nullptr;
    if (ORDER) rin = (u < 2) ? ra + (size_t)u * 2048 : ratt + (size_t)(u - 2) * 2048;
    float acc[8] = {};
    int row0 = rc * 64 + rh * 32;
#pragma unroll 4
    for (int i = 0; i < 32; i++) {
        int row = row0 + i;
        f16x8 mv = *reinterpret_cast<const f16x8*>(M + (size_t)row * 1024 + v0);
        float sc = ORDER ? rin[row] : 1.f;
#pragma unroll
        for (int j = 0; j < 8; j++) acc[j] += (float)mv[j] * sc;
    }
    float* pp = partial + ((size_t)u * 32 + rc * 2 + rh) * 1024 + v0;
#pragma unroll
    for (int j = 0; j < 8; j++) pp[j] = acc[j];
}

// ---------- colsum stage 2: reduce 32 partials -> ra/ratt[order] ----------
template <int ORDER>
__global__ void k_colsum2(const float* __restrict__ partial, float* __restrict__ ra,
                          float* __restrict__ ratt) {
    int u = blockIdx.x, t = threadIdx.x;
    for (int v = t; v < 1024; v += 256) {
        float s = 0.f;
#pragma unroll
        for (int k = 0; k < 32; k++) s += partial[((size_t)u * 32 + k) * 1024 + v];
        float* out = (u < 2) ? ra + (size_t)u * 2048 : ratt + (size_t)(u - 2) * 2048;
        out[ORDER * 1024 + v] = s;
    }
}

__global__ void k_feat13(const float* __restrict__ xl, const float* __restrict__ ra,
                         const float* __restrict__ ratt, float* __restrict__ feats) {
    int bd = blockIdx.x;
    int b = bd >> 6, d = bd & 63;
    const float* xp = xl + (size_t)bd * 1024;
    int t = threadIdx.x;
    float s[13];
#pragma unroll
    for (int i = 0; i < 13; i++) s[i] = 0.f;
    for (int v = t; v < 1024; v += 256) {
        float xv = xp[v];
        s[0] += xv;
#pragma unroll
        for (int ss = 0; ss < 2; ss++) {
            s[1 + ss * 6 + 0] += xv * ra[ss * 2048 + v];
            s[1 + ss * 6 + 1] += xv * ra[ss * 2048 + 1024 + v];
#pragma unroll
            for (int hh = 0; hh < 2; hh++) {
                const float* rb = ratt + (((size_t)(ss * 2 + hh) * 8 + b)) * 2048;
                s[1 + ss * 6 + 2 + hh * 2] += xv * rb[v];
                s[1 + ss * 6 + 3 + hh * 2] += xv * rb[1024 + v];
            }
        }
    }
    int wid = t >> 6, lane = t & 63;
#pragma unroll
    for (int i = 0; i < 13; i++)
#pragma unroll
        for (int off = 1; off < 64; off <<= 1) s[i] += __shfl_xor(s[i], off);
    __shared__ float red[13][4];
    if (lane == 0)
#pragma unroll
        for (int i = 0; i < 13; i++) red[i][wid] = s[i];
    __syncthreads();
    if (t < 13) {
        float tot = red[t][0] + red[t][1] + red[t][2] + red[t][3];
        feats[(size_t)b * 832 + t * 64 + d] = tot * (1.f / (1024.f * 12.f));
    }
}

__global__ void k_gate(const float* __restrict__ feats, const float* __restrict__ aw,
                       const float* __restrict__ ab, float* __restrict__ gate) {
    int b = blockIdx.x, t = threadIdx.x;
    __shared__ float lg[13];
    if (t < 13) {
        float s = ab[t];
        const float* f = feats + (size_t)b * 832;
        const float* w = aw + (size_t)t * 832;
        for (int k = 0; k < 832; k++) s += f[k] * w[k];
        lg[t] = s;
    }
    __syncthreads();
    if (t == 0) {
        float m = lg[0];
        for (int j = 1; j < 13; j++) m = fmaxf(m, lg[j]);
        float ss = 0.f;
        for (int j = 0; j < 13; j++) ss += __expf(lg[j] - m);
        float inv = 1.f / ss;
        for (int j = 0; j < 13; j++) gate[b * 13 + j] = __expf(lg[j] - m) * inv;
    }
}

__global__ void k_hinit(const float* __restrict__ x, const float* __restrict__ gate,
                        float* __restrict__ h) {
    size_t i4 = (size_t)blockIdx.x * 256 + threadIdx.x;
    int b = (int)(i4 / 196608);
    float g = gate[b * 13];
    float4 v = reinterpret_cast<const float4*>(x)[i4];
    float4 o = {v.x * g, v.y * g, v.z * g, v.w * g};
    reinterpret_cast<float4*>(h)[i4] = o;
}

__global__ __launch_bounds__(256) void k_final(float* __restrict__ h,
                                               const float* __restrict__ fw,
                                               const float* __restrict__ fb) {
    int col = blockIdx.x * 256 + threadIdx.x;
    int b = col / 12288, r = col - b * 12288;
    size_t base = (size_t)b * 786432 + r;
    float hreg[64];
#pragma unroll
    for (int d = 0; d < 64; d++) hreg[d] = h[base + (size_t)d * 12288];
#pragma unroll 4
    for (int o = 0; o < 64; o++) {
        float acc = fb[o];
#pragma unroll
        for (int d = 0; d < 64; d++) acc += fw[o * 64 + d] * hreg[d];
        h[base + (size_t)o * 12288] = acc;
    }
}

// ================= launch ===================================================

extern "C" void kernel_launch(void* const* d_in, const int* in_sizes, int n_in,
                              void* d_out, int out_size, void* d_ws, size_t ws_size,
                              hipStream_t stream) {
    const float* x   = (const float*)d_in[0];
    const float* sup = (const float*)d_in[1];
    const float* nv1 = (const float*)d_in[2];
    const float* nv2 = (const float*)d_in[3];
    const float* kw  = (const float*)d_in[4];
    const float* kb  = (const float*)d_in[5];
    const float* qw  = (const float*)d_in[6];
    const float* qb  = (const float*)d_in[7];
    const float* aw  = (const float*)d_in[8];
    const float* ab  = (const float*)d_in[9];
    const float* fw  = (const float*)d_in[10];
    const float* fb  = (const float*)d_in[11];
    float* hout = (float*)d_out;

    float* wsf = (float*)d_ws;
    size_t o = 0;
    f16*   XT     = (f16*)(wsf + o);  o += 3145728;   // [8][768][1024] f16
    float* attReg = wsf + o;          o += 16777216;  // attT [4][8][1024][1024] f16
    f16*   attT   = (f16*)attReg;
    f16*   xT2    = (f16*)attReg;                     // overlay (dead before attT)
    f16*   aT     = (f16*)(wsf + o);  o += 1048576;   // [2][1024][1024] f16
    float* scT    = wsf + o;          o += 4194304;   // [4][1024][1024] f32
    f16*   P1     = (f16*)scT;                        // overlay (after softmax)
    f16*   keysT  = (f16*)(wsf + o);  o += 2097152;   // [4][8][1024][128] f16
    f16*   kwb    = (f16*)(wsf + o);  o += 196608;    // [4][128][768] f16
    float* kwl    = wsf + o;          o += 32768;     // [4][128][64]
    float* tkq    = wsf + o;          o += 524288;    // [4][1024][128]
    float* xl     = wsf + o;          o += 524288;    // [8][64][1024]
    float* ra     = wsf + o;          o += 4096;      // [2][2][1024]
    float* ratt   = wsf + o;          o += 65536;     // [4][8][2][1024]
    float* feats  = wsf + o;          o += 6656;
    float* gate   = wsf + o;          o += 128;
    float* partial= wsf + o;          o += 1114112;   // [34][32][1024]
    if (ws_size < o * 4) return;

    k_xt<<<2048, 256, 0, stream>>>(x, XT, xl);
    k_xt2<<<dim3(16, 4, 8), 256, 0, stream>>>(x, xT2);
    k_wcvt<<<128, 256, 0, stream>>>(kw, qw, kwl, kwb);
    k_tkq<<<2048, 256, 0, stream>>>(kwl, nv1, nv2, kb, qb, tkq);
    k_acvt<<<dim3(16, 16, 2), 256, 0, stream>>>(sup, aT);

    k_kqgemm<<<dim3(8, 1, 32), 256, 0, stream>>>(xT2, kwb, tkq, keysT);

    for (int h = 0; h < 2; h++)
        for (int bh = 0; bh < 2; bh++) {
            k_scoregemm<<<dim3(8, 8, 4), 256, 0, stream>>>(keysT, scT, h, bh);
            for (int s = 0; s < 2; s++) {
                f16* attM = attT + (size_t)(s * 2 + h) * 8 * 1048576;
                k_softmax<<<1024, 256, 0, stream>>>(scT, aT, attM, s, bh);
            }
        }

    k_colsum1<0><<<dim3(16, 34), 256, 0, stream>>>(aT, attT, ra, ratt, partial);
    k_colsum2<0><<<34, 256, 0, stream>>>(partial, ra, ratt);
    k_colsum1<1><<<dim3(16, 34), 256, 0, stream>>>(aT, attT, ra, ratt, partial);
    k_colsum2<1><<<34, 256, 0, stream>>>(partial, ra, ratt);
    k_feat13<<<512, 256, 0, stream>>>(xl, ra, ratt, feats);
    k_gate<<<8, 64, 0, stream>>>(feats, aw, ab, gate);
    k_hinit<<<6144, 256, 0, stream>>>(x, gate, hout);

    for (int s = 0; s < 2; s++)
        for (int kind = 0; kind < 3; kind++) {
            const f16* B0;
            size_t bsB;
            if (kind == 0) { B0 = aT + (size_t)s * 1048576; bsB = 0; }
            else { B0 = attT + (size_t)((s * 2 + kind - 1) * 8) * 1048576; bsB = 1048576; }
            int g1 = 1 + s * 6 + 2 * kind;
            k_prop<true><<<dim3(8, 6, 8), 256, 0, stream>>>(XT, B0, bsB, P1, hout, gate, g1);
            k_prop<false><<<dim3(8, 6, 8), 256, 0, stream>>>(P1, B0, bsB, (f16*)nullptr, hout, gate, g1 + 1);
        }

    k_final<<<384, 256, 0, stream>>>(hout, fw, fb);
}

// Round 4
// 666.029 us; speedup vs baseline: 6.3861x; 1.2186x over previous
//
#include <hip/hip_runtime.h>
#include <hip/hip_bf16.h>

#define BB 8
#define DD 64
#define NNODE 1024
#define LLL 12
#define EE 128
#define NEGV -9.0e15f

typedef _Float16 f16;
typedef _Float16 f16x8 __attribute__((ext_vector_type(8)));
typedef float f32x4 __attribute__((ext_vector_type(4)));

// ================= GEMM core helpers (128x128 tile, BK=64, 4 waves) =========

__device__ __forceinline__ void stage_tile(const char* g, int ld, char* lds, int t) {
    int wid = t >> 6, lane = t & 63;
#pragma unroll
    for (int it = 0; it < 4; it++) {
        int cbase = it * 256 + wid * 64;          // wave-uniform chunk base
        int c = cbase + lane;
        int row = c >> 3, p = c & 7;
        int gch = p ^ (row & 7);                  // inverse swizzle on SOURCE
        const char* src = g + (size_t)row * ld + gch * 16;
        char* dst = lds + (size_t)cbase * 16;     // wave-uniform; lane*16 implicit
        __builtin_amdgcn_global_load_lds(
            (const __attribute__((address_space(1))) unsigned int*)src,
            (__attribute__((address_space(3))) unsigned int*)dst, 16, 0, 0);
    }
}

__device__ __forceinline__ void mma_tile(const char* As, const char* Bs, int t,
                                         f32x4 acc[4][4]) {
    int lane = t & 63, wid = t >> 6;
    int wr = (wid >> 1) * 64, wc = (wid & 1) * 64;
    int lrow = lane & 15, lk = lane >> 4;
#pragma unroll
    for (int kk = 0; kk < 2; kk++) {
        f16x8 af[4], bf[4];
#pragma unroll
        for (int m = 0; m < 4; m++) {
            int row = wr + m * 16 + lrow;
            int p = (kk * 4 + lk) ^ (row & 7);    // swizzled read
            af[m] = *(const f16x8*)(As + row * 128 + p * 16);
        }
#pragma unroll
        for (int n = 0; n < 4; n++) {
            int row = wc + n * 16 + lrow;
            int p = (kk * 4 + lk) ^ (row & 7);
            bf[n] = *(const f16x8*)(Bs + row * 128 + p * 16);
        }
#pragma unroll
        for (int m = 0; m < 4; m++)
#pragma unroll
            for (int n = 0; n < 4; n++)
                acc[m][n] = __builtin_amdgcn_mfma_f32_16x16x32_f16(
                    af[m], bf[n], acc[m][n], 0, 0, 0);
    }
}

__device__ __forceinline__ void zero_acc(f32x4 acc[4][4]) {
#pragma unroll
    for (int m = 0; m < 4; m++)
#pragma unroll
        for (int n = 0; n < 4; n++)
#pragma unroll
            for (int q = 0; q < 4; q++) acc[m][n][q] = 0.f;
}

// ================= prep kernels =============================================

// XT[b][(d,l)][v] f16 + xl[b,d,v] = sum_l x
__global__ void k_xt(const float* __restrict__ x, f16* __restrict__ XT,
                     float* __restrict__ xl) {
    int i = blockIdx.x * 256 + threadIdx.x;       // (b,d,v)
    int v = i & 1023, d = (i >> 10) & 63, b = i >> 16;
    const float4* p = reinterpret_cast<const float4*>(x + (size_t)i * 12);
    float4 a = p[0], c = p[1], e = p[2];
    float vv[12] = {a.x, a.y, a.z, a.w, c.x, c.y, c.z, c.w, e.x, e.y, e.z, e.w};
    float ssum = 0.f;
    size_t base = ((size_t)b * 768) * 1024 + v;
    int r0 = d * 12;
#pragma unroll
    for (int l = 0; l < 12; l++) {
        ssum += vv[l];
        XT[base + (size_t)(r0 + l) * 1024] = (f16)vv[l];
    }
    xl[i] = ssum;
}

// xT2[b][n][(d,l)] f16 via LDS transpose of 16d x 64n tiles
__global__ __launch_bounds__(256) void k_xt2(const float* __restrict__ x,
                                             f16* __restrict__ xT2) {
    __shared__ f16 Ls[64][208];
    int b = blockIdx.z, d0 = blockIdx.y * 16, n0 = blockIdx.x * 64, t = threadIdx.x;
    for (int f = t; f < 3072; f += 256) {
        int dd = f / 192, rem = f - dd * 192, j = rem / 3, q = rem - j * 3;
        float4 v = *reinterpret_cast<const float4*>(
            x + (((size_t)(b * 64 + d0 + dd) * 1024) + n0 + j) * 12 + q * 4);
        f16* dst = &Ls[j][dd * 12 + q * 4];
        dst[0] = (f16)v.x; dst[1] = (f16)v.y; dst[2] = (f16)v.z; dst[3] = (f16)v.w;
    }
    __syncthreads();
    for (int c = t; c < 1536; c += 256) {
        int j = c / 24, p = c - j * 24;
        *reinterpret_cast<f16x8*>(
            xT2 + ((size_t)(b * 1024) + n0 + j) * 768 + d0 * 12 + p * 8) =
            *reinterpret_cast<const f16x8*>(&Ls[j][p * 8]);
    }
}

// kwb[var][e][768] f16, kwl[var][e][d] = sum_l w
__global__ void k_wcvt(const float* __restrict__ kw, const float* __restrict__ qw,
                       float* __restrict__ kwl, f16* __restrict__ kwb) {
    int i = blockIdx.x * 256 + threadIdx.x;       // (var,e,d)
    int d = i & 63, e = (i >> 6) & 127, var = i >> 13;
    const float* src = (var < 2 ? kw + (size_t)var * 98304
                                : qw + (size_t)(var - 2) * 98304) +
                       ((size_t)e * 64 + d) * 12;
    f16* dst = kwb + ((size_t)var * 128 + e) * 768 + d * 12;
    float ssum = 0.f;
#pragma unroll
    for (int l = 0; l < 12; l++) {
        float v = src[l];
        ssum += v;
        dst[l] = (f16)v;
    }
    kwl[i] = ssum;
}

// tkq[var][n][e] = sum_d kwl[var][e][d]*nv + bias[var][e]
__global__ void k_tkq(const float* __restrict__ kwl, const float* __restrict__ nv1,
                      const float* __restrict__ nv2, const float* __restrict__ kb,
                      const float* __restrict__ qb, float* __restrict__ tkq) {
    int i = blockIdx.x * 256 + threadIdx.x;       // (var,n,e)
    int e = i & 127, n = (i >> 7) & 1023, var = i >> 17;
    float ssum = (var < 2) ? kb[var * 128 + e] : qb[(var - 2) * 128 + e];
    const float* wl = kwl + ((size_t)var * 128 + e) * 64;
    if (var < 2) {
        const float* nvp = nv1 + (size_t)n * 64;
#pragma unroll 8
        for (int d = 0; d < 64; d++) ssum += wl[d] * nvp[d];
    } else {
#pragma unroll 8
        for (int d = 0; d < 64; d++) ssum += wl[d] * nv2[(size_t)d * 1024 + n];
    }
    tkq[i] = ssum;
}

// aT[s][w][v] f16 (transpose of support)
__global__ void k_acvt(const float* __restrict__ sup, f16* __restrict__ aT) {
    __shared__ float Ls[64][65];
    int s = blockIdx.z, v0 = blockIdx.y * 64, w0 = blockIdx.x * 64, t = threadIdx.x;
    int j = t & 63, i0 = t >> 6;
    for (int i = i0; i < 64; i += 4)
        Ls[i][j] = sup[((size_t)s * 1024 + v0 + i) * 1024 + w0 + j];
    __syncthreads();
    for (int i = i0; i < 64; i += 4)
        aT[((size_t)s * 1024 + w0 + i) * 1024 + v0 + j] = (f16)Ls[j][i];
}

// ================= MFMA GEMM kernels ========================================

// keysT[var][b][n][e] = sum_dl xT2[b][n][dl]*kwb[var][e][dl] + tkq[var][n][e]
__global__ __launch_bounds__(256) void k_kqgemm(const f16* __restrict__ xT2,
                                                const f16* __restrict__ kwb,
                                                const float* __restrict__ tkq,
                                                f16* __restrict__ keysT) {
    __shared__ char As[16384], Bs[16384];
    int z = blockIdx.z, var = z >> 3, b = z & 7;
    int nt = blockIdx.x, t = threadIdx.x;
    const char* Ag = (const char*)(xT2 + ((size_t)b * 1024 + nt * 128) * 768);
    const char* Bg = (const char*)(kwb + (size_t)var * 128 * 768);
    f32x4 acc[4][4];
    zero_acc(acc);
    for (int kt = 0; kt < 12; kt++) {
        stage_tile(Ag + kt * 128, 1536, As, t);
        stage_tile(Bg + kt * 128, 1536, Bs, t);
        __syncthreads();
        mma_tile(As, Bs, t, acc);
        __syncthreads();
    }
    int lane = t & 63, wid = t >> 6;
    int wr = (wid >> 1) * 64, wc = (wid & 1) * 64;
    int cn = lane & 15, rq = (lane >> 4) * 4;
#pragma unroll
    for (int m = 0; m < 4; m++)
#pragma unroll
        for (int q = 0; q < 4; q++) {
            int n_g = nt * 128 + wr + m * 16 + rq + q;
#pragma unroll
            for (int nn = 0; nn < 4; nn++) {
                int e = wc + nn * 16 + cn;
                float v = acc[m][nn][q] + tkq[((size_t)var * 1024 + n_g) * 128 + e];
                keysT[(((size_t)var * 8 + b) * 1024 + n_g) * 128 + e] = (f16)v;
            }
        }
}

// scT[bl][w][v] = relu(sum_e query[w,e]*keys[v,e]) for b = bh*2+bl
__global__ __launch_bounds__(256) void k_scoregemm(const f16* __restrict__ keysT,
                                                   float* __restrict__ scT,
                                                   int h, int bh) {
    __shared__ char As[16384], Bs[16384];
    int bl = blockIdx.z, b = bh * 2 + bl;
    int wt = blockIdx.y, vt = blockIdx.x, t = threadIdx.x;
    const char* Ag = (const char*)(keysT + (((size_t)(2 + h) * 8 + b) * 1024 + wt * 128) * 128);
    const char* Bg = (const char*)(keysT + (((size_t)h * 8 + b) * 1024 + vt * 128) * 128);
    f32x4 acc[4][4];
    zero_acc(acc);
    for (int kt = 0; kt < 2; kt++) {
        stage_tile(Ag + kt * 128, 256, As, t);
        stage_tile(Bg + kt * 128, 256, Bs, t);
        __syncthreads();
        mma_tile(As, Bs, t, acc);
        __syncthreads();
    }
    int lane = t & 63, wid = t >> 6;
    int wr = (wid >> 1) * 64, wc = (wid & 1) * 64;
    int cn = lane & 15, rq = (lane >> 4) * 4;
#pragma unroll
    for (int m = 0; m < 4; m++)
#pragma unroll
        for (int q = 0; q < 4; q++) {
            int w = wt * 128 + wr + m * 16 + rq + q;
#pragma unroll
            for (int nn = 0; nn < 4; nn++) {
                int v = vt * 128 + wc + nn * 16 + cn;
                scT[((size_t)bl * 1024 + w) * 1024 + v] = fmaxf(acc[m][nn][q], 0.f);
            }
        }
}

// out[r][w] = sum_v A[r][v] * MT[w][v];  hacc[b][r][w] += gate*out;  opt P1=f16(out)
template <bool WP1>
__global__ __launch_bounds__(256) void k_prop(const f16* __restrict__ A0,
                                              const f16* __restrict__ B0, size_t bsB,
                                              f16* __restrict__ P1,
                                              float* __restrict__ hacc,
                                              const float* __restrict__ gate, int gidx) {
    __shared__ char As[16384], Bs[16384];
    int b = blockIdx.z, rt = blockIdx.y, wt = blockIdx.x, t = threadIdx.x;
    const char* Ag = (const char*)(A0 + ((size_t)b * 768 + rt * 128) * 1024);
    const char* Bg = (const char*)(B0 + (size_t)b * bsB + (size_t)wt * 128 * 1024);
    f32x4 acc[4][4];
    zero_acc(acc);
    for (int kt = 0; kt < 16; kt++) {
        stage_tile(Ag + kt * 128, 2048, As, t);
        stage_tile(Bg + kt * 128, 2048, Bs, t);
        __syncthreads();
        mma_tile(As, Bs, t, acc);
        __syncthreads();
    }
    float gs = gate[b * 13 + gidx];
    int lane = t & 63, wid = t >> 6;
    int wr = (wid >> 1) * 64, wc = (wid & 1) * 64;
    int cn = lane & 15, rq = (lane >> 4) * 4;
#pragma unroll
    for (int m = 0; m < 4; m++)
#pragma unroll
        for (int q = 0; q < 4; q++) {
            int r = rt * 128 + wr + m * 16 + rq + q;
            size_t pbase = ((size_t)b * 768 + r) * 1024;
#pragma unroll
            for (int nn = 0; nn < 4; nn++) {
                int w = wt * 128 + wc + nn * 16 + cn;
                float val = acc[m][nn][q];
                if (WP1) P1[pbase + w] = (f16)val;
                hacc[pbase + w] += gs * val;
            }
        }
}

// ================= softmax / stats / gate ===================================

__global__ void k_softmax(const float* __restrict__ scT, const f16* __restrict__ aT,
                          f16* __restrict__ attM, int s, int bh) {
    int gw = blockIdx.x * 4 + (threadIdx.x >> 6);  // bl*1024 + w, gw in [0,2048)
    int bl = gw >> 10, w = gw & 1023;
    int lane = threadIdx.x & 63;
    const float* sp = scT + (size_t)gw * 1024;
    const f16* ap = aT + ((size_t)s * 1024 + w) * 1024;
    float xx[16];
    float m = NEGV;
#pragma unroll
    for (int k = 0; k < 16; k++) {
        int v = k * 64 + lane;
        float e = sp[v];
        xx[k] = ((float)ap[v] > 0.f) ? e : NEGV;
        m = fmaxf(m, xx[k]);
    }
#pragma unroll
    for (int off = 1; off < 64; off <<= 1) m = fmaxf(m, __shfl_xor(m, off));
    float ssum = 0.f;
#pragma unroll
    for (int k = 0; k < 16; k++) {
        xx[k] = __expf(xx[k] - m);
        ssum += xx[k];
    }
#pragma unroll
    for (int off = 1; off < 64; off <<= 1) ssum += __shfl_xor(ssum, off);
    float inv = 1.f / ssum;
    f16* op = attM + (((size_t)(bh * 2 + bl)) * 1024 + w) * 1024;
#pragma unroll
    for (int k = 0; k < 16; k++) op[k * 64 + lane] = (f16)(xx[k] * inv);
}

// ---------- colsum stage 1 ----------
template <int ORDER>
__global__ __launch_bounds__(256) void k_colsum1(
    const f16* __restrict__ aT, const f16* __restrict__ attT,
    const float* __restrict__ ra, const float* __restrict__ ratt,
    float* __restrict__ partial) {
    int u = blockIdx.y, rc = blockIdx.x;          // rc 0..15
    int t = threadIdx.x;
    int lane7 = t & 127, rh = t >> 7;
    int v0 = lane7 * 8;
    const f16* M = (u < 2) ? aT + (size_t)u * 1048576
                           : attT + (size_t)(u - 2) * 1048576;
    const float* rin = nullptr;
    if (ORDER) rin = (u < 2) ? ra + (size_t)u * 2048 : ratt + (size_t)(u - 2) * 2048;
    float acc[8] = {};
    int row0 = rc * 64 + rh * 32;
#pragma unroll 4
    for (int i = 0; i < 32; i++) {
        int row = row0 + i;
        f16x8 mv = *reinterpret_cast<const f16x8*>(M + (size_t)row * 1024 + v0);
        float sc = ORDER ? rin[row] : 1.f;
#pragma unroll
        for (int j = 0; j < 8; j++) acc[j] += (float)mv[j] * sc;
    }
    float* pp = partial + ((size_t)u * 32 + rc * 2 + rh) * 1024 + v0;
#pragma unroll
    for (int j = 0; j < 8; j++) pp[j] = acc[j];
}

// ---------- colsum stage 2 ----------
template <int ORDER>
__global__ void k_colsum2(const float* __restrict__ partial, float* __restrict__ ra,
                          float* __restrict__ ratt) {
    int u = blockIdx.x, t = threadIdx.x;
    for (int v = t; v < 1024; v += 256) {
        float s = 0.f;
#pragma unroll
        for (int k = 0; k < 32; k++) s += partial[((size_t)u * 32 + k) * 1024 + v];
        float* out = (u < 2) ? ra + (size_t)u * 2048 : ratt + (size_t)(u - 2) * 2048;
        out[ORDER * 1024 + v] = s;
    }
}

__global__ void k_feat13(const float* __restrict__ xl, const float* __restrict__ ra,
                         const float* __restrict__ ratt, float* __restrict__ feats) {
    int bd = blockIdx.x;
    int b = bd >> 6, d = bd & 63;
    const float* xp = xl + (size_t)bd * 1024;
    int t = threadIdx.x;
    float s[13];
#pragma unroll
    for (int i = 0; i < 13; i++) s[i] = 0.f;
    for (int v = t; v < 1024; v += 256) {
        float xv = xp[v];
        s[0] += xv;
#pragma unroll
        for (int ss = 0; ss < 2; ss++) {
            s[1 + ss * 6 + 0] += xv * ra[ss * 2048 + v];
            s[1 + ss * 6 + 1] += xv * ra[ss * 2048 + 1024 + v];
#pragma unroll
            for (int hh = 0; hh < 2; hh++) {
                const float* rb = ratt + (((size_t)(ss * 2 + hh) * 8 + b)) * 2048;
                s[1 + ss * 6 + 2 + hh * 2] += xv * rb[v];
                s[1 + ss * 6 + 3 + hh * 2] += xv * rb[1024 + v];
            }
        }
    }
    int wid = t >> 6, lane = t & 63;
#pragma unroll
    for (int i = 0; i < 13; i++)
#pragma unroll
        for (int off = 1; off < 64; off <<= 1) s[i] += __shfl_xor(s[i], off);
    __shared__ float red[13][4];
    if (lane == 0)
#pragma unroll
        for (int i = 0; i < 13; i++) red[i][wid] = s[i];
    __syncthreads();
    if (t < 13) {
        float tot = red[t][0] + red[t][1] + red[t][2] + red[t][3];
        feats[(size_t)b * 832 + t * 64 + d] = tot * (1.f / (1024.f * 12.f));
    }
}

__global__ void k_gate(const float* __restrict__ feats, const float* __restrict__ aw,
                       const float* __restrict__ ab, float* __restrict__ gate) {
    int b = blockIdx.x, t = threadIdx.x;
    __shared__ float lg[13];
    if (t < 13) {
        float s = ab[t];
        const float* f = feats + (size_t)b * 832;
        const float* w = aw + (size_t)t * 832;
        for (int k = 0; k < 832; k++) s += f[k] * w[k];
        lg[t] = s;
    }
    __syncthreads();
    if (t == 0) {
        float m = lg[0];
        for (int j = 1; j < 13; j++) m = fmaxf(m, lg[j]);
        float ss = 0.f;
        for (int j = 0; j < 13; j++) ss += __expf(lg[j] - m);
        float inv = 1.f / ss;
        for (int j = 0; j < 13; j++) gate[b * 13 + j] = __expf(lg[j] - m) * inv;
    }
}

// hacc init: hacc[b][r][w] = gate0 * XT (f16 x)
__global__ void k_hinit2(const f16* __restrict__ XT, const float* __restrict__ gate,
                         float* __restrict__ hacc) {
    size_t i8 = (size_t)blockIdx.x * 256 + threadIdx.x;   // element-octet index
    int b = (int)(i8 / 98304);                            // 786432/8 per b
    float g = gate[b * 13];
    f16x8 v = *reinterpret_cast<const f16x8*>(XT + i8 * 8);
    float4 o0 = {g * (float)v[0], g * (float)v[1], g * (float)v[2], g * (float)v[3]};
    float4 o1 = {g * (float)v[4], g * (float)v[5], g * (float)v[6], g * (float)v[7]};
    float4* dst = reinterpret_cast<float4*>(hacc + i8 * 8);
    dst[0] = o0; dst[1] = o1;
}

// final: out[b,o,n,l] = fb[o] + sum_d fw[o,d] * hacc[b][(d,l)][n]
__global__ __launch_bounds__(256) void k_final2(const float* __restrict__ hacc,
                                                const float* __restrict__ fw,
                                                const float* __restrict__ fb,
                                                float* __restrict__ out) {
    int nt = blockIdx.x, l = blockIdx.y, b = blockIdx.z;
    int t = threadIdx.x, nl = t & 63, q = t >> 6;        // q: o-quarter, wave-uniform
    int n = nt * 64 + nl;
    const float* fwp = fw + (size_t)q * 16 * 64;
    float acc[16];
#pragma unroll
    for (int oo = 0; oo < 16; oo++) acc[oo] = fb[q * 16 + oo];
    const float* hp = hacc + ((size_t)b * 768 + l) * 1024 + n;
#pragma unroll 4
    for (int d = 0; d < 64; d++) {
        float hv = hp[(size_t)d * 12 * 1024];
#pragma unroll
        for (int oo = 0; oo < 16; oo++) acc[oo] += fwp[oo * 64 + d] * hv;
    }
#pragma unroll
    for (int oo = 0; oo < 16; oo++) {
        int oidx = q * 16 + oo;
        out[(((size_t)b * 64 + oidx) * 1024 + n) * 12 + l] = acc[oo];
    }
}

// ================= launch ===================================================

extern "C" void kernel_launch(void* const* d_in, const int* in_sizes, int n_in,
                              void* d_out, int out_size, void* d_ws, size_t ws_size,
                              hipStream_t stream) {
    const float* x   = (const float*)d_in[0];
    const float* sup = (const float*)d_in[1];
    const float* nv1 = (const float*)d_in[2];
    const float* nv2 = (const float*)d_in[3];
    const float* kw  = (const float*)d_in[4];
    const float* kb  = (const float*)d_in[5];
    const float* qw  = (const float*)d_in[6];
    const float* qb  = (const float*)d_in[7];
    const float* aw  = (const float*)d_in[8];
    const float* ab  = (const float*)d_in[9];
    const float* fw  = (const float*)d_in[10];
    const float* fb  = (const float*)d_in[11];
    float* hout = (float*)d_out;

    float* wsf = (float*)d_ws;
    size_t o = 0;
    f16*   XT     = (f16*)(wsf + o);  o += 3145728;   // [8][768][1024] f16
    float* attReg = wsf + o;          o += 16777216;  // attT [4][8][1024][1024] f16
    f16*   attT   = (f16*)attReg;
    f16*   xT2    = (f16*)attReg;                     // overlay (dead before attT)
    f16*   aT     = (f16*)(wsf + o);  o += 1048576;   // [2][1024][1024] f16
    f16*   P1     = (f16*)(wsf + o);  o += 3145728;   // [8][768][1024] f16
    float* gate   = wsf + o;          o += 128;
    // ---- region overlaid by hacc after the gate is computed ----
    size_t region0 = o;
    float* scT    = wsf + o;          o += 2097152;   // [2][1024][1024] f32
    f16*   keysT  = (f16*)(wsf + o);  o += 2097152;   // [4][8][1024][128] f16
    f16*   kwb    = (f16*)(wsf + o);  o += 196608;    // [4][128][768] f16
    float* kwl    = wsf + o;          o += 32768;     // [4][128][64]
    float* tkq    = wsf + o;          o += 524288;    // [4][1024][128]
    float* xl     = wsf + o;          o += 524288;    // [8][64][1024]
    float* ra     = wsf + o;          o += 4096;      // [2][2][1024]
    float* ratt   = wsf + o;          o += 65536;     // [4][8][2][1024]
    float* feats  = wsf + o;          o += 6656;
    float* partial= wsf + o;          o += 1114112;   // [34][32][1024]
    float* hacc   = wsf + region0;                    // [8][768][1024] f32 (6291456)
    if (o - region0 < 6291456) o = region0 + 6291456; // ensure hacc fits
    if (ws_size < o * 4) return;

    k_xt<<<2048, 256, 0, stream>>>(x, XT, xl);
    k_xt2<<<dim3(16, 4, 8), 256, 0, stream>>>(x, xT2);
    k_wcvt<<<128, 256, 0, stream>>>(kw, qw, kwl, kwb);
    k_tkq<<<2048, 256, 0, stream>>>(kwl, nv1, nv2, kb, qb, tkq);
    k_acvt<<<dim3(16, 16, 2), 256, 0, stream>>>(sup, aT);

    k_kqgemm<<<dim3(8, 1, 32), 256, 0, stream>>>(xT2, kwb, tkq, keysT);

    for (int h = 0; h < 2; h++)
        for (int bh = 0; bh < 4; bh++) {
            k_scoregemm<<<dim3(8, 8, 2), 256, 0, stream>>>(keysT, scT, h, bh);
            for (int s = 0; s < 2; s++) {
                f16* attM = attT + (size_t)(s * 2 + h) * 8 * 1048576;
                k_softmax<<<512, 256, 0, stream>>>(scT, aT, attM, s, bh);
            }
        }

    k_colsum1<0><<<dim3(16, 34), 256, 0, stream>>>(aT, attT, ra, ratt, partial);
    k_colsum2<0><<<34, 256, 0, stream>>>(partial, ra, ratt);
    k_colsum1<1><<<dim3(16, 34), 256, 0, stream>>>(aT, attT, ra, ratt, partial);
    k_colsum2<1><<<34, 256, 0, stream>>>(partial, ra, ratt);
    k_feat13<<<512, 256, 0, stream>>>(xl, ra, ratt, feats);
    k_gate<<<8, 64, 0, stream>>>(feats, aw, ab, gate);

    // hacc accumulation phase (region buffers all dead now)
    k_hinit2<<<3072, 256, 0, stream>>>(XT, gate, hacc);

    for (int s = 0; s < 2; s++)
        for (int kind = 0; kind < 3; kind++) {
            const f16* B0;
            size_t bsB;
            if (kind == 0) { B0 = aT + (size_t)s * 1048576; bsB = 0; }
            else { B0 = attT + (size_t)((s * 2 + kind - 1) * 8) * 1048576; bsB = 1048576; }
            int g1 = 1 + s * 6 + 2 * kind;
            k_prop<true><<<dim3(8, 6, 8), 256, 0, stream>>>(XT, B0, bsB, P1, hacc, gate, g1);
            k_prop<false><<<dim3(8, 6, 8), 256, 0, stream>>>(P1, B0, bsB, (f16*)nullptr, hacc, gate, g1 + 1);
        }

    k_final2<<<dim3(16, 12, 8), 256, 0, stream>>>(hacc, fw, fb, hout);
}

// Round 5
// 659.867 us; speedup vs baseline: 6.4457x; 1.0093x over previous
//
#include <hip/hip_runtime.h>
#include <hip/hip_bf16.h>

#define BB 8
#define DD 64
#define NNODE 1024
#define LLL 12
#define EE 128
#define NEGV -9.0e15f

typedef _Float16 f16;
typedef _Float16 f16x8 __attribute__((ext_vector_type(8)));
typedef float f32x4 __attribute__((ext_vector_type(4)));

// ================= GEMM core helpers (128x128 tile, BK=64, 4 waves) =========

__device__ __forceinline__ void stage_tile(const char* g, int ld, char* lds, int t) {
    int wid = t >> 6, lane = t & 63;
#pragma unroll
    for (int it = 0; it < 4; it++) {
        int cbase = it * 256 + wid * 64;          // wave-uniform chunk base
        int c = cbase + lane;
        int row = c >> 3, p = c & 7;
        int gch = p ^ (row & 7);                  // inverse swizzle on SOURCE
        const char* src = g + (size_t)row * ld + gch * 16;
        char* dst = lds + (size_t)cbase * 16;     // wave-uniform; lane*16 implicit
        __builtin_amdgcn_global_load_lds(
            (const __attribute__((address_space(1))) unsigned int*)src,
            (__attribute__((address_space(3))) unsigned int*)dst, 16, 0, 0);
    }
}

__device__ __forceinline__ void mma_tile(const char* As, const char* Bs, int t,
                                         f32x4 acc[4][4]) {
    int lane = t & 63, wid = t >> 6;
    int wr = (wid >> 1) * 64, wc = (wid & 1) * 64;
    int lrow = lane & 15, lk = lane >> 4;
#pragma unroll
    for (int kk = 0; kk < 2; kk++) {
        f16x8 af[4], bf[4];
#pragma unroll
        for (int m = 0; m < 4; m++) {
            int row = wr + m * 16 + lrow;
            int p = (kk * 4 + lk) ^ (row & 7);    // swizzled read
            af[m] = *(const f16x8*)(As + row * 128 + p * 16);
        }
#pragma unroll
        for (int n = 0; n < 4; n++) {
            int row = wc + n * 16 + lrow;
            int p = (kk * 4 + lk) ^ (row & 7);
            bf[n] = *(const f16x8*)(Bs + row * 128 + p * 16);
        }
#pragma unroll
        for (int m = 0; m < 4; m++)
#pragma unroll
            for (int n = 0; n < 4; n++)
                acc[m][n] = __builtin_amdgcn_mfma_f32_16x16x32_f16(
                    af[m], bf[n], acc[m][n], 0, 0, 0);
    }
}

__device__ __forceinline__ void zero_acc(f32x4 acc[4][4]) {
#pragma unroll
    for (int m = 0; m < 4; m++)
#pragma unroll
        for (int n = 0; n < 4; n++)
#pragma unroll
            for (int q = 0; q < 4; q++) acc[m][n][q] = 0.f;
}

// ================= prep kernels =============================================

// XT[b][(d,l)][v] f16 + xl[b,d,v] = sum_l x
__global__ void k_xt(const float* __restrict__ x, f16* __restrict__ XT,
                     float* __restrict__ xl) {
    int i = blockIdx.x * 256 + threadIdx.x;       // (b,d,v)
    int v = i & 1023, d = (i >> 10) & 63, b = i >> 16;
    const float4* p = reinterpret_cast<const float4*>(x + (size_t)i * 12);
    float4 a = p[0], c = p[1], e = p[2];
    float vv[12] = {a.x, a.y, a.z, a.w, c.x, c.y, c.z, c.w, e.x, e.y, e.z, e.w};
    float ssum = 0.f;
    size_t base = ((size_t)b * 768) * 1024 + v;
    int r0 = d * 12;
#pragma unroll
    for (int l = 0; l < 12; l++) {
        ssum += vv[l];
        XT[base + (size_t)(r0 + l) * 1024] = (f16)vv[l];
    }
    xl[i] = ssum;
}

// xT2[b][n][(d,l)] f16 via LDS transpose of 16d x 64n tiles
__global__ __launch_bounds__(256) void k_xt2(const float* __restrict__ x,
                                             f16* __restrict__ xT2) {
    __shared__ f16 Ls[64][208];
    int b = blockIdx.z, d0 = blockIdx.y * 16, n0 = blockIdx.x * 64, t = threadIdx.x;
    for (int f = t; f < 3072; f += 256) {
        int dd = f / 192, rem = f - dd * 192, j = rem / 3, q = rem - j * 3;
        float4 v = *reinterpret_cast<const float4*>(
            x + (((size_t)(b * 64 + d0 + dd) * 1024) + n0 + j) * 12 + q * 4);
        f16* dst = &Ls[j][dd * 12 + q * 4];
        dst[0] = (f16)v.x; dst[1] = (f16)v.y; dst[2] = (f16)v.z; dst[3] = (f16)v.w;
    }
    __syncthreads();
    for (int c = t; c < 1536; c += 256) {
        int j = c / 24, p = c - j * 24;
        *reinterpret_cast<f16x8*>(
            xT2 + ((size_t)(b * 1024) + n0 + j) * 768 + d0 * 12 + p * 8) =
            *reinterpret_cast<const f16x8*>(&Ls[j][p * 8]);
    }
}

// kwb[var][e][768] f16, kwl[var][e][d] = sum_l w
__global__ void k_wcvt(const float* __restrict__ kw, const float* __restrict__ qw,
                       float* __restrict__ kwl, f16* __restrict__ kwb) {
    int i = blockIdx.x * 256 + threadIdx.x;       // (var,e,d)
    int d = i & 63, e = (i >> 6) & 127, var = i >> 13;
    const float* src = (var < 2 ? kw + (size_t)var * 98304
                                : qw + (size_t)(var - 2) * 98304) +
                       ((size_t)e * 64 + d) * 12;
    f16* dst = kwb + ((size_t)var * 128 + e) * 768 + d * 12;
    float ssum = 0.f;
#pragma unroll
    for (int l = 0; l < 12; l++) {
        float v = src[l];
        ssum += v;
        dst[l] = (f16)v;
    }
    kwl[i] = ssum;
}

// tkq[var][n][e] = sum_d kwl[var][e][d]*nv + bias[var][e]
__global__ void k_tkq(const float* __restrict__ kwl, const float* __restrict__ nv1,
                      const float* __restrict__ nv2, const float* __restrict__ kb,
                      const float* __restrict__ qb, float* __restrict__ tkq) {
    int i = blockIdx.x * 256 + threadIdx.x;       // (var,n,e)
    int e = i & 127, n = (i >> 7) & 1023, var = i >> 17;
    float ssum = (var < 2) ? kb[var * 128 + e] : qb[(var - 2) * 128 + e];
    const float* wl = kwl + ((size_t)var * 128 + e) * 64;
    if (var < 2) {
        const float* nvp = nv1 + (size_t)n * 64;
#pragma unroll 8
        for (int d = 0; d < 64; d++) ssum += wl[d] * nvp[d];
    } else {
#pragma unroll 8
        for (int d = 0; d < 64; d++) ssum += wl[d] * nv2[(size_t)d * 1024 + n];
    }
    tkq[i] = ssum;
}

// aT[s][w][v] f16 (transpose of support)
__global__ void k_acvt(const float* __restrict__ sup, f16* __restrict__ aT) {
    __shared__ float Ls[64][65];
    int s = blockIdx.z, v0 = blockIdx.y * 64, w0 = blockIdx.x * 64, t = threadIdx.x;
    int j = t & 63, i0 = t >> 6;
    for (int i = i0; i < 64; i += 4)
        Ls[i][j] = sup[((size_t)s * 1024 + v0 + i) * 1024 + w0 + j];
    __syncthreads();
    for (int i = i0; i < 64; i += 4)
        aT[((size_t)s * 1024 + w0 + i) * 1024 + v0 + j] = (f16)Ls[j][i];
}

// ================= MFMA GEMM kernels ========================================

// keysT[var][b][n][e] = sum_dl xT2[b][n][dl]*kwb[var][e][dl] + tkq[var][n][e]
__global__ __launch_bounds__(256) void k_kqgemm(const f16* __restrict__ xT2,
                                                const f16* __restrict__ kwb,
                                                const float* __restrict__ tkq,
                                                f16* __restrict__ keysT) {
    __shared__ char As[16384], Bs[16384];
    int z = blockIdx.z, var = z >> 3, b = z & 7;
    int nt = blockIdx.x, t = threadIdx.x;
    const char* Ag = (const char*)(xT2 + ((size_t)b * 1024 + nt * 128) * 768);
    const char* Bg = (const char*)(kwb + (size_t)var * 128 * 768);
    f32x4 acc[4][4];
    zero_acc(acc);
    for (int kt = 0; kt < 12; kt++) {
        stage_tile(Ag + kt * 128, 1536, As, t);
        stage_tile(Bg + kt * 128, 1536, Bs, t);
        __syncthreads();
        mma_tile(As, Bs, t, acc);
        __syncthreads();
    }
    int lane = t & 63, wid = t >> 6;
    int wr = (wid >> 1) * 64, wc = (wid & 1) * 64;
    int cn = lane & 15, rq = (lane >> 4) * 4;
#pragma unroll
    for (int m = 0; m < 4; m++)
#pragma unroll
        for (int q = 0; q < 4; q++) {
            int n_g = nt * 128 + wr + m * 16 + rq + q;
#pragma unroll
            for (int nn = 0; nn < 4; nn++) {
                int e = wc + nn * 16 + cn;
                float v = acc[m][nn][q] + tkq[((size_t)var * 1024 + n_g) * 128 + e];
                keysT[(((size_t)var * 8 + b) * 1024 + n_g) * 128 + e] = (f16)v;
            }
        }
}

// scT[bl][w][v] = relu(sum_e query[w,e]*keys[v,e]) for b = bh*2+bl
__global__ __launch_bounds__(256) void k_scoregemm(const f16* __restrict__ keysT,
                                                   float* __restrict__ scT,
                                                   int h, int bh) {
    __shared__ char As[16384], Bs[16384];
    int bl = blockIdx.z, b = bh * 2 + bl;
    int wt = blockIdx.y, vt = blockIdx.x, t = threadIdx.x;
    const char* Ag = (const char*)(keysT + (((size_t)(2 + h) * 8 + b) * 1024 + wt * 128) * 128);
    const char* Bg = (const char*)(keysT + (((size_t)h * 8 + b) * 1024 + vt * 128) * 128);
    f32x4 acc[4][4];
    zero_acc(acc);
    for (int kt = 0; kt < 2; kt++) {
        stage_tile(Ag + kt * 128, 256, As, t);
        stage_tile(Bg + kt * 128, 256, Bs, t);
        __syncthreads();
        mma_tile(As, Bs, t, acc);
        __syncthreads();
    }
    int lane = t & 63, wid = t >> 6;
    int wr = (wid >> 1) * 64, wc = (wid & 1) * 64;
    int cn = lane & 15, rq = (lane >> 4) * 4;
#pragma unroll
    for (int m = 0; m < 4; m++)
#pragma unroll
        for (int q = 0; q < 4; q++) {
            int w = wt * 128 + wr + m * 16 + rq + q;
#pragma unroll
            for (int nn = 0; nn < 4; nn++) {
                int v = vt * 128 + wc + nn * 16 + cn;
                scT[((size_t)bl * 1024 + w) * 1024 + v] = fmaxf(acc[m][nn][q], 0.f);
            }
        }
}

// out[r][w] = sum_v A[r][v] * MT[w][v];  hacc[b][r][w] += gate*out;  opt P1=f16(out)
template <bool WP1>
__global__ __launch_bounds__(256) void k_prop(const f16* __restrict__ A0,
                                              const f16* __restrict__ B0, size_t bsB,
                                              f16* __restrict__ P1,
                                              float* __restrict__ hacc,
                                              const float* __restrict__ gate, int gidx) {
    __shared__ char As[16384], Bs[16384];
    int b = blockIdx.z, rt = blockIdx.y, wt = blockIdx.x, t = threadIdx.x;
    const char* Ag = (const char*)(A0 + ((size_t)b * 768 + rt * 128) * 1024);
    const char* Bg = (const char*)(B0 + (size_t)b * bsB + (size_t)wt * 128 * 1024);
    f32x4 acc[4][4];
    zero_acc(acc);
    for (int kt = 0; kt < 16; kt++) {
        stage_tile(Ag + kt * 128, 2048, As, t);
        stage_tile(Bg + kt * 128, 2048, Bs, t);
        __syncthreads();
        mma_tile(As, Bs, t, acc);
        __syncthreads();
    }
    float gs = gate[b * 13 + gidx];
    int lane = t & 63, wid = t >> 6;
    int wr = (wid >> 1) * 64, wc = (wid & 1) * 64;
    int cn = lane & 15, rq = (lane >> 4) * 4;
#pragma unroll
    for (int m = 0; m < 4; m++)
#pragma unroll
        for (int q = 0; q < 4; q++) {
            int r = rt * 128 + wr + m * 16 + rq + q;
            size_t pbase = ((size_t)b * 768 + r) * 1024;
#pragma unroll
            for (int nn = 0; nn < 4; nn++) {
                int w = wt * 128 + wc + nn * 16 + cn;
                float val = acc[m][nn][q];
                if (WP1) P1[pbase + w] = (f16)val;
                hacc[pbase + w] += gs * val;
            }
        }
}

// ================= softmax / stats / gate ===================================

// fused both supports: read raw score row once, mask+softmax per s
__global__ void k_softmax2(const float* __restrict__ scT, const f16* __restrict__ aT,
                           f16* __restrict__ attT, int h, int bh) {
    int gw = blockIdx.x * 4 + (threadIdx.x >> 6);  // bl*1024 + w, gw in [0,2048)
    int bl = gw >> 10, w = gw & 1023;
    int lane = threadIdx.x & 63;
    const float* sp = scT + (size_t)gw * 1024;
    float e[16];
#pragma unroll
    for (int k = 0; k < 16; k++) e[k] = sp[k * 64 + lane];
#pragma unroll
    for (int s = 0; s < 2; s++) {
        const f16* ap = aT + ((size_t)s * 1024 + w) * 1024;
        float xx[16];
        float m = NEGV;
#pragma unroll
        for (int k = 0; k < 16; k++) {
            int v = k * 64 + lane;
            xx[k] = ((float)ap[v] > 0.f) ? e[k] : NEGV;
            m = fmaxf(m, xx[k]);
        }
#pragma unroll
        for (int off = 1; off < 64; off <<= 1) m = fmaxf(m, __shfl_xor(m, off));
        float ssum = 0.f;
#pragma unroll
        for (int k = 0; k < 16; k++) {
            xx[k] = __expf(xx[k] - m);
            ssum += xx[k];
        }
#pragma unroll
        for (int off = 1; off < 64; off <<= 1) ssum += __shfl_xor(ssum, off);
        float inv = 1.f / ssum;
        f16* op = attT + (size_t)(s * 2 + h) * 8 * 1048576 +
                  (((size_t)(bh * 2 + bl)) * 1024 + w) * 1024;
#pragma unroll
        for (int k = 0; k < 16; k++) op[k * 64 + lane] = (f16)(xx[k] * inv);
    }
}

// ---------- colsum stage 1 ----------
template <int ORDER>
__global__ __launch_bounds__(256) void k_colsum1(
    const f16* __restrict__ aT, const f16* __restrict__ attT,
    const float* __restrict__ ra, const float* __restrict__ ratt,
    float* __restrict__ partial) {
    int u = blockIdx.y, rc = blockIdx.x;          // rc 0..15
    int t = threadIdx.x;
    int lane7 = t & 127, rh = t >> 7;
    int v0 = lane7 * 8;
    const f16* M = (u < 2) ? aT + (size_t)u * 1048576
                           : attT + (size_t)(u - 2) * 1048576;
    const float* rin = nullptr;
    if (ORDER) rin = (u < 2) ? ra + (size_t)u * 2048 : ratt + (size_t)(u - 2) * 2048;
    float acc[8] = {};
    int row0 = rc * 64 + rh * 32;
#pragma unroll 4
    for (int i = 0; i < 32; i++) {
        int row = row0 + i;
        f16x8 mv = *reinterpret_cast<const f16x8*>(M + (size_t)row * 1024 + v0);
        float sc = ORDER ? rin[row] : 1.f;
#pragma unroll
        for (int j = 0; j < 8; j++) acc[j] += (float)mv[j] * sc;
    }
    float* pp = partial + ((size_t)u * 32 + rc * 2 + rh) * 1024 + v0;
#pragma unroll
    for (int j = 0; j < 8; j++) pp[j] = acc[j];
}

// ---------- colsum stage 2 ----------
template <int ORDER>
__global__ void k_colsum2(const float* __restrict__ partial, float* __restrict__ ra,
                          float* __restrict__ ratt) {
    int u = blockIdx.x, t = threadIdx.x;
    for (int v = t; v < 1024; v += 256) {
        float s = 0.f;
#pragma unroll
        for (int k = 0; k < 32; k++) s += partial[((size_t)u * 32 + k) * 1024 + v];
        float* out = (u < 2) ? ra + (size_t)u * 2048 : ratt + (size_t)(u - 2) * 2048;
        out[ORDER * 1024 + v] = s;
    }
}

__global__ void k_feat13(const float* __restrict__ xl, const float* __restrict__ ra,
                         const float* __restrict__ ratt, float* __restrict__ feats) {
    int bd = blockIdx.x;
    int b = bd >> 6, d = bd & 63;
    const float* xp = xl + (size_t)bd * 1024;
    int t = threadIdx.x;
    float s[13];
#pragma unroll
    for (int i = 0; i < 13; i++) s[i] = 0.f;
    for (int v = t; v < 1024; v += 256) {
        float xv = xp[v];
        s[0] += xv;
#pragma unroll
        for (int ss = 0; ss < 2; ss++) {
            s[1 + ss * 6 + 0] += xv * ra[ss * 2048 + v];
            s[1 + ss * 6 + 1] += xv * ra[ss * 2048 + 1024 + v];
#pragma unroll
            for (int hh = 0; hh < 2; hh++) {
                const float* rb = ratt + (((size_t)(ss * 2 + hh) * 8 + b)) * 2048;
                s[1 + ss * 6 + 2 + hh * 2] += xv * rb[v];
                s[1 + ss * 6 + 3 + hh * 2] += xv * rb[1024 + v];
            }
        }
    }
    int wid = t >> 6, lane = t & 63;
#pragma unroll
    for (int i = 0; i < 13; i++)
#pragma unroll
        for (int off = 1; off < 64; off <<= 1) s[i] += __shfl_xor(s[i], off);
    __shared__ float red[13][4];
    if (lane == 0)
#pragma unroll
        for (int i = 0; i < 13; i++) red[i][wid] = s[i];
    __syncthreads();
    if (t < 13) {
        float tot = red[t][0] + red[t][1] + red[t][2] + red[t][3];
        feats[(size_t)b * 832 + t * 64 + d] = tot * (1.f / (1024.f * 12.f));
    }
}

__global__ void k_gate(const float* __restrict__ feats, const float* __restrict__ aw,
                       const float* __restrict__ ab, float* __restrict__ gate) {
    int b = blockIdx.x, t = threadIdx.x;
    __shared__ float lg[13];
    if (t < 13) {
        float s = ab[t];
        const float* f = feats + (size_t)b * 832;
        const float* w = aw + (size_t)t * 832;
        for (int k = 0; k < 832; k++) s += f[k] * w[k];
        lg[t] = s;
    }
    __syncthreads();
    if (t == 0) {
        float m = lg[0];
        for (int j = 1; j < 13; j++) m = fmaxf(m, lg[j]);
        float ss = 0.f;
        for (int j = 0; j < 13; j++) ss += __expf(lg[j] - m);
        float inv = 1.f / ss;
        for (int j = 0; j < 13; j++) gate[b * 13 + j] = __expf(lg[j] - m) * inv;
    }
}

// hacc init: hacc[b][r][w] = gate0 * XT (f16 x)
__global__ void k_hinit2(const f16* __restrict__ XT, const float* __restrict__ gate,
                         float* __restrict__ hacc) {
    size_t i8 = (size_t)blockIdx.x * 256 + threadIdx.x;   // element-octet index
    int b = (int)(i8 / 98304);                            // 786432/8 per b
    float g = gate[b * 13];
    f16x8 v = *reinterpret_cast<const f16x8*>(XT + i8 * 8);
    float4 o0 = {g * (float)v[0], g * (float)v[1], g * (float)v[2], g * (float)v[3]};
    float4 o1 = {g * (float)v[4], g * (float)v[5], g * (float)v[6], g * (float)v[7]};
    float4* dst = reinterpret_cast<float4*>(hacc + i8 * 8);
    dst[0] = o0; dst[1] = o1;
}

// final: out[b,o,n,l] = fb[o] + sum_d fw[o,d] * hacc[b][(d,l)][n]
// fully-unrolled d-loop: 64 independent loads in flight per thread
__global__ __launch_bounds__(256) void k_final3(const float* __restrict__ hacc,
                                                const float* __restrict__ fw,
                                                const float* __restrict__ fb,
                                                float* __restrict__ out) {
    int nt = blockIdx.x, l = blockIdx.y, b = blockIdx.z;
    int t = threadIdx.x, nl = t & 63, q = t >> 6;        // q: o-quarter, wave-uniform
    int n = nt * 64 + nl;
    const float* hp = hacc + ((size_t)b * 768 + l) * 1024 + n;
    float hv[64];
#pragma unroll
    for (int d = 0; d < 64; d++) hv[d] = hp[(size_t)d * 12288];
#pragma unroll
    for (int oo = 0; oo < 16; oo++) {
        int oidx = q * 16 + oo;
        const float* fwp = fw + (size_t)oidx * 64;
        float acc = fb[oidx];
#pragma unroll
        for (int d = 0; d < 64; d++) acc += fwp[d] * hv[d];
        out[(((size_t)b * 64 + oidx) * 1024 + n) * 12 + l] = acc;
    }
}

// ================= launch ===================================================

extern "C" void kernel_launch(void* const* d_in, const int* in_sizes, int n_in,
                              void* d_out, int out_size, void* d_ws, size_t ws_size,
                              hipStream_t stream) {
    const float* x   = (const float*)d_in[0];
    const float* sup = (const float*)d_in[1];
    const float* nv1 = (const float*)d_in[2];
    const float* nv2 = (const float*)d_in[3];
    const float* kw  = (const float*)d_in[4];
    const float* kb  = (const float*)d_in[5];
    const float* qw  = (const float*)d_in[6];
    const float* qb  = (const float*)d_in[7];
    const float* aw  = (const float*)d_in[8];
    const float* ab  = (const float*)d_in[9];
    const float* fw  = (const float*)d_in[10];
    const float* fb  = (const float*)d_in[11];
    float* hout = (float*)d_out;

    float* wsf = (float*)d_ws;
    size_t o = 0;
    f16*   XT     = (f16*)(wsf + o);  o += 3145728;   // [8][768][1024] f16
    float* attReg = wsf + o;          o += 16777216;  // attT [4][8][1024][1024] f16
    f16*   attT   = (f16*)attReg;
    f16*   xT2    = (f16*)attReg;                     // overlay (dead before attT)
    f16*   aT     = (f16*)(wsf + o);  o += 1048576;   // [2][1024][1024] f16
    f16*   P1     = (f16*)(wsf + o);  o += 3145728;   // [8][768][1024] f16
    float* gate   = wsf + o;          o += 128;
    // ---- region overlaid by hacc after the gate is computed ----
    size_t region0 = o;
    float* scT    = wsf + o;          o += 2097152;   // [2][1024][1024] f32
    f16*   keysT  = (f16*)(wsf + o);  o += 2097152;   // [4][8][1024][128] f16
    f16*   kwb    = (f16*)(wsf + o);  o += 196608;    // [4][128][768] f16
    float* kwl    = wsf + o;          o += 32768;     // [4][128][64]
    float* tkq    = wsf + o;          o += 524288;    // [4][1024][128]
    float* xl     = wsf + o;          o += 524288;    // [8][64][1024]
    float* ra     = wsf + o;          o += 4096;      // [2][2][1024]
    float* ratt   = wsf + o;          o += 65536;     // [4][8][2][1024]
    float* feats  = wsf + o;          o += 6656;
    float* partial= wsf + o;          o += 1114112;   // [34][32][1024]
    float* hacc   = wsf + region0;                    // [8][768][1024] f32 (6291456)
    if (o - region0 < 6291456) o = region0 + 6291456; // ensure hacc fits
    if (ws_size < o * 4) return;

    k_xt<<<2048, 256, 0, stream>>>(x, XT, xl);
    k_xt2<<<dim3(16, 4, 8), 256, 0, stream>>>(x, xT2);
    k_wcvt<<<128, 256, 0, stream>>>(kw, qw, kwl, kwb);
    k_tkq<<<2048, 256, 0, stream>>>(kwl, nv1, nv2, kb, qb, tkq);
    k_acvt<<<dim3(16, 16, 2), 256, 0, stream>>>(sup, aT);

    k_kqgemm<<<dim3(8, 1, 32), 256, 0, stream>>>(xT2, kwb, tkq, keysT);

    for (int h = 0; h < 2; h++)
        for (int bh = 0; bh < 4; bh++) {
            k_scoregemm<<<dim3(8, 8, 2), 256, 0, stream>>>(keysT, scT, h, bh);
            k_softmax2<<<512, 256, 0, stream>>>(scT, aT, attT, h, bh);
        }

    k_colsum1<0><<<dim3(16, 34), 256, 0, stream>>>(aT, attT, ra, ratt, partial);
    k_colsum2<0><<<34, 256, 0, stream>>>(partial, ra, ratt);
    k_colsum1<1><<<dim3(16, 34), 256, 0, stream>>>(aT, attT, ra, ratt, partial);
    k_colsum2<1><<<34, 256, 0, stream>>>(partial, ra, ratt);
    k_feat13<<<512, 256, 0, stream>>>(xl, ra, ratt, feats);
    k_gate<<<8, 64, 0, stream>>>(feats, aw, ab, gate);

    // hacc accumulation phase (region buffers all dead now)
    k_hinit2<<<3072, 256, 0, stream>>>(XT, gate, hacc);

    for (int s = 0; s < 2; s++)
        for (int kind = 0; kind < 3; kind++) {
            const f16* B0;
            size_t bsB;
            if (kind == 0) { B0 = aT + (size_t)s * 1048576; bsB = 0; }
            else { B0 = attT + (size_t)((s * 2 + kind - 1) * 8) * 1048576; bsB = 1048576; }
            int g1 = 1 + s * 6 + 2 * kind;
            k_prop<true><<<dim3(8, 6, 8), 256, 0, stream>>>(XT, B0, bsB, P1, hacc, gate, g1);
            k_prop<false><<<dim3(8, 6, 8), 256, 0, stream>>>(P1, B0, bsB, (f16*)nullptr, hacc, gate, g1 + 1);
        }

    k_final3<<<dim3(16, 12, 8), 256, 0, stream>>>(hacc, fw, fb, hout);
}

// Round 6
// 612.708 us; speedup vs baseline: 6.9418x; 1.0770x over previous
//
#include <hip/hip_runtime.h>
#include <hip/hip_bf16.h>

#define BB 8
#define DD 64
#define NNODE 1024
#define LLL 12
#define EE 128
#define NEGV -9.0e15f

typedef _Float16 f16;
typedef _Float16 f16x8 __attribute__((ext_vector_type(8)));
typedef float f32x4 __attribute__((ext_vector_type(4)));

// ================= GEMM core helpers (128x128 tile, BK=64, 4 waves) =========

__device__ __forceinline__ void stage_tile(const char* g, int ld, char* lds, int t) {
    int wid = t >> 6, lane = t & 63;
#pragma unroll
    for (int it = 0; it < 4; it++) {
        int cbase = it * 256 + wid * 64;          // wave-uniform chunk base
        int c = cbase + lane;
        int row = c >> 3, p = c & 7;
        int gch = p ^ (row & 7);                  // inverse swizzle on SOURCE
        const char* src = g + (size_t)row * ld + gch * 16;
        char* dst = lds + (size_t)cbase * 16;     // wave-uniform; lane*16 implicit
        __builtin_amdgcn_global_load_lds(
            (const __attribute__((address_space(1))) unsigned int*)src,
            (__attribute__((address_space(3))) unsigned int*)dst, 16, 0, 0);
    }
}

__device__ __forceinline__ void mma_tile(const char* As, const char* Bs, int t,
                                         f32x4 acc[4][4]) {
    int lane = t & 63, wid = t >> 6;
    int wr = (wid >> 1) * 64, wc = (wid & 1) * 64;
    int lrow = lane & 15, lk = lane >> 4;
#pragma unroll
    for (int kk = 0; kk < 2; kk++) {
        f16x8 af[4], bf[4];
#pragma unroll
        for (int m = 0; m < 4; m++) {
            int row = wr + m * 16 + lrow;
            int p = (kk * 4 + lk) ^ (row & 7);    // swizzled read
            af[m] = *(const f16x8*)(As + row * 128 + p * 16);
        }
#pragma unroll
        for (int n = 0; n < 4; n++) {
            int row = wc + n * 16 + lrow;
            int p = (kk * 4 + lk) ^ (row & 7);
            bf[n] = *(const f16x8*)(Bs + row * 128 + p * 16);
        }
#pragma unroll
        for (int m = 0; m < 4; m++)
#pragma unroll
            for (int n = 0; n < 4; n++)
                acc[m][n] = __builtin_amdgcn_mfma_f32_16x16x32_f16(
                    af[m], bf[n], acc[m][n], 0, 0, 0);
    }
}

__device__ __forceinline__ void zero_acc(f32x4 acc[4][4]) {
#pragma unroll
    for (int m = 0; m < 4; m++)
#pragma unroll
        for (int n = 0; n < 4; n++)
#pragma unroll
            for (int q = 0; q < 4; q++) acc[m][n][q] = 0.f;
}

// ================= prep kernels =============================================

// XT[b][(d,l)][v] f16 + xl[b,d,v] = sum_l x
__global__ void k_xt(const float* __restrict__ x, f16* __restrict__ XT,
                     float* __restrict__ xl) {
    int i = blockIdx.x * 256 + threadIdx.x;       // (b,d,v)
    int v = i & 1023, d = (i >> 10) & 63, b = i >> 16;
    const float4* p = reinterpret_cast<const float4*>(x + (size_t)i * 12);
    float4 a = p[0], c = p[1], e = p[2];
    float vv[12] = {a.x, a.y, a.z, a.w, c.x, c.y, c.z, c.w, e.x, e.y, e.z, e.w};
    float ssum = 0.f;
    size_t base = ((size_t)b * 768) * 1024 + v;
    int r0 = d * 12;
#pragma unroll
    for (int l = 0; l < 12; l++) {
        ssum += vv[l];
        XT[base + (size_t)(r0 + l) * 1024] = (f16)vv[l];
    }
    xl[i] = ssum;
}

// xT2[b][n][(d,l)] f16 via LDS transpose of 16d x 64n tiles
__global__ __launch_bounds__(256) void k_xt2(const float* __restrict__ x,
                                             f16* __restrict__ xT2) {
    __shared__ f16 Ls[64][208];
    int b = blockIdx.z, d0 = blockIdx.y * 16, n0 = blockIdx.x * 64, t = threadIdx.x;
    for (int f = t; f < 3072; f += 256) {
        int dd = f / 192, rem = f - dd * 192, j = rem / 3, q = rem - j * 3;
        float4 v = *reinterpret_cast<const float4*>(
            x + (((size_t)(b * 64 + d0 + dd) * 1024) + n0 + j) * 12 + q * 4);
        f16* dst = &Ls[j][dd * 12 + q * 4];
        dst[0] = (f16)v.x; dst[1] = (f16)v.y; dst[2] = (f16)v.z; dst[3] = (f16)v.w;
    }
    __syncthreads();
    for (int c = t; c < 1536; c += 256) {
        int j = c / 24, p = c - j * 24;
        *reinterpret_cast<f16x8*>(
            xT2 + ((size_t)(b * 1024) + n0 + j) * 768 + d0 * 12 + p * 8) =
            *reinterpret_cast<const f16x8*>(&Ls[j][p * 8]);
    }
}

// kwb[var][e][768] f16, kwl[var][e][d] = sum_l w
__global__ void k_wcvt(const float* __restrict__ kw, const float* __restrict__ qw,
                       float* __restrict__ kwl, f16* __restrict__ kwb) {
    int i = blockIdx.x * 256 + threadIdx.x;       // (var,e,d)
    int d = i & 63, e = (i >> 6) & 127, var = i >> 13;
    const float* src = (var < 2 ? kw + (size_t)var * 98304
                                : qw + (size_t)(var - 2) * 98304) +
                       ((size_t)e * 64 + d) * 12;
    f16* dst = kwb + ((size_t)var * 128 + e) * 768 + d * 12;
    float ssum = 0.f;
#pragma unroll
    for (int l = 0; l < 12; l++) {
        float v = src[l];
        ssum += v;
        dst[l] = (f16)v;
    }
    kwl[i] = ssum;
}

// tkq[var][n][e] = sum_d kwl[var][e][d]*nv + bias[var][e]
__global__ void k_tkq(const float* __restrict__ kwl, const float* __restrict__ nv1,
                      const float* __restrict__ nv2, const float* __restrict__ kb,
                      const float* __restrict__ qb, float* __restrict__ tkq) {
    int i = blockIdx.x * 256 + threadIdx.x;       // (var,n,e)
    int e = i & 127, n = (i >> 7) & 1023, var = i >> 17;
    float ssum = (var < 2) ? kb[var * 128 + e] : qb[(var - 2) * 128 + e];
    const float* wl = kwl + ((size_t)var * 128 + e) * 64;
    if (var < 2) {
        const float* nvp = nv1 + (size_t)n * 64;
#pragma unroll 8
        for (int d = 0; d < 64; d++) ssum += wl[d] * nvp[d];
    } else {
#pragma unroll 8
        for (int d = 0; d < 64; d++) ssum += wl[d] * nv2[(size_t)d * 1024 + n];
    }
    tkq[i] = ssum;
}

// aT[s][w][v] f16 (transpose of support)
__global__ void k_acvt(const float* __restrict__ sup, f16* __restrict__ aT) {
    __shared__ float Ls[64][65];
    int s = blockIdx.z, v0 = blockIdx.y * 64, w0 = blockIdx.x * 64, t = threadIdx.x;
    int j = t & 63, i0 = t >> 6;
    for (int i = i0; i < 64; i += 4)
        Ls[i][j] = sup[((size_t)s * 1024 + v0 + i) * 1024 + w0 + j];
    __syncthreads();
    for (int i = i0; i < 64; i += 4)
        aT[((size_t)s * 1024 + w0 + i) * 1024 + v0 + j] = (f16)Ls[j][i];
}

// ================= MFMA GEMM kernels ========================================

// keysT[var][b][n][e] = sum_dl xT2[b][n][dl]*kwb[var][e][dl] + tkq[var][n][e]
__global__ __launch_bounds__(256) void k_kqgemm(const f16* __restrict__ xT2,
                                                const f16* __restrict__ kwb,
                                                const float* __restrict__ tkq,
                                                f16* __restrict__ keysT) {
    __shared__ char As[16384], Bs[16384];
    int z = blockIdx.z, var = z >> 3, b = z & 7;
    int nt = blockIdx.x, t = threadIdx.x;
    const char* Ag = (const char*)(xT2 + ((size_t)b * 1024 + nt * 128) * 768);
    const char* Bg = (const char*)(kwb + (size_t)var * 128 * 768);
    f32x4 acc[4][4];
    zero_acc(acc);
    for (int kt = 0; kt < 12; kt++) {
        stage_tile(Ag + kt * 128, 1536, As, t);
        stage_tile(Bg + kt * 128, 1536, Bs, t);
        __syncthreads();
        mma_tile(As, Bs, t, acc);
        __syncthreads();
    }
    int lane = t & 63, wid = t >> 6;
    int wr = (wid >> 1) * 64, wc = (wid & 1) * 64;
    int cn = lane & 15, rq = (lane >> 4) * 4;
#pragma unroll
    for (int m = 0; m < 4; m++)
#pragma unroll
        for (int q = 0; q < 4; q++) {
            int n_g = nt * 128 + wr + m * 16 + rq + q;
#pragma unroll
            for (int nn = 0; nn < 4; nn++) {
                int e = wc + nn * 16 + cn;
                float v = acc[m][nn][q] + tkq[((size_t)var * 1024 + n_g) * 128 + e];
                keysT[(((size_t)var * 8 + b) * 1024 + n_g) * 128 + e] = (f16)v;
            }
        }
}

// scT[bl][w][v] = relu(sum_e query[w,e]*keys[v,e]) for b = bh*4+bl
__global__ __launch_bounds__(256) void k_scoregemm(const f16* __restrict__ keysT,
                                                   float* __restrict__ scT,
                                                   int h, int bh) {
    __shared__ char As[16384], Bs[16384];
    int bl = blockIdx.z, b = bh * 4 + bl;
    int wt = blockIdx.y, vt = blockIdx.x, t = threadIdx.x;
    const char* Ag = (const char*)(keysT + (((size_t)(2 + h) * 8 + b) * 1024 + wt * 128) * 128);
    const char* Bg = (const char*)(keysT + (((size_t)h * 8 + b) * 1024 + vt * 128) * 128);
    f32x4 acc[4][4];
    zero_acc(acc);
    for (int kt = 0; kt < 2; kt++) {
        stage_tile(Ag + kt * 128, 256, As, t);
        stage_tile(Bg + kt * 128, 256, Bs, t);
        __syncthreads();
        mma_tile(As, Bs, t, acc);
        __syncthreads();
    }
    int lane = t & 63, wid = t >> 6;
    int wr = (wid >> 1) * 64, wc = (wid & 1) * 64;
    int cn = lane & 15, rq = (lane >> 4) * 4;
#pragma unroll
    for (int m = 0; m < 4; m++)
#pragma unroll
        for (int q = 0; q < 4; q++) {
            int w = wt * 128 + wr + m * 16 + rq + q;
#pragma unroll
            for (int nn = 0; nn < 4; nn++) {
                int v = vt * 128 + wc + nn * 16 + cn;
                scT[((size_t)bl * 1024 + w) * 1024 + v] = fmaxf(acc[m][nn][q], 0.f);
            }
        }
}

// prop order-1: P1[b][r][w] = f16( sum_v ZT[b][r][v] * MT[w][v] )   (no hacc)
__global__ __launch_bounds__(256) void k_prop1g(const f16* __restrict__ A0,
                                                const f16* __restrict__ B0, size_t bsB,
                                                f16* __restrict__ P1) {
    __shared__ char As[16384], Bs[16384];
    int b = blockIdx.z, rt = blockIdx.y, wt = blockIdx.x, t = threadIdx.x;
    const char* Ag = (const char*)(A0 + ((size_t)b * 768 + rt * 128) * 1024);
    const char* Bg = (const char*)(B0 + (size_t)b * bsB + (size_t)wt * 128 * 1024);
    f32x4 acc[4][4];
    zero_acc(acc);
    for (int kt = 0; kt < 16; kt++) {
        stage_tile(Ag + kt * 128, 2048, As, t);
        stage_tile(Bg + kt * 128, 2048, Bs, t);
        __syncthreads();
        mma_tile(As, Bs, t, acc);
        __syncthreads();
    }
    int lane = t & 63, wid = t >> 6;
    int wr = (wid >> 1) * 64, wc = (wid & 1) * 64;
    int cn = lane & 15, rq = (lane >> 4) * 4;
#pragma unroll
    for (int m = 0; m < 4; m++)
#pragma unroll
        for (int q = 0; q < 4; q++) {
            int r = rt * 128 + wr + m * 16 + rq + q;
            size_t pbase = ((size_t)b * 768 + r) * 1024;
#pragma unroll
            for (int nn = 0; nn < 4; nn++) {
                int w = wt * 128 + wc + nn * 16 + cn;
                P1[pbase + w] = (f16)acc[m][nn][q];
            }
        }
}

// prop order-2: val = P1·M ; hacc += g1*P1[r][w] + g2*val
__global__ __launch_bounds__(256) void k_prop2g(const f16* __restrict__ P1,
                                                const f16* __restrict__ B0, size_t bsB,
                                                float* __restrict__ hacc,
                                                const float* __restrict__ gate, int gidx) {
    __shared__ char As[16384], Bs[16384];
    int b = blockIdx.z, rt = blockIdx.y, wt = blockIdx.x, t = threadIdx.x;
    const char* Ag = (const char*)(P1 + ((size_t)b * 768 + rt * 128) * 1024);
    const char* Bg = (const char*)(B0 + (size_t)b * bsB + (size_t)wt * 128 * 1024);
    f32x4 acc[4][4];
    zero_acc(acc);
    for (int kt = 0; kt < 16; kt++) {
        stage_tile(Ag + kt * 128, 2048, As, t);
        stage_tile(Bg + kt * 128, 2048, Bs, t);
        __syncthreads();
        mma_tile(As, Bs, t, acc);
        __syncthreads();
    }
    float g1 = gate[b * 13 + gidx], g2 = gate[b * 13 + gidx + 1];
    int lane = t & 63, wid = t >> 6;
    int wr = (wid >> 1) * 64, wc = (wid & 1) * 64;
    int cn = lane & 15, rq = (lane >> 4) * 4;
#pragma unroll
    for (int m = 0; m < 4; m++)
#pragma unroll
        for (int q = 0; q < 4; q++) {
            int r = rt * 128 + wr + m * 16 + rq + q;
            size_t pbase = ((size_t)b * 768 + r) * 1024;
#pragma unroll
            for (int nn = 0; nn < 4; nn++) {
                int w = wt * 128 + wc + nn * 16 + cn;
                float p1v = (float)P1[pbase + w];
                hacc[pbase + w] += g1 * p1v + g2 * acc[m][nn][q];
            }
        }
}

// ================= softmax / stats / gate ===================================

// fused both supports: read raw score row once, mask+softmax per s (4 b's)
__global__ void k_softmax2(const float* __restrict__ scT, const f16* __restrict__ aT,
                           f16* __restrict__ attT, int h, int bh) {
    int gw = blockIdx.x * 4 + (threadIdx.x >> 6);  // bl*1024 + w, gw in [0,4096)
    int bl = gw >> 10, w = gw & 1023;
    int lane = threadIdx.x & 63;
    const float* sp = scT + (size_t)gw * 1024;
    float e[16];
#pragma unroll
    for (int k = 0; k < 16; k++) e[k] = sp[k * 64 + lane];
#pragma unroll
    for (int s = 0; s < 2; s++) {
        const f16* ap = aT + ((size_t)s * 1024 + w) * 1024;
        float xx[16];
        float m = NEGV;
#pragma unroll
        for (int k = 0; k < 16; k++) {
            int v = k * 64 + lane;
            xx[k] = ((float)ap[v] > 0.f) ? e[k] : NEGV;
            m = fmaxf(m, xx[k]);
        }
#pragma unroll
        for (int off = 1; off < 64; off <<= 1) m = fmaxf(m, __shfl_xor(m, off));
        float ssum = 0.f;
#pragma unroll
        for (int k = 0; k < 16; k++) {
            xx[k] = __expf(xx[k] - m);
            ssum += xx[k];
        }
#pragma unroll
        for (int off = 1; off < 64; off <<= 1) ssum += __shfl_xor(ssum, off);
        float inv = 1.f / ssum;
        f16* op = attT + (size_t)(s * 2 + h) * 8 * 1048576 +
                  (((size_t)(bh * 4 + bl)) * 1024 + w) * 1024;
#pragma unroll
        for (int k = 0; k < 16; k++) op[k * 64 + lane] = (f16)(xx[k] * inv);
    }
}

// ---------- colsum stage 1 ----------
template <int ORDER>
__global__ __launch_bounds__(256) void k_colsum1(
    const f16* __restrict__ aT, const f16* __restrict__ attT,
    const float* __restrict__ ra, const float* __restrict__ ratt,
    float* __restrict__ partial) {
    int u = blockIdx.y, rc = blockIdx.x;          // rc 0..15
    int t = threadIdx.x;
    int lane7 = t & 127, rh = t >> 7;
    int v0 = lane7 * 8;
    const f16* M = (u < 2) ? aT + (size_t)u * 1048576
                           : attT + (size_t)(u - 2) * 1048576;
    const float* rin = nullptr;
    if (ORDER) rin = (u < 2) ? ra + (size_t)u * 2048 : ratt + (size_t)(u - 2) * 2048;
    float acc[8] = {};
    int row0 = rc * 64 + rh * 32;
#pragma unroll 4
    for (int i = 0; i < 32; i++) {
        int row = row0 + i;
        f16x8 mv = *reinterpret_cast<const f16x8*>(M + (size_t)row * 1024 + v0);
        float sc = ORDER ? rin[row] : 1.f;
#pragma unroll
        for (int j = 0; j < 8; j++) acc[j] += (float)mv[j] * sc;
    }
    float* pp = partial + ((size_t)u * 32 + rc * 2 + rh) * 1024 + v0;
#pragma unroll
    for (int j = 0; j < 8; j++) pp[j] = acc[j];
}

// ---------- colsum stage 2 ----------
template <int ORDER>
__global__ void k_colsum2(const float* __restrict__ partial, float* __restrict__ ra,
                          float* __restrict__ ratt) {
    int u = blockIdx.x, t = threadIdx.x;
    for (int v = t; v < 1024; v += 256) {
        float s = 0.f;
#pragma unroll
        for (int k = 0; k < 32; k++) s += partial[((size_t)u * 32 + k) * 1024 + v];
        float* out = (u < 2) ? ra + (size_t)u * 2048 : ratt + (size_t)(u - 2) * 2048;
        out[ORDER * 1024 + v] = s;
    }
}

__global__ void k_feat13(const float* __restrict__ xl, const float* __restrict__ ra,
                         const float* __restrict__ ratt, float* __restrict__ feats) {
    int bd = blockIdx.x;
    int b = bd >> 6, d = bd & 63;
    const float* xp = xl + (size_t)bd * 1024;
    int t = threadIdx.x;
    float s[13];
#pragma unroll
    for (int i = 0; i < 13; i++) s[i] = 0.f;
    for (int v = t; v < 1024; v += 256) {
        float xv = xp[v];
        s[0] += xv;
#pragma unroll
        for (int ss = 0; ss < 2; ss++) {
            s[1 + ss * 6 + 0] += xv * ra[ss * 2048 + v];
            s[1 + ss * 6 + 1] += xv * ra[ss * 2048 + 1024 + v];
#pragma unroll
            for (int hh = 0; hh < 2; hh++) {
                const float* rb = ratt + (((size_t)(ss * 2 + hh) * 8 + b)) * 2048;
                s[1 + ss * 6 + 2 + hh * 2] += xv * rb[v];
                s[1 + ss * 6 + 3 + hh * 2] += xv * rb[1024 + v];
            }
        }
    }
    int wid = t >> 6, lane = t & 63;
#pragma unroll
    for (int i = 0; i < 13; i++)
#pragma unroll
        for (int off = 1; off < 64; off <<= 1) s[i] += __shfl_xor(s[i], off);
    __shared__ float red[13][4];
    if (lane == 0)
#pragma unroll
        for (int i = 0; i < 13; i++) red[i][wid] = s[i];
    __syncthreads();
    if (t < 13) {
        float tot = red[t][0] + red[t][1] + red[t][2] + red[t][3];
        feats[(size_t)b * 832 + t * 64 + d] = tot * (1.f / (1024.f * 12.f));
    }
}

__global__ void k_gate(const float* __restrict__ feats, const float* __restrict__ aw,
                       const float* __restrict__ ab, float* __restrict__ gate) {
    int b = blockIdx.x, t = threadIdx.x;
    __shared__ float lg[13];
    if (t < 13) {
        float s = ab[t];
        const float* f = feats + (size_t)b * 832;
        const float* w = aw + (size_t)t * 832;
        for (int k = 0; k < 832; k++) s += f[k] * w[k];
        lg[t] = s;
    }
    __syncthreads();
    if (t == 0) {
        float m = lg[0];
        for (int j = 1; j < 13; j++) m = fmaxf(m, lg[j]);
        float ss = 0.f;
        for (int j = 0; j < 13; j++) ss += __expf(lg[j] - m);
        float inv = 1.f / ss;
        for (int j = 0; j < 13; j++) gate[b * 13 + j] = __expf(lg[j] - m) * inv;
    }
}

// ---------- z-projection, IN PLACE on XT: ZT[b][(o,l)][n] = sum_d fw[o][d]*XT[b][(d,l)][n]
// Block (nt,l,b): reads rows {d*12+l} at n-slice, writes rows {o*12+l} at same slice.
// One barrier separates all reads from all writes (same footprint, block-local).
__global__ __launch_bounds__(256) void k_zt(f16* __restrict__ XT,
                                            const float* __restrict__ fw) {
    int nt = blockIdx.x, l = blockIdx.y, b = blockIdx.z;
    int t = threadIdx.x, lane = t & 63, q = t >> 6;
    int n = nt * 64 + lane;
    f16* base = XT + (size_t)b * 768 * 1024 + n;
    float acc[16];
#pragma unroll
    for (int i = 0; i < 16; i++) acc[i] = 0.f;
#pragma unroll 4
    for (int d = 0; d < 64; d++) {
        float xv = (float)base[(size_t)(d * 12 + l) * 1024];
#pragma unroll
        for (int i = 0; i < 16; i++)
            acc[i] += fw[(q * 16 + i) * 64 + d] * xv;   // wave-uniform -> s_load
    }
    __syncthreads();
#pragma unroll
    for (int i = 0; i < 16; i++)
        base[(size_t)((q * 16 + i) * 12 + l) * 1024] = (f16)acc[i];
}

// hacc init: hacc[b][r][w] = gate0 * ZT
__global__ void k_hinit2(const f16* __restrict__ ZT, const float* __restrict__ gate,
                         float* __restrict__ hacc) {
    size_t i8 = (size_t)blockIdx.x * 256 + threadIdx.x;   // element-octet index
    int b = (int)(i8 / 98304);                            // 786432/8 per b
    float g = gate[b * 13];
    f16x8 v = *reinterpret_cast<const f16x8*>(ZT + i8 * 8);
    float4 o0 = {g * (float)v[0], g * (float)v[1], g * (float)v[2], g * (float)v[3]};
    float4 o1 = {g * (float)v[4], g * (float)v[5], g * (float)v[6], g * (float)v[7]};
    float4* dst = reinterpret_cast<float4*>(hacc + i8 * 8);
    dst[0] = o0; dst[1] = o1;
}

// final: out[b,o,n,l] = hacc[b][(o,l)][n] + fb[o]  (pure layout + bias)
__global__ void k_biasout(const float* __restrict__ hacc, const float* __restrict__ fb,
                          float* __restrict__ out) {
    int idx = blockIdx.x * 256 + threadIdx.x;     // (b,o,n), n fastest
    int n = idx & 1023, o = (idx >> 10) & 63, b = idx >> 16;
    float fbv = fb[o];
    float v[12];
#pragma unroll
    for (int l = 0; l < 12; l++)
        v[l] = hacc[((size_t)b * 768 + o * 12 + l) * 1024 + n] + fbv;
    float4* dst = reinterpret_cast<float4*>(out + (((size_t)b * 64 + o) * 1024 + n) * 12);
    float4 o0 = {v[0], v[1], v[2], v[3]};
    float4 o1 = {v[4], v[5], v[6], v[7]};
    float4 o2 = {v[8], v[9], v[10], v[11]};
    dst[0] = o0; dst[1] = o1; dst[2] = o2;
}

// ================= launch ===================================================

extern "C" void kernel_launch(void* const* d_in, const int* in_sizes, int n_in,
                              void* d_out, int out_size, void* d_ws, size_t ws_size,
                              hipStream_t stream) {
    const float* x   = (const float*)d_in[0];
    const float* sup = (const float*)d_in[1];
    const float* nv1 = (const float*)d_in[2];
    const float* nv2 = (const float*)d_in[3];
    const float* kw  = (const float*)d_in[4];
    const float* kb  = (const float*)d_in[5];
    const float* qw  = (const float*)d_in[6];
    const float* qb  = (const float*)d_in[7];
    const float* aw  = (const float*)d_in[8];
    const float* ab  = (const float*)d_in[9];
    const float* fw  = (const float*)d_in[10];
    const float* fb  = (const float*)d_in[11];
    float* hout = (float*)d_out;

    float* wsf = (float*)d_ws;
    size_t o = 0;
    f16*   XT     = (f16*)(wsf + o);  o += 3145728;   // [8][768][1024] f16 (becomes ZT)
    float* attReg = wsf + o;          o += 16777216;  // attT [4][8][1024][1024] f16
    f16*   attT   = (f16*)attReg;
    f16*   xT2    = (f16*)attReg;                     // overlay (dead before attT)
    f16*   aT     = (f16*)(wsf + o);  o += 1048576;   // [2][1024][1024] f16
    float* gate   = wsf + o;          o += 128;
    size_t rc = o;                                    // phase-union region
    // ---- phase A (through k_gate) ----
    size_t oA = rc;
    float* scT    = wsf + oA;          oA += 4194304;  // [4][1024][1024] f32
    f16*   keysT  = (f16*)(wsf + oA);  oA += 2097152;  // [4][8][1024][128] f16
    f16*   kwb    = (f16*)(wsf + oA);  oA += 196608;
    float* kwl    = wsf + oA;          oA += 32768;
    float* tkq    = wsf + oA;          oA += 524288;
    float* xl     = wsf + oA;          oA += 524288;
    float* ra     = wsf + oA;          oA += 4096;
    float* ratt   = wsf + oA;          oA += 65536;
    float* feats  = wsf + oA;          oA += 6656;
    float* partial= wsf + oA;          oA += 1114112;
    // ---- phase B (props) ----
    size_t oB = rc;
    f16*   P1     = (f16*)(wsf + oB);  oB += 3145728;  // [8][768][1024] f16
    float* hacc   = wsf + oB;          oB += 6291456;  // [8][768][1024] f32
    size_t oTot = (oA > oB) ? oA : oB;
    if (ws_size < oTot * 4) return;

    f16* ZT = XT;   // after k_zt, XT region holds ZT

    k_xt<<<2048, 256, 0, stream>>>(x, XT, xl);
    k_xt2<<<dim3(16, 4, 8), 256, 0, stream>>>(x, xT2);
    k_wcvt<<<128, 256, 0, stream>>>(kw, qw, kwl, kwb);
    k_tkq<<<2048, 256, 0, stream>>>(kwl, nv1, nv2, kb, qb, tkq);
    k_acvt<<<dim3(16, 16, 2), 256, 0, stream>>>(sup, aT);

    k_kqgemm<<<dim3(8, 1, 32), 256, 0, stream>>>(xT2, kwb, tkq, keysT);

    for (int h = 0; h < 2; h++)
        for (int bh = 0; bh < 2; bh++) {
            k_scoregemm<<<dim3(8, 8, 4), 256, 0, stream>>>(keysT, scT, h, bh);
            k_softmax2<<<1024, 256, 0, stream>>>(scT, aT, attT, h, bh);
        }

    k_colsum1<0><<<dim3(16, 34), 256, 0, stream>>>(aT, attT, ra, ratt, partial);
    k_colsum2<0><<<34, 256, 0, stream>>>(partial, ra, ratt);
    k_colsum1<1><<<dim3(16, 34), 256, 0, stream>>>(aT, attT, ra, ratt, partial);
    k_colsum2<1><<<34, 256, 0, stream>>>(partial, ra, ratt);
    k_feat13<<<512, 256, 0, stream>>>(xl, ra, ratt, feats);
    k_gate<<<8, 64, 0, stream>>>(feats, aw, ab, gate);

    // ---- phase B: project to o-domain, accumulate gated sum ----
    k_zt<<<dim3(16, 12, 8), 256, 0, stream>>>(XT, fw);
    k_hinit2<<<3072, 256, 0, stream>>>(ZT, gate, hacc);

    for (int s = 0; s < 2; s++)
        for (int kind = 0; kind < 3; kind++) {
            const f16* B0;
            size_t bsB;
            if (kind == 0) { B0 = aT + (size_t)s * 1048576; bsB = 0; }
            else { B0 = attT + (size_t)((s * 2 + kind - 1) * 8) * 1048576; bsB = 1048576; }
            int g1 = 1 + s * 6 + 2 * kind;
            k_prop1g<<<dim3(8, 6, 8), 256, 0, stream>>>(ZT, B0, bsB, P1);
            k_prop2g<<<dim3(8, 6, 8), 256, 0, stream>>>(P1, B0, bsB, hacc, gate, g1);
        }

    k_biasout<<<2048, 256, 0, stream>>>(hacc, fb, hout);
}

// Round 7
// 561.834 us; speedup vs baseline: 7.5704x; 1.0905x over previous
//
#include <hip/hip_runtime.h>
#include <hip/hip_bf16.h>

#define BB 8
#define DD 64
#define NNODE 1024
#define LLL 12
#define EE 128
#define NEGV -9.0e15f

typedef _Float16 f16;
typedef _Float16 f16x4 __attribute__((ext_vector_type(4)));
typedef _Float16 f16x8 __attribute__((ext_vector_type(8)));
typedef float f32x4 __attribute__((ext_vector_type(4)));

// ================= GEMM core helpers (128x128 tile, BK=64, 4 waves) =========

__device__ __forceinline__ void stage_tile(const char* g, int ld, char* lds, int t) {
    int wid = t >> 6, lane = t & 63;
#pragma unroll
    for (int it = 0; it < 4; it++) {
        int cbase = it * 256 + wid * 64;          // wave-uniform chunk base
        int c = cbase + lane;
        int row = c >> 3, p = c & 7;
        int gch = p ^ (row & 7);                  // inverse swizzle on SOURCE
        const char* src = g + (size_t)row * ld + gch * 16;
        char* dst = lds + (size_t)cbase * 16;     // wave-uniform; lane*16 implicit
        __builtin_amdgcn_global_load_lds(
            (const __attribute__((address_space(1))) unsigned int*)src,
            (__attribute__((address_space(3))) unsigned int*)dst, 16, 0, 0);
    }
}

__device__ __forceinline__ void mma_tile(const char* As, const char* Bs, int t,
                                         f32x4 acc[4][4]) {
    int lane = t & 63, wid = t >> 6;
    int wr = (wid >> 1) * 64, wc = (wid & 1) * 64;
    int lrow = lane & 15, lk = lane >> 4;
#pragma unroll
    for (int kk = 0; kk < 2; kk++) {
        f16x8 af[4], bf[4];
#pragma unroll
        for (int m = 0; m < 4; m++) {
            int row = wr + m * 16 + lrow;
            int p = (kk * 4 + lk) ^ (row & 7);    // swizzled read
            af[m] = *(const f16x8*)(As + row * 128 + p * 16);
        }
#pragma unroll
        for (int n = 0; n < 4; n++) {
            int row = wc + n * 16 + lrow;
            int p = (kk * 4 + lk) ^ (row & 7);
            bf[n] = *(const f16x8*)(Bs + row * 128 + p * 16);
        }
#pragma unroll
        for (int m = 0; m < 4; m++)
#pragma unroll
            for (int n = 0; n < 4; n++)
                acc[m][n] = __builtin_amdgcn_mfma_f32_16x16x32_f16(
                    af[m], bf[n], acc[m][n], 0, 0, 0);
    }
}

__device__ __forceinline__ void zero_acc(f32x4 acc[4][4]) {
#pragma unroll
    for (int m = 0; m < 4; m++)
#pragma unroll
        for (int n = 0; n < 4; n++)
#pragma unroll
            for (int q = 0; q < 4; q++) acc[m][n][q] = 0.f;
}

// ================= prep kernels =============================================

// XT[b][(d,l)][v] f16 + xl[b,d,v] = sum_l x
__global__ void k_xt(const float* __restrict__ x, f16* __restrict__ XT,
                     float* __restrict__ xl) {
    int i = blockIdx.x * 256 + threadIdx.x;       // (b,d,v)
    int v = i & 1023, d = (i >> 10) & 63, b = i >> 16;
    const float4* p = reinterpret_cast<const float4*>(x + (size_t)i * 12);
    float4 a = p[0], c = p[1], e = p[2];
    float vv[12] = {a.x, a.y, a.z, a.w, c.x, c.y, c.z, c.w, e.x, e.y, e.z, e.w};
    float ssum = 0.f;
    size_t base = ((size_t)b * 768) * 1024 + v;
    int r0 = d * 12;
#pragma unroll
    for (int l = 0; l < 12; l++) {
        ssum += vv[l];
        XT[base + (size_t)(r0 + l) * 1024] = (f16)vv[l];
    }
    xl[i] = ssum;
}

// xT2[b][n][(d,l)] f16 via LDS transpose of 16d x 64n tiles
__global__ __launch_bounds__(256) void k_xt2(const float* __restrict__ x,
                                             f16* __restrict__ xT2) {
    __shared__ f16 Ls[64][208];
    int b = blockIdx.z, d0 = blockIdx.y * 16, n0 = blockIdx.x * 64, t = threadIdx.x;
    for (int f = t; f < 3072; f += 256) {
        int dd = f / 192, rem = f - dd * 192, j = rem / 3, q = rem - j * 3;
        float4 v = *reinterpret_cast<const float4*>(
            x + (((size_t)(b * 64 + d0 + dd) * 1024) + n0 + j) * 12 + q * 4);
        f16* dst = &Ls[j][dd * 12 + q * 4];
        dst[0] = (f16)v.x; dst[1] = (f16)v.y; dst[2] = (f16)v.z; dst[3] = (f16)v.w;
    }
    __syncthreads();
    for (int c = t; c < 1536; c += 256) {
        int j = c / 24, p = c - j * 24;
        *reinterpret_cast<f16x8*>(
            xT2 + ((size_t)(b * 1024) + n0 + j) * 768 + d0 * 12 + p * 8) =
            *reinterpret_cast<const f16x8*>(&Ls[j][p * 8]);
    }
}

// kwb[var][e][768] f16, kwl[var][e][d] = sum_l w
__global__ void k_wcvt(const float* __restrict__ kw, const float* __restrict__ qw,
                       float* __restrict__ kwl, f16* __restrict__ kwb) {
    int i = blockIdx.x * 256 + threadIdx.x;       // (var,e,d)
    int d = i & 63, e = (i >> 6) & 127, var = i >> 13;
    const float* src = (var < 2 ? kw + (size_t)var * 98304
                                : qw + (size_t)(var - 2) * 98304) +
                       ((size_t)e * 64 + d) * 12;
    f16* dst = kwb + ((size_t)var * 128 + e) * 768 + d * 12;
    float ssum = 0.f;
#pragma unroll
    for (int l = 0; l < 12; l++) {
        float v = src[l];
        ssum += v;
        dst[l] = (f16)v;
    }
    kwl[i] = ssum;
}

// tkq[var][n][e] = sum_d kwl[var][e][d]*nv + bias[var][e]
__global__ void k_tkq(const float* __restrict__ kwl, const float* __restrict__ nv1,
                      const float* __restrict__ nv2, const float* __restrict__ kb,
                      const float* __restrict__ qb, float* __restrict__ tkq) {
    int i = blockIdx.x * 256 + threadIdx.x;       // (var,n,e)
    int e = i & 127, n = (i >> 7) & 1023, var = i >> 17;
    float ssum = (var < 2) ? kb[var * 128 + e] : qb[(var - 2) * 128 + e];
    const float* wl = kwl + ((size_t)var * 128 + e) * 64;
    if (var < 2) {
        const float* nvp = nv1 + (size_t)n * 64;
#pragma unroll 8
        for (int d = 0; d < 64; d++) ssum += wl[d] * nvp[d];
    } else {
#pragma unroll 8
        for (int d = 0; d < 64; d++) ssum += wl[d] * nv2[(size_t)d * 1024 + n];
    }
    tkq[i] = ssum;
}

// aT[s][w][v] f16 (transpose of support)
__global__ void k_acvt(const float* __restrict__ sup, f16* __restrict__ aT) {
    __shared__ float Ls[64][65];
    int s = blockIdx.z, v0 = blockIdx.y * 64, w0 = blockIdx.x * 64, t = threadIdx.x;
    int j = t & 63, i0 = t >> 6;
    for (int i = i0; i < 64; i += 4)
        Ls[i][j] = sup[((size_t)s * 1024 + v0 + i) * 1024 + w0 + j];
    __syncthreads();
    for (int i = i0; i < 64; i += 4)
        aT[((size_t)s * 1024 + w0 + i) * 1024 + v0 + j] = (f16)Ls[j][i];
}

// ================= MFMA GEMM kernels ========================================

// keysT[var][b][n][e] = sum_dl xT2[b][n][dl]*kwb[var][e][dl] + tkq[var][n][e]
__global__ __launch_bounds__(256) void k_kqgemm(const f16* __restrict__ xT2,
                                                const f16* __restrict__ kwb,
                                                const float* __restrict__ tkq,
                                                f16* __restrict__ keysT) {
    __shared__ char As[16384], Bs[16384];
    int z = blockIdx.z, var = z >> 3, b = z & 7;
    int nt = blockIdx.x, t = threadIdx.x;
    const char* Ag = (const char*)(xT2 + ((size_t)b * 1024 + nt * 128) * 768);
    const char* Bg = (const char*)(kwb + (size_t)var * 128 * 768);
    f32x4 acc[4][4];
    zero_acc(acc);
    for (int kt = 0; kt < 12; kt++) {
        stage_tile(Ag + kt * 128, 1536, As, t);
        stage_tile(Bg + kt * 128, 1536, Bs, t);
        __syncthreads();
        mma_tile(As, Bs, t, acc);
        __syncthreads();
    }
    int lane = t & 63, wid = t >> 6;
    int wr = (wid >> 1) * 64, wc = (wid & 1) * 64;
    int cn = lane & 15, rq = (lane >> 4) * 4;
#pragma unroll
    for (int m = 0; m < 4; m++)
#pragma unroll
        for (int q = 0; q < 4; q++) {
            int n_g = nt * 128 + wr + m * 16 + rq + q;
#pragma unroll
            for (int nn = 0; nn < 4; nn++) {
                int e = wc + nn * 16 + cn;
                float v = acc[m][nn][q] + tkq[((size_t)var * 1024 + n_g) * 128 + e];
                keysT[(((size_t)var * 8 + b) * 1024 + n_g) * 128 + e] = (f16)v;
            }
        }
}

// scT[bl][w][v] = relu(sum_e query[w,e]*keys[v,e]) for b = bh*4+bl
__global__ __launch_bounds__(256) void k_scoregemm(const f16* __restrict__ keysT,
                                                   float* __restrict__ scT,
                                                   int h, int bh) {
    __shared__ char As[16384], Bs[16384];
    int bl = blockIdx.z, b = bh * 4 + bl;
    int wt = blockIdx.y, vt = blockIdx.x, t = threadIdx.x;
    const char* Ag = (const char*)(keysT + (((size_t)(2 + h) * 8 + b) * 1024 + wt * 128) * 128);
    const char* Bg = (const char*)(keysT + (((size_t)h * 8 + b) * 1024 + vt * 128) * 128);
    f32x4 acc[4][4];
    zero_acc(acc);
    for (int kt = 0; kt < 2; kt++) {
        stage_tile(Ag + kt * 128, 256, As, t);
        stage_tile(Bg + kt * 128, 256, Bs, t);
        __syncthreads();
        mma_tile(As, Bs, t, acc);
        __syncthreads();
    }
    int lane = t & 63, wid = t >> 6;
    int wr = (wid >> 1) * 64, wc = (wid & 1) * 64;
    int cn = lane & 15, rq = (lane >> 4) * 4;
#pragma unroll
    for (int m = 0; m < 4; m++)
#pragma unroll
        for (int q = 0; q < 4; q++) {
            int w = wt * 128 + wr + m * 16 + rq + q;
#pragma unroll
            for (int nn = 0; nn < 4; nn++) {
                int v = vt * 128 + wc + nn * 16 + cn;
                scT[((size_t)bl * 1024 + w) * 1024 + v] = fmaxf(acc[m][nn][q], 0.f);
            }
        }
}

// prop order-1: P1[b][r][w] = f16( sum_v ZT[b][r][v] * MT[w][v] )   (no hacc)
__global__ __launch_bounds__(256) void k_prop1g(const f16* __restrict__ A0,
                                                const f16* __restrict__ B0, size_t bsB,
                                                f16* __restrict__ P1) {
    __shared__ char As[16384], Bs[16384];
    int b = blockIdx.z, rt = blockIdx.y, wt = blockIdx.x, t = threadIdx.x;
    const char* Ag = (const char*)(A0 + ((size_t)b * 768 + rt * 128) * 1024);
    const char* Bg = (const char*)(B0 + (size_t)b * bsB + (size_t)wt * 128 * 1024);
    f32x4 acc[4][4];
    zero_acc(acc);
    for (int kt = 0; kt < 16; kt++) {
        stage_tile(Ag + kt * 128, 2048, As, t);
        stage_tile(Bg + kt * 128, 2048, Bs, t);
        __syncthreads();
        mma_tile(As, Bs, t, acc);
        __syncthreads();
    }
    int lane = t & 63, wid = t >> 6;
    int wr = (wid >> 1) * 64, wc = (wid & 1) * 64;
    int cn = lane & 15, rq = (lane >> 4) * 4;
#pragma unroll
    for (int m = 0; m < 4; m++)
#pragma unroll
        for (int q = 0; q < 4; q++) {
            int r = rt * 128 + wr + m * 16 + rq + q;
            size_t pbase = ((size_t)b * 768 + r) * 1024;
#pragma unroll
            for (int nn = 0; nn < 4; nn++) {
                int w = wt * 128 + wc + nn * 16 + cn;
                P1[pbase + w] = (f16)acc[m][nn][q];
            }
        }
}

// prop order-2: val = P1·M ; hacc(f16) += g1*P1[r][w] + g2*val
__global__ __launch_bounds__(256) void k_prop2g(const f16* __restrict__ P1,
                                                const f16* __restrict__ B0, size_t bsB,
                                                f16* __restrict__ hacc,
                                                const float* __restrict__ gate, int gidx) {
    __shared__ char As[16384], Bs[16384];
    int b = blockIdx.z, rt = blockIdx.y, wt = blockIdx.x, t = threadIdx.x;
    const char* Ag = (const char*)(P1 + ((size_t)b * 768 + rt * 128) * 1024);
    const char* Bg = (const char*)(B0 + (size_t)b * bsB + (size_t)wt * 128 * 1024);
    f32x4 acc[4][4];
    zero_acc(acc);
    for (int kt = 0; kt < 16; kt++) {
        stage_tile(Ag + kt * 128, 2048, As, t);
        stage_tile(Bg + kt * 128, 2048, Bs, t);
        __syncthreads();
        mma_tile(As, Bs, t, acc);
        __syncthreads();
    }
    float g1 = gate[b * 13 + gidx], g2 = gate[b * 13 + gidx + 1];
    int lane = t & 63, wid = t >> 6;
    int wr = (wid >> 1) * 64, wc = (wid & 1) * 64;
    int cn = lane & 15, rq = (lane >> 4) * 4;
#pragma unroll
    for (int m = 0; m < 4; m++)
#pragma unroll
        for (int q = 0; q < 4; q++) {
            int r = rt * 128 + wr + m * 16 + rq + q;
            size_t pbase = ((size_t)b * 768 + r) * 1024;
#pragma unroll
            for (int nn = 0; nn < 4; nn++) {
                int w = wt * 128 + wc + nn * 16 + cn;
                float p1v = (float)P1[pbase + w];
                float hv = (float)hacc[pbase + w];
                hacc[pbase + w] = (f16)(hv + g1 * p1v + g2 * acc[m][nn][q]);
            }
        }
}

// ================= softmax / stats / gate ===================================

// fused both supports: read raw score row once, mask+softmax per s (4 b's)
__global__ void k_softmax2(const float* __restrict__ scT, const f16* __restrict__ aT,
                           f16* __restrict__ attT, int h, int bh) {
    int gw = blockIdx.x * 4 + (threadIdx.x >> 6);  // bl*1024 + w, gw in [0,4096)
    int bl = gw >> 10, w = gw & 1023;
    int lane = threadIdx.x & 63;
    const float* sp = scT + (size_t)gw * 1024;
    float e[16];
#pragma unroll
    for (int k = 0; k < 16; k++) e[k] = sp[k * 64 + lane];
#pragma unroll
    for (int s = 0; s < 2; s++) {
        const f16* ap = aT + ((size_t)s * 1024 + w) * 1024;
        float xx[16];
        float m = NEGV;
#pragma unroll
        for (int k = 0; k < 16; k++) {
            int v = k * 64 + lane;
            xx[k] = ((float)ap[v] > 0.f) ? e[k] : NEGV;
            m = fmaxf(m, xx[k]);
        }
#pragma unroll
        for (int off = 1; off < 64; off <<= 1) m = fmaxf(m, __shfl_xor(m, off));
        float ssum = 0.f;
#pragma unroll
        for (int k = 0; k < 16; k++) {
            xx[k] = __expf(xx[k] - m);
            ssum += xx[k];
        }
#pragma unroll
        for (int off = 1; off < 64; off <<= 1) ssum += __shfl_xor(ssum, off);
        float inv = 1.f / ssum;
        f16* op = attT + (size_t)(s * 2 + h) * 8 * 1048576 +
                  (((size_t)(bh * 4 + bl)) * 1024 + w) * 1024;
#pragma unroll
        for (int k = 0; k < 16; k++) op[k * 64 + lane] = (f16)(xx[k] * inv);
    }
}

// ---------- colsum stage 1 ----------
template <int ORDER>
__global__ __launch_bounds__(256) void k_colsum1(
    const f16* __restrict__ aT, const f16* __restrict__ attT,
    const float* __restrict__ ra, const float* __restrict__ ratt,
    float* __restrict__ partial) {
    int u = blockIdx.y, rc = blockIdx.x;          // rc 0..15
    int t = threadIdx.x;
    int lane7 = t & 127, rh = t >> 7;
    int v0 = lane7 * 8;
    const f16* M = (u < 2) ? aT + (size_t)u * 1048576
                           : attT + (size_t)(u - 2) * 1048576;
    const float* rin = nullptr;
    if (ORDER) rin = (u < 2) ? ra + (size_t)u * 2048 : ratt + (size_t)(u - 2) * 2048;
    float acc[8] = {};
    int row0 = rc * 64 + rh * 32;
#pragma unroll 4
    for (int i = 0; i < 32; i++) {
        int row = row0 + i;
        f16x8 mv = *reinterpret_cast<const f16x8*>(M + (size_t)row * 1024 + v0);
        float sc = ORDER ? rin[row] : 1.f;
#pragma unroll
        for (int j = 0; j < 8; j++) acc[j] += (float)mv[j] * sc;
    }
    float* pp = partial + ((size_t)u * 32 + rc * 2 + rh) * 1024 + v0;
#pragma unroll
    for (int j = 0; j < 8; j++) pp[j] = acc[j];
}

// ---------- colsum stage 2 ----------
template <int ORDER>
__global__ void k_colsum2(const float* __restrict__ partial, float* __restrict__ ra,
                          float* __restrict__ ratt) {
    int u = blockIdx.x, t = threadIdx.x;
    for (int v = t; v < 1024; v += 256) {
        float s = 0.f;
#pragma unroll
        for (int k = 0; k < 32; k++) s += partial[((size_t)u * 32 + k) * 1024 + v];
        float* out = (u < 2) ? ra + (size_t)u * 2048 : ratt + (size_t)(u - 2) * 2048;
        out[ORDER * 1024 + v] = s;
    }
}

__global__ void k_feat13(const float* __restrict__ xl, const float* __restrict__ ra,
                         const float* __restrict__ ratt, float* __restrict__ feats) {
    int bd = blockIdx.x;
    int b = bd >> 6, d = bd & 63;
    const float* xp = xl + (size_t)bd * 1024;
    int t = threadIdx.x;
    float s[13];
#pragma unroll
    for (int i = 0; i < 13; i++) s[i] = 0.f;
    for (int v = t; v < 1024; v += 256) {
        float xv = xp[v];
        s[0] += xv;
#pragma unroll
        for (int ss = 0; ss < 2; ss++) {
            s[1 + ss * 6 + 0] += xv * ra[ss * 2048 + v];
            s[1 + ss * 6 + 1] += xv * ra[ss * 2048 + 1024 + v];
#pragma unroll
            for (int hh = 0; hh < 2; hh++) {
                const float* rb = ratt + (((size_t)(ss * 2 + hh) * 8 + b)) * 2048;
                s[1 + ss * 6 + 2 + hh * 2] += xv * rb[v];
                s[1 + ss * 6 + 3 + hh * 2] += xv * rb[1024 + v];
            }
        }
    }
    int wid = t >> 6, lane = t & 63;
#pragma unroll
    for (int i = 0; i < 13; i++)
#pragma unroll
        for (int off = 1; off < 64; off <<= 1) s[i] += __shfl_xor(s[i], off);
    __shared__ float red[13][4];
    if (lane == 0)
#pragma unroll
        for (int i = 0; i < 13; i++) red[i][wid] = s[i];
    __syncthreads();
    if (t < 13) {
        float tot = red[t][0] + red[t][1] + red[t][2] + red[t][3];
        feats[(size_t)b * 832 + t * 64 + d] = tot * (1.f / (1024.f * 12.f));
    }
}

__global__ void k_gate(const float* __restrict__ feats, const float* __restrict__ aw,
                       const float* __restrict__ ab, float* __restrict__ gate) {
    int b = blockIdx.x, t = threadIdx.x;
    __shared__ float lg[13];
    if (t < 13) {
        float s = ab[t];
        const float* f = feats + (size_t)b * 832;
        const float* w = aw + (size_t)t * 832;
        for (int k = 0; k < 832; k++) s += f[k] * w[k];
        lg[t] = s;
    }
    __syncthreads();
    if (t == 0) {
        float m = lg[0];
        for (int j = 1; j < 13; j++) m = fmaxf(m, lg[j]);
        float ss = 0.f;
        for (int j = 0; j < 13; j++) ss += __expf(lg[j] - m);
        float inv = 1.f / ss;
        for (int j = 0; j < 13; j++) gate[b * 13 + j] = __expf(lg[j] - m) * inv;
    }
}

// ---------- z-projection, in place on XT, LDS-staged ----------
// Block (nt,l,b): loads x rows {d*12+l, d=0..63} for n-slice [nt*128,+128) into LDS,
// computes Z rows {o*12+l} for the same slice, writes back. Block-local; no races.
__global__ __launch_bounds__(256) void k_zt2(f16* __restrict__ XT,
                                             const float* __restrict__ fw) {
    __shared__ f16 xs[64][136];     // 64 d-rows x 128 n (pad 8 f16)
    __shared__ float fws[64][64];   // fws[o][d] = fw[o][d]
    int nt = blockIdx.x, l = blockIdx.y, b = blockIdx.z;
    int t = threadIdx.x;
    f16* base = XT + (size_t)b * 786432 + (size_t)l * 1024 + nt * 128;
    // stage x rows (f16x8 coalesced: 16 chunks of 16B per 256-B row)
#pragma unroll
    for (int it = 0; it < 4; it++) {
        int idx = it * 256 + t;
        int row = idx >> 4, c = idx & 15;
        *reinterpret_cast<f16x8*>(&xs[row][c * 8]) =
            *reinterpret_cast<const f16x8*>(base + (size_t)row * 12288 + c * 8);
    }
    for (int i = t; i < 4096; i += 256) ((float*)fws)[i] = fw[i];
    __syncthreads();
    int nl = t & 31, og = t >> 5;   // n-octet (4 n each), o-group (8 o each)
    float acc[8][4];
#pragma unroll
    for (int oo = 0; oo < 8; oo++)
#pragma unroll
        for (int j = 0; j < 4; j++) acc[oo][j] = 0.f;
#pragma unroll 4
    for (int d = 0; d < 64; d++) {
        f16x4 xv = *reinterpret_cast<const f16x4*>(&xs[d][nl * 4]);
        float x0 = (float)xv[0], x1 = (float)xv[1], x2 = (float)xv[2], x3 = (float)xv[3];
#pragma unroll
        for (int oo = 0; oo < 8; oo++) {
            float w = fws[og * 8 + oo][d];
            acc[oo][0] += w * x0; acc[oo][1] += w * x1;
            acc[oo][2] += w * x2; acc[oo][3] += w * x3;
        }
    }
#pragma unroll
    for (int oo = 0; oo < 8; oo++) {
        int o = og * 8 + oo;
        f16x4 ov;
        ov[0] = (f16)acc[oo][0]; ov[1] = (f16)acc[oo][1];
        ov[2] = (f16)acc[oo][2]; ov[3] = (f16)acc[oo][3];
        *reinterpret_cast<f16x4*>(base + (size_t)o * 12288 + nl * 4) = ov;
    }
}

// hacc init: hacc[b][r][w] = f16( gate0 * ZT )
__global__ void k_hinit2(const f16* __restrict__ ZT, const float* __restrict__ gate,
                         f16* __restrict__ hacc) {
    size_t i8 = (size_t)blockIdx.x * 256 + threadIdx.x;   // element-octet index
    int b = (int)(i8 / 98304);                            // 786432/8 per b
    float g = gate[b * 13];
    f16x8 v = *reinterpret_cast<const f16x8*>(ZT + i8 * 8);
    f16x8 o;
#pragma unroll
    for (int j = 0; j < 8; j++) o[j] = (f16)(g * (float)v[j]);
    *reinterpret_cast<f16x8*>(hacc + i8 * 8) = o;
}

// final: out[b,o,n,l] = hacc[b][(o,l)][n] + fb[o]  (pure layout + bias)
__global__ void k_biasout(const f16* __restrict__ hacc, const float* __restrict__ fb,
                          float* __restrict__ out) {
    int idx = blockIdx.x * 256 + threadIdx.x;     // (b,o,n), n fastest
    int n = idx & 1023, o = (idx >> 10) & 63, b = idx >> 16;
    float fbv = fb[o];
    float v[12];
#pragma unroll
    for (int l = 0; l < 12; l++)
        v[l] = (float)hacc[((size_t)b * 768 + o * 12 + l) * 1024 + n] + fbv;
    float4* dst = reinterpret_cast<float4*>(out + (((size_t)b * 64 + o) * 1024 + n) * 12);
    float4 o0 = {v[0], v[1], v[2], v[3]};
    float4 o1 = {v[4], v[5], v[6], v[7]};
    float4 o2 = {v[8], v[9], v[10], v[11]};
    dst[0] = o0; dst[1] = o1; dst[2] = o2;
}

// ================= launch ===================================================

extern "C" void kernel_launch(void* const* d_in, const int* in_sizes, int n_in,
                              void* d_out, int out_size, void* d_ws, size_t ws_size,
                              hipStream_t stream) {
    const float* x   = (const float*)d_in[0];
    const float* sup = (const float*)d_in[1];
    const float* nv1 = (const float*)d_in[2];
    const float* nv2 = (const float*)d_in[3];
    const float* kw  = (const float*)d_in[4];
    const float* kb  = (const float*)d_in[5];
    const float* qw  = (const float*)d_in[6];
    const float* qb  = (const float*)d_in[7];
    const float* aw  = (const float*)d_in[8];
    const float* ab  = (const float*)d_in[9];
    const float* fw  = (const float*)d_in[10];
    const float* fb  = (const float*)d_in[11];
    float* hout = (float*)d_out;

    float* wsf = (float*)d_ws;
    size_t o = 0;
    f16*   XT     = (f16*)(wsf + o);  o += 3145728;   // [8][768][1024] f16 (becomes ZT)
    float* attReg = wsf + o;          o += 16777216;  // attT [4][8][1024][1024] f16
    f16*   attT   = (f16*)attReg;
    f16*   xT2    = (f16*)attReg;                     // overlay (dead before attT)
    f16*   aT     = (f16*)(wsf + o);  o += 1048576;   // [2][1024][1024] f16
    float* gate   = wsf + o;          o += 128;
    size_t rc = o;                                    // phase-union region
    // ---- phase A (through k_gate) ----
    size_t oA = rc;
    float* scT    = wsf + oA;          oA += 4194304;  // [4][1024][1024] f32
    f16*   keysT  = (f16*)(wsf + oA);  oA += 2097152;  // [4][8][1024][128] f16
    f16*   kwb    = (f16*)(wsf + oA);  oA += 196608;
    float* kwl    = wsf + oA;          oA += 32768;
    float* tkq    = wsf + oA;          oA += 524288;
    float* xl     = wsf + oA;          oA += 524288;
    float* ra     = wsf + oA;          oA += 4096;
    float* ratt   = wsf + oA;          oA += 65536;
    float* feats  = wsf + oA;          oA += 6656;
    float* partial= wsf + oA;          oA += 1114112;
    // ---- phase B (props) ----
    size_t oB = rc;
    f16*   P1     = (f16*)(wsf + oB);  oB += 3145728;  // [8][768][1024] f16
    f16*   hacc   = (f16*)(wsf + oB);  oB += 3145728;  // [8][768][1024] f16
    size_t oTot = (oA > oB) ? oA : oB;
    if (ws_size < oTot * 4) return;

    f16* ZT = XT;   // after k_zt2, XT region holds ZT

    k_xt<<<2048, 256, 0, stream>>>(x, XT, xl);
    k_xt2<<<dim3(16, 4, 8), 256, 0, stream>>>(x, xT2);
    k_wcvt<<<128, 256, 0, stream>>>(kw, qw, kwl, kwb);
    k_tkq<<<2048, 256, 0, stream>>>(kwl, nv1, nv2, kb, qb, tkq);
    k_acvt<<<dim3(16, 16, 2), 256, 0, stream>>>(sup, aT);

    k_kqgemm<<<dim3(8, 1, 32), 256, 0, stream>>>(xT2, kwb, tkq, keysT);

    for (int h = 0; h < 2; h++)
        for (int bh = 0; bh < 2; bh++) {
            k_scoregemm<<<dim3(8, 8, 4), 256, 0, stream>>>(keysT, scT, h, bh);
            k_softmax2<<<1024, 256, 0, stream>>>(scT, aT, attT, h, bh);
        }

    k_colsum1<0><<<dim3(16, 34), 256, 0, stream>>>(aT, attT, ra, ratt, partial);
    k_colsum2<0><<<34, 256, 0, stream>>>(partial, ra, ratt);
    k_colsum1<1><<<dim3(16, 34), 256, 0, stream>>>(aT, attT, ra, ratt, partial);
    k_colsum2<1><<<34, 256, 0, stream>>>(partial, ra, ratt);
    k_feat13<<<512, 256, 0, stream>>>(xl, ra, ratt, feats);
    k_gate<<<8, 64, 0, stream>>>(feats, aw, ab, gate);

    // ---- phase B: project to o-domain, accumulate gated sum ----
    k_zt2<<<dim3(8, 12, 8), 256, 0, stream>>>(XT, fw);
    k_hinit2<<<3072, 256, 0, stream>>>(ZT, gate, hacc);

    for (int s = 0; s < 2; s++)
        for (int kind = 0; kind < 3; kind++) {
            const f16* B0;
            size_t bsB;
            if (kind == 0) { B0 = aT + (size_t)s * 1048576; bsB = 0; }
            else { B0 = attT + (size_t)((s * 2 + kind - 1) * 8) * 1048576; bsB = 1048576; }
            int g1 = 1 + s * 6 + 2 * kind;
            k_prop1g<<<dim3(8, 6, 8), 256, 0, stream>>>(ZT, B0, bsB, P1);
            k_prop2g<<<dim3(8, 6, 8), 256, 0, stream>>>(P1, B0, bsB, hacc, gate, g1);
        }

    k_biasout<<<2048, 256, 0, stream>>>(hacc, fb, hout);
}

// Round 8
// 464.162 us; speedup vs baseline: 9.1634x; 1.2104x over previous
//
#include <hip/hip_runtime.h>
#include <hip/hip_bf16.h>

#define BB 8
#define DD 64
#define NNODE 1024
#define LLL 12
#define EE 128
#define NEGV -9.0e15f

typedef _Float16 f16;
typedef _Float16 f16x4 __attribute__((ext_vector_type(4)));
typedef _Float16 f16x8 __attribute__((ext_vector_type(8)));
typedef float f32x4 __attribute__((ext_vector_type(4)));

// ================= GEMM core helpers (128x128 tile, BK=64, 4 waves) =========

__device__ __forceinline__ void stage_tile(const char* g, int ld, char* lds, int t) {
    int wid = t >> 6, lane = t & 63;
#pragma unroll
    for (int it = 0; it < 4; it++) {
        int cbase = it * 256 + wid * 64;          // wave-uniform chunk base
        int c = cbase + lane;
        int row = c >> 3, p = c & 7;
        int gch = p ^ (row & 7);                  // inverse swizzle on SOURCE
        const char* src = g + (size_t)row * ld + gch * 16;
        char* dst = lds + (size_t)cbase * 16;     // wave-uniform; lane*16 implicit
        __builtin_amdgcn_global_load_lds(
            (const __attribute__((address_space(1))) unsigned int*)src,
            (__attribute__((address_space(3))) unsigned int*)dst, 16, 0, 0);
    }
}

__device__ __forceinline__ void mma_tile(const char* As, const char* Bs, int t,
                                         f32x4 acc[4][4]) {
    int lane = t & 63, wid = t >> 6;
    int wr = (wid >> 1) * 64, wc = (wid & 1) * 64;
    int lrow = lane & 15, lk = lane >> 4;
#pragma unroll
    for (int kk = 0; kk < 2; kk++) {
        f16x8 af[4], bf[4];
#pragma unroll
        for (int m = 0; m < 4; m++) {
            int row = wr + m * 16 + lrow;
            int p = (kk * 4 + lk) ^ (row & 7);    // swizzled read
            af[m] = *(const f16x8*)(As + row * 128 + p * 16);
        }
#pragma unroll
        for (int n = 0; n < 4; n++) {
            int row = wc + n * 16 + lrow;
            int p = (kk * 4 + lk) ^ (row & 7);
            bf[n] = *(const f16x8*)(Bs + row * 128 + p * 16);
        }
#pragma unroll
        for (int m = 0; m < 4; m++)
#pragma unroll
            for (int n = 0; n < 4; n++)
                acc[m][n] = __builtin_amdgcn_mfma_f32_16x16x32_f16(
                    af[m], bf[n], acc[m][n], 0, 0, 0);
    }
}

__device__ __forceinline__ void zero_acc(f32x4 acc[4][4]) {
#pragma unroll
    for (int m = 0; m < 4; m++)
#pragma unroll
        for (int n = 0; n < 4; n++)
#pragma unroll
            for (int q = 0; q < 4; q++) acc[m][n][q] = 0.f;
}

// Map pair index j (0..5) to its B matrix base (aT shared over b, attT per b).
__device__ __forceinline__ const f16* pair_B(const f16* aT, const f16* attT,
                                             int j, int b) {
    if (j == 0) return aT;
    if (j == 3) return aT + 1048576;
    int idx = (j < 3) ? (j - 1) : (j - 2);        // att slot 0..3
    return attT + (size_t)idx * 8388608 + (size_t)b * 1048576;
}

// ================= prep kernels =============================================

// XT[b][(d,l)][v] f16 + xl[b,d,v] = sum_l x
__global__ void k_xt(const float* __restrict__ x, f16* __restrict__ XT,
                     float* __restrict__ xl) {
    int i = blockIdx.x * 256 + threadIdx.x;       // (b,d,v)
    int v = i & 1023, d = (i >> 10) & 63, b = i >> 16;
    const float4* p = reinterpret_cast<const float4*>(x + (size_t)i * 12);
    float4 a = p[0], c = p[1], e = p[2];
    float vv[12] = {a.x, a.y, a.z, a.w, c.x, c.y, c.z, c.w, e.x, e.y, e.z, e.w};
    float ssum = 0.f;
    size_t base = ((size_t)b * 768) * 1024 + v;
    int r0 = d * 12;
#pragma unroll
    for (int l = 0; l < 12; l++) {
        ssum += vv[l];
        XT[base + (size_t)(r0 + l) * 1024] = (f16)vv[l];
    }
    xl[i] = ssum;
}

// xT2[b][n][(d,l)] f16 via LDS transpose of 16d x 64n tiles
__global__ __launch_bounds__(256) void k_xt2(const float* __restrict__ x,
                                             f16* __restrict__ xT2) {
    __shared__ f16 Ls[64][208];
    int b = blockIdx.z, d0 = blockIdx.y * 16, n0 = blockIdx.x * 64, t = threadIdx.x;
    for (int f = t; f < 3072; f += 256) {
        int dd = f / 192, rem = f - dd * 192, j = rem / 3, q = rem - j * 3;
        float4 v = *reinterpret_cast<const float4*>(
            x + (((size_t)(b * 64 + d0 + dd) * 1024) + n0 + j) * 12 + q * 4);
        f16* dst = &Ls[j][dd * 12 + q * 4];
        dst[0] = (f16)v.x; dst[1] = (f16)v.y; dst[2] = (f16)v.z; dst[3] = (f16)v.w;
    }
    __syncthreads();
    for (int c = t; c < 1536; c += 256) {
        int j = c / 24, p = c - j * 24;
        *reinterpret_cast<f16x8*>(
            xT2 + ((size_t)(b * 1024) + n0 + j) * 768 + d0 * 12 + p * 8) =
            *reinterpret_cast<const f16x8*>(&Ls[j][p * 8]);
    }
}

// kwb[var][e][768] f16, kwl[var][e][d] = sum_l w
__global__ void k_wcvt(const float* __restrict__ kw, const float* __restrict__ qw,
                       float* __restrict__ kwl, f16* __restrict__ kwb) {
    int i = blockIdx.x * 256 + threadIdx.x;       // (var,e,d)
    int d = i & 63, e = (i >> 6) & 127, var = i >> 13;
    const float* src = (var < 2 ? kw + (size_t)var * 98304
                                : qw + (size_t)(var - 2) * 98304) +
                       ((size_t)e * 64 + d) * 12;
    f16* dst = kwb + ((size_t)var * 128 + e) * 768 + d * 12;
    float ssum = 0.f;
#pragma unroll
    for (int l = 0; l < 12; l++) {
        float v = src[l];
        ssum += v;
        dst[l] = (f16)v;
    }
    kwl[i] = ssum;
}

// tkq[var][n][e] = sum_d kwl[var][e][d]*nv + bias[var][e]
__global__ void k_tkq(const float* __restrict__ kwl, const float* __restrict__ nv1,
                      const float* __restrict__ nv2, const float* __restrict__ kb,
                      const float* __restrict__ qb, float* __restrict__ tkq) {
    int i = blockIdx.x * 256 + threadIdx.x;       // (var,n,e)
    int e = i & 127, n = (i >> 7) & 1023, var = i >> 17;
    float ssum = (var < 2) ? kb[var * 128 + e] : qb[(var - 2) * 128 + e];
    const float* wl = kwl + ((size_t)var * 128 + e) * 64;
    if (var < 2) {
        const float* nvp = nv1 + (size_t)n * 64;
#pragma unroll 8
        for (int d = 0; d < 64; d++) ssum += wl[d] * nvp[d];
    } else {
#pragma unroll 8
        for (int d = 0; d < 64; d++) ssum += wl[d] * nv2[(size_t)d * 1024 + n];
    }
    tkq[i] = ssum;
}

// aT[s][w][v] f16 (transpose of support)
__global__ void k_acvt(const float* __restrict__ sup, f16* __restrict__ aT) {
    __shared__ float Ls[64][65];
    int s = blockIdx.z, v0 = blockIdx.y * 64, w0 = blockIdx.x * 64, t = threadIdx.x;
    int j = t & 63, i0 = t >> 6;
    for (int i = i0; i < 64; i += 4)
        Ls[i][j] = sup[((size_t)s * 1024 + v0 + i) * 1024 + w0 + j];
    __syncthreads();
    for (int i = i0; i < 64; i += 4)
        aT[((size_t)s * 1024 + w0 + i) * 1024 + v0 + j] = (f16)Ls[j][i];
}

// ================= MFMA GEMM kernels ========================================

// keysT[var][b][n][e] = sum_dl xT2[b][n][dl]*kwb[var][e][dl] + tkq[var][n][e]
__global__ __launch_bounds__(256) void k_kqgemm(const f16* __restrict__ xT2,
                                                const f16* __restrict__ kwb,
                                                const float* __restrict__ tkq,
                                                f16* __restrict__ keysT) {
    __shared__ char As[16384], Bs[16384];
    int z = blockIdx.z, var = z >> 3, b = z & 7;
    int nt = blockIdx.x, t = threadIdx.x;
    const char* Ag = (const char*)(xT2 + ((size_t)b * 1024 + nt * 128) * 768);
    const char* Bg = (const char*)(kwb + (size_t)var * 128 * 768);
    f32x4 acc[4][4];
    zero_acc(acc);
    for (int kt = 0; kt < 12; kt++) {
        stage_tile(Ag + kt * 128, 1536, As, t);
        stage_tile(Bg + kt * 128, 1536, Bs, t);
        __syncthreads();
        mma_tile(As, Bs, t, acc);
        __syncthreads();
    }
    int lane = t & 63, wid = t >> 6;
    int wr = (wid >> 1) * 64, wc = (wid & 1) * 64;
    int cn = lane & 15, rq = (lane >> 4) * 4;
#pragma unroll
    for (int m = 0; m < 4; m++)
#pragma unroll
        for (int q = 0; q < 4; q++) {
            int n_g = nt * 128 + wr + m * 16 + rq + q;
#pragma unroll
            for (int nn = 0; nn < 4; nn++) {
                int e = wc + nn * 16 + cn;
                float v = acc[m][nn][q] + tkq[((size_t)var * 1024 + n_g) * 128 + e];
                keysT[(((size_t)var * 8 + b) * 1024 + n_g) * 128 + e] = (f16)v;
            }
        }
}

// scT[bl][w][v] = relu(sum_e query[w,e]*keys[v,e]) for b = bh*4+bl
__global__ __launch_bounds__(256) void k_scoregemm(const f16* __restrict__ keysT,
                                                   float* __restrict__ scT,
                                                   int h, int bh) {
    __shared__ char As[16384], Bs[16384];
    int bl = blockIdx.z, b = bh * 4 + bl;
    int wt = blockIdx.y, vt = blockIdx.x, t = threadIdx.x;
    const char* Ag = (const char*)(keysT + (((size_t)(2 + h) * 8 + b) * 1024 + wt * 128) * 128);
    const char* Bg = (const char*)(keysT + (((size_t)h * 8 + b) * 1024 + vt * 128) * 128);
    f32x4 acc[4][4];
    zero_acc(acc);
    for (int kt = 0; kt < 2; kt++) {
        stage_tile(Ag + kt * 128, 256, As, t);
        stage_tile(Bg + kt * 128, 256, Bs, t);
        __syncthreads();
        mma_tile(As, Bs, t, acc);
        __syncthreads();
    }
    int lane = t & 63, wid = t >> 6;
    int wr = (wid >> 1) * 64, wc = (wid & 1) * 64;
    int cn = lane & 15, rq = (lane >> 4) * 4;
#pragma unroll
    for (int m = 0; m < 4; m++)
#pragma unroll
        for (int q = 0; q < 4; q++) {
            int w = wt * 128 + wr + m * 16 + rq + q;
#pragma unroll
            for (int nn = 0; nn < 4; nn++) {
                int v = vt * 128 + wc + nn * 16 + cn;
                scT[((size_t)bl * 1024 + w) * 1024 + v] = fmaxf(acc[m][nn][q], 0.f);
            }
        }
}

// ---- mega prop order-1: P1all[j][b][r][w] = f16( Z[b][r]·M[j] ), z = j*8+b ----
__global__ __launch_bounds__(256) void k_prop1m(const f16* __restrict__ ZT,
                                                const f16* __restrict__ aT,
                                                const f16* __restrict__ attT,
                                                f16* __restrict__ P1all) {
    __shared__ char As[16384], Bs[16384];
    int z = blockIdx.z, j = z >> 3, b = z & 7;
    int rt = blockIdx.y, wt = blockIdx.x, t = threadIdx.x;
    const char* Ag = (const char*)(ZT + ((size_t)b * 768 + rt * 128) * 1024);
    const char* Bg = (const char*)(pair_B(aT, attT, j, b) + (size_t)wt * 128 * 1024);
    f32x4 acc[4][4];
    zero_acc(acc);
    for (int kt = 0; kt < 16; kt++) {
        stage_tile(Ag + kt * 128, 2048, As, t);
        stage_tile(Bg + kt * 128, 2048, Bs, t);
        __syncthreads();
        mma_tile(As, Bs, t, acc);
        __syncthreads();
    }
    f16* P1 = P1all + (size_t)j * 6291456;
    int lane = t & 63, wid = t >> 6;
    int wr = (wid >> 1) * 64, wc = (wid & 1) * 64;
    int cn = lane & 15, rq = (lane >> 4) * 4;
#pragma unroll
    for (int m = 0; m < 4; m++)
#pragma unroll
        for (int q = 0; q < 4; q++) {
            int r = rt * 128 + wr + m * 16 + rq + q;
            size_t pbase = ((size_t)b * 768 + r) * 1024;
#pragma unroll
            for (int nn = 0; nn < 4; nn++) {
                int w = wt * 128 + wc + nn * 16 + cn;
                P1[pbase + w] = (f16)acc[m][nn][q];
            }
        }
}

// ---- mega prop order-2: P2all[j] = P1all[j]·M[j] ----
__global__ __launch_bounds__(256) void k_prop2m(const f16* __restrict__ P1all,
                                                const f16* __restrict__ aT,
                                                const f16* __restrict__ attT,
                                                f16* __restrict__ P2all) {
    __shared__ char As[16384], Bs[16384];
    int z = blockIdx.z, j = z >> 3, b = z & 7;
    int rt = blockIdx.y, wt = blockIdx.x, t = threadIdx.x;
    const char* Ag = (const char*)(P1all + (size_t)j * 6291456 +
                                   ((size_t)b * 768 + rt * 128) * 1024);
    const char* Bg = (const char*)(pair_B(aT, attT, j, b) + (size_t)wt * 128 * 1024);
    f32x4 acc[4][4];
    zero_acc(acc);
    for (int kt = 0; kt < 16; kt++) {
        stage_tile(Ag + kt * 128, 2048, As, t);
        stage_tile(Bg + kt * 128, 2048, Bs, t);
        __syncthreads();
        mma_tile(As, Bs, t, acc);
        __syncthreads();
    }
    f16* P2 = P2all + (size_t)j * 6291456;
    int lane = t & 63, wid = t >> 6;
    int wr = (wid >> 1) * 64, wc = (wid & 1) * 64;
    int cn = lane & 15, rq = (lane >> 4) * 4;
#pragma unroll
    for (int m = 0; m < 4; m++)
#pragma unroll
        for (int q = 0; q < 4; q++) {
            int r = rt * 128 + wr + m * 16 + rq + q;
            size_t pbase = ((size_t)b * 768 + r) * 1024;
#pragma unroll
            for (int nn = 0; nn < 4; nn++) {
                int w = wt * 128 + wc + nn * 16 + cn;
                P2[pbase + w] = (f16)acc[m][nn][q];
            }
        }
}

// ---- fallback sequential props (used if workspace too small) ----
__global__ __launch_bounds__(256) void k_prop1g(const f16* __restrict__ A0,
                                                const f16* __restrict__ B0, size_t bsB,
                                                f16* __restrict__ P1) {
    __shared__ char As[16384], Bs[16384];
    int b = blockIdx.z, rt = blockIdx.y, wt = blockIdx.x, t = threadIdx.x;
    const char* Ag = (const char*)(A0 + ((size_t)b * 768 + rt * 128) * 1024);
    const char* Bg = (const char*)(B0 + (size_t)b * bsB + (size_t)wt * 128 * 1024);
    f32x4 acc[4][4];
    zero_acc(acc);
    for (int kt = 0; kt < 16; kt++) {
        stage_tile(Ag + kt * 128, 2048, As, t);
        stage_tile(Bg + kt * 128, 2048, Bs, t);
        __syncthreads();
        mma_tile(As, Bs, t, acc);
        __syncthreads();
    }
    int lane = t & 63, wid = t >> 6;
    int wr = (wid >> 1) * 64, wc = (wid & 1) * 64;
    int cn = lane & 15, rq = (lane >> 4) * 4;
#pragma unroll
    for (int m = 0; m < 4; m++)
#pragma unroll
        for (int q = 0; q < 4; q++) {
            int r = rt * 128 + wr + m * 16 + rq + q;
            size_t pbase = ((size_t)b * 768 + r) * 1024;
#pragma unroll
            for (int nn = 0; nn < 4; nn++) {
                int w = wt * 128 + wc + nn * 16 + cn;
                P1[pbase + w] = (f16)acc[m][nn][q];
            }
        }
}

__global__ __launch_bounds__(256) void k_prop2g(const f16* __restrict__ P1,
                                                const f16* __restrict__ B0, size_t bsB,
                                                f16* __restrict__ hacc,
                                                const float* __restrict__ gate, int gidx) {
    __shared__ char As[16384], Bs[16384];
    int b = blockIdx.z, rt = blockIdx.y, wt = blockIdx.x, t = threadIdx.x;
    const char* Ag = (const char*)(P1 + ((size_t)b * 768 + rt * 128) * 1024);
    const char* Bg = (const char*)(B0 + (size_t)b * bsB + (size_t)wt * 128 * 1024);
    f32x4 acc[4][4];
    zero_acc(acc);
    for (int kt = 0; kt < 16; kt++) {
        stage_tile(Ag + kt * 128, 2048, As, t);
        stage_tile(Bg + kt * 128, 2048, Bs, t);
        __syncthreads();
        mma_tile(As, Bs, t, acc);
        __syncthreads();
    }
    float g1 = gate[b * 13 + gidx], g2 = gate[b * 13 + gidx + 1];
    int lane = t & 63, wid = t >> 6;
    int wr = (wid >> 1) * 64, wc = (wid & 1) * 64;
    int cn = lane & 15, rq = (lane >> 4) * 4;
#pragma unroll
    for (int m = 0; m < 4; m++)
#pragma unroll
        for (int q = 0; q < 4; q++) {
            int r = rt * 128 + wr + m * 16 + rq + q;
            size_t pbase = ((size_t)b * 768 + r) * 1024;
#pragma unroll
            for (int nn = 0; nn < 4; nn++) {
                int w = wt * 128 + wc + nn * 16 + cn;
                float p1v = (float)P1[pbase + w];
                float hv = (float)hacc[pbase + w];
                hacc[pbase + w] = (f16)(hv + g1 * p1v + g2 * acc[m][nn][q]);
            }
        }
}

// ================= softmax / stats / gate ===================================

__global__ void k_softmax2(const float* __restrict__ scT, const f16* __restrict__ aT,
                           f16* __restrict__ attT, int h, int bh) {
    int gw = blockIdx.x * 4 + (threadIdx.x >> 6);  // bl*1024 + w
    int bl = gw >> 10, w = gw & 1023;
    int lane = threadIdx.x & 63;
    const float* sp = scT + (size_t)gw * 1024;
    float e[16];
#pragma unroll
    for (int k = 0; k < 16; k++) e[k] = sp[k * 64 + lane];
#pragma unroll
    for (int s = 0; s < 2; s++) {
        const f16* ap = aT + ((size_t)s * 1024 + w) * 1024;
        float xx[16];
        float m = NEGV;
#pragma unroll
        for (int k = 0; k < 16; k++) {
            int v = k * 64 + lane;
            xx[k] = ((float)ap[v] > 0.f) ? e[k] : NEGV;
            m = fmaxf(m, xx[k]);
        }
#pragma unroll
        for (int off = 1; off < 64; off <<= 1) m = fmaxf(m, __shfl_xor(m, off));
        float ssum = 0.f;
#pragma unroll
        for (int k = 0; k < 16; k++) {
            xx[k] = __expf(xx[k] - m);
            ssum += xx[k];
        }
#pragma unroll
        for (int off = 1; off < 64; off <<= 1) ssum += __shfl_xor(ssum, off);
        float inv = 1.f / ssum;
        f16* op = attT + (size_t)(s * 2 + h) * 8 * 1048576 +
                  (((size_t)(bh * 4 + bl)) * 1024 + w) * 1024;
#pragma unroll
        for (int k = 0; k < 16; k++) op[k * 64 + lane] = (f16)(xx[k] * inv);
    }
}

template <int ORDER>
__global__ __launch_bounds__(256) void k_colsum1(
    const f16* __restrict__ aT, const f16* __restrict__ attT,
    const float* __restrict__ ra, const float* __restrict__ ratt,
    float* __restrict__ partial) {
    int u = blockIdx.y, rc = blockIdx.x;          // rc 0..15
    int t = threadIdx.x;
    int lane7 = t & 127, rh = t >> 7;
    int v0 = lane7 * 8;
    const f16* M = (u < 2) ? aT + (size_t)u * 1048576
                           : attT + (size_t)(u - 2) * 1048576;
    const float* rin = nullptr;
    if (ORDER) rin = (u < 2) ? ra + (size_t)u * 2048 : ratt + (size_t)(u - 2) * 2048;
    float acc[8] = {};
    int row0 = rc * 64 + rh * 32;
#pragma unroll 4
    for (int i = 0; i < 32; i++) {
        int row = row0 + i;
        f16x8 mv = *reinterpret_cast<const f16x8*>(M + (size_t)row * 1024 + v0);
        float sc = ORDER ? rin[row] : 1.f;
#pragma unroll
        for (int j = 0; j < 8; j++) acc[j] += (float)mv[j] * sc;
    }
    float* pp = partial + ((size_t)u * 32 + rc * 2 + rh) * 1024 + v0;
#pragma unroll
    for (int j = 0; j < 8; j++) pp[j] = acc[j];
}

template <int ORDER>
__global__ void k_colsum2(const float* __restrict__ partial, float* __restrict__ ra,
                          float* __restrict__ ratt) {
    int u = blockIdx.x, t = threadIdx.x;
    for (int v = t; v < 1024; v += 256) {
        float s = 0.f;
#pragma unroll
        for (int k = 0; k < 32; k++) s += partial[((size_t)u * 32 + k) * 1024 + v];
        float* out = (u < 2) ? ra + (size_t)u * 2048 : ratt + (size_t)(u - 2) * 2048;
        out[ORDER * 1024 + v] = s;
    }
}

__global__ void k_feat13(const float* __restrict__ xl, const float* __restrict__ ra,
                         const float* __restrict__ ratt, float* __restrict__ feats) {
    int bd = blockIdx.x;
    int b = bd >> 6, d = bd & 63;
    const float* xp = xl + (size_t)bd * 1024;
    int t = threadIdx.x;
    float s[13];
#pragma unroll
    for (int i = 0; i < 13; i++) s[i] = 0.f;
    for (int v = t; v < 1024; v += 256) {
        float xv = xp[v];
        s[0] += xv;
#pragma unroll
        for (int ss = 0; ss < 2; ss++) {
            s[1 + ss * 6 + 0] += xv * ra[ss * 2048 + v];
            s[1 + ss * 6 + 1] += xv * ra[ss * 2048 + 1024 + v];
#pragma unroll
            for (int hh = 0; hh < 2; hh++) {
                const float* rb = ratt + (((size_t)(ss * 2 + hh) * 8 + b)) * 2048;
                s[1 + ss * 6 + 2 + hh * 2] += xv * rb[v];
                s[1 + ss * 6 + 3 + hh * 2] += xv * rb[1024 + v];
            }
        }
    }
    int wid = t >> 6, lane = t & 63;
#pragma unroll
    for (int i = 0; i < 13; i++)
#pragma unroll
        for (int off = 1; off < 64; off <<= 1) s[i] += __shfl_xor(s[i], off);
    __shared__ float red[13][4];
    if (lane == 0)
#pragma unroll
        for (int i = 0; i < 13; i++) red[i][wid] = s[i];
    __syncthreads();
    if (t < 13) {
        float tot = red[t][0] + red[t][1] + red[t][2] + red[t][3];
        feats[(size_t)b * 832 + t * 64 + d] = tot * (1.f / (1024.f * 12.f));
    }
}

__global__ void k_gate(const float* __restrict__ feats, const float* __restrict__ aw,
                       const float* __restrict__ ab, float* __restrict__ gate) {
    int b = blockIdx.x, t = threadIdx.x;
    __shared__ float lg[13];
    if (t < 13) {
        float s = ab[t];
        const float* f = feats + (size_t)b * 832;
        const float* w = aw + (size_t)t * 832;
        for (int k = 0; k < 832; k++) s += f[k] * w[k];
        lg[t] = s;
    }
    __syncthreads();
    if (t == 0) {
        float m = lg[0];
        for (int j = 1; j < 13; j++) m = fmaxf(m, lg[j]);
        float ss = 0.f;
        for (int j = 0; j < 13; j++) ss += __expf(lg[j] - m);
        float inv = 1.f / ss;
        for (int j = 0; j < 13; j++) gate[b * 13 + j] = __expf(lg[j] - m) * inv;
    }
}

// ---------- z-projection, in place on XT, LDS-staged ----------
__global__ __launch_bounds__(256) void k_zt2(f16* __restrict__ XT,
                                             const float* __restrict__ fw) {
    __shared__ f16 xs[64][136];     // 64 d-rows x 128 n (pad 8 f16)
    __shared__ float fws[64][64];   // fws[o][d] = fw[o][d]
    int nt = blockIdx.x, l = blockIdx.y, b = blockIdx.z;
    int t = threadIdx.x;
    f16* base = XT + (size_t)b * 786432 + (size_t)l * 1024 + nt * 128;
#pragma unroll
    for (int it = 0; it < 4; it++) {
        int idx = it * 256 + t;
        int row = idx >> 4, c = idx & 15;
        *reinterpret_cast<f16x8*>(&xs[row][c * 8]) =
            *reinterpret_cast<const f16x8*>(base + (size_t)row * 12288 + c * 8);
    }
    for (int i = t; i < 4096; i += 256) ((float*)fws)[i] = fw[i];
    __syncthreads();
    int nl = t & 31, og = t >> 5;   // n-quad, o-group (8 o each)
    float acc[8][4];
#pragma unroll
    for (int oo = 0; oo < 8; oo++)
#pragma unroll
        for (int j = 0; j < 4; j++) acc[oo][j] = 0.f;
#pragma unroll 4
    for (int d = 0; d < 64; d++) {
        f16x4 xv = *reinterpret_cast<const f16x4*>(&xs[d][nl * 4]);
        float x0 = (float)xv[0], x1 = (float)xv[1], x2 = (float)xv[2], x3 = (float)xv[3];
#pragma unroll
        for (int oo = 0; oo < 8; oo++) {
            float w = fws[og * 8 + oo][d];
            acc[oo][0] += w * x0; acc[oo][1] += w * x1;
            acc[oo][2] += w * x2; acc[oo][3] += w * x3;
        }
    }
#pragma unroll
    for (int oo = 0; oo < 8; oo++) {
        int o = og * 8 + oo;
        f16x4 ov;
        ov[0] = (f16)acc[oo][0]; ov[1] = (f16)acc[oo][1];
        ov[2] = (f16)acc[oo][2]; ov[3] = (f16)acc[oo][3];
        *reinterpret_cast<f16x4*>(base + (size_t)o * 12288 + nl * 4) = ov;
    }
}

// ---- mega final: out = fb + g0*Z + sum_j (g1j*P1[j] + g2j*P2[j]), layout fix ----
__global__ void k_out(const f16* __restrict__ ZT, const f16* __restrict__ P1all,
                      const f16* __restrict__ P2all, const float* __restrict__ gate,
                      const float* __restrict__ fb, float* __restrict__ out) {
    int idx = blockIdx.x * 256 + threadIdx.x;     // (b,o,n), n fastest
    int n = idx & 1023, o = (idx >> 10) & 63, b = idx >> 16;
    const float* g = gate + b * 13;
    size_t rowbase = ((size_t)b * 768 + o * 12) * 1024 + n;
    float v[12];
    float g0 = g[0], fbv = fb[o];
#pragma unroll
    for (int l = 0; l < 12; l++)
        v[l] = fbv + g0 * (float)ZT[rowbase + (size_t)l * 1024];
#pragma unroll
    for (int j = 0; j < 6; j++) {
        float g1 = g[1 + 2 * j], g2 = g[2 + 2 * j];
        const f16* p1 = P1all + (size_t)j * 6291456 + rowbase;
        const f16* p2 = P2all + (size_t)j * 6291456 + rowbase;
#pragma unroll
        for (int l = 0; l < 12; l++)
            v[l] += g1 * (float)p1[(size_t)l * 1024] + g2 * (float)p2[(size_t)l * 1024];
    }
    float4* dst = reinterpret_cast<float4*>(out + (((size_t)b * 64 + o) * 1024 + n) * 12);
    float4 o0 = {v[0], v[1], v[2], v[3]};
    float4 o1 = {v[4], v[5], v[6], v[7]};
    float4 o2 = {v[8], v[9], v[10], v[11]};
    dst[0] = o0; dst[1] = o1; dst[2] = o2;
}

// ---- fallback final pieces ----
__global__ void k_hinit2(const f16* __restrict__ ZT, const float* __restrict__ gate,
                         f16* __restrict__ hacc) {
    size_t i8 = (size_t)blockIdx.x * 256 + threadIdx.x;
    int b = (int)(i8 / 98304);
    float g = gate[b * 13];
    f16x8 v = *reinterpret_cast<const f16x8*>(ZT + i8 * 8);
    f16x8 o;
#pragma unroll
    for (int j = 0; j < 8; j++) o[j] = (f16)(g * (float)v[j]);
    *reinterpret_cast<f16x8*>(hacc + i8 * 8) = o;
}

__global__ void k_biasout(const f16* __restrict__ hacc, const float* __restrict__ fb,
                          float* __restrict__ out) {
    int idx = blockIdx.x * 256 + threadIdx.x;
    int n = idx & 1023, o = (idx >> 10) & 63, b = idx >> 16;
    float fbv = fb[o];
    float v[12];
#pragma unroll
    for (int l = 0; l < 12; l++)
        v[l] = (float)hacc[((size_t)b * 768 + o * 12 + l) * 1024 + n] + fbv;
    float4* dst = reinterpret_cast<float4*>(out + (((size_t)b * 64 + o) * 1024 + n) * 12);
    float4 o0 = {v[0], v[1], v[2], v[3]};
    float4 o1 = {v[4], v[5], v[6], v[7]};
    float4 o2 = {v[8], v[9], v[10], v[11]};
    dst[0] = o0; dst[1] = o1; dst[2] = o2;
}

// ================= launch ===================================================

extern "C" void kernel_launch(void* const* d_in, const int* in_sizes, int n_in,
                              void* d_out, int out_size, void* d_ws, size_t ws_size,
                              hipStream_t stream) {
    const float* x   = (const float*)d_in[0];
    const float* sup = (const float*)d_in[1];
    const float* nv1 = (const float*)d_in[2];
    const float* nv2 = (const float*)d_in[3];
    const float* kw  = (const float*)d_in[4];
    const float* kb  = (const float*)d_in[5];
    const float* qw  = (const float*)d_in[6];
    const float* qb  = (const float*)d_in[7];
    const float* aw  = (const float*)d_in[8];
    const float* ab  = (const float*)d_in[9];
    const float* fw  = (const float*)d_in[10];
    const float* fb  = (const float*)d_in[11];
    float* hout = (float*)d_out;

    float* wsf = (float*)d_ws;
    size_t o = 0;
    f16*   XT     = (f16*)(wsf + o);  o += 3145728;   // [8][768][1024] f16 (becomes ZT)
    float* attReg = wsf + o;          o += 16777216;  // attT [4][8][1024][1024] f16
    f16*   attT   = (f16*)attReg;
    f16*   xT2    = (f16*)attReg;                     // overlay (dead before attT)
    f16*   aT     = (f16*)(wsf + o);  o += 1048576;   // [2][1024][1024] f16
    float* gate   = wsf + o;          o += 128;
    size_t rc = o;                                    // phase-union region
    // ---- phase A (through k_gate) ----
    size_t oA = rc;
    float* scT    = wsf + oA;          oA += 4194304;  // [4][1024][1024] f32
    f16*   keysT  = (f16*)(wsf + oA);  oA += 2097152;
    f16*   kwb    = (f16*)(wsf + oA);  oA += 196608;
    float* kwl    = wsf + oA;          oA += 32768;
    float* tkq    = wsf + oA;          oA += 524288;
    float* xl     = wsf + oA;          oA += 524288;
    float* ra     = wsf + oA;          oA += 4096;
    float* ratt   = wsf + oA;          oA += 65536;
    float* feats  = wsf + oA;          oA += 6656;
    float* partial= wsf + oA;          oA += 1114112;
    // ---- phase B mega (preferred): P1all + P2all, 6 pairs ----
    size_t oBm = rc;
    f16*   P1all  = (f16*)(wsf + oBm); oBm += 18874368; // 6*[8][768][1024] f16
    f16*   P2all  = (f16*)(wsf + oBm); oBm += 18874368;
    // ---- phase B fallback ----
    size_t oBf = rc;
    f16*   P1f    = (f16*)(wsf + oBf); oBf += 3145728;
    f16*   haccf  = (f16*)(wsf + oBf); oBf += 3145728;
    bool mega = ws_size >= ((oA > oBm ? oA : oBm) * 4);
    if (!mega && ws_size < ((oA > oBf ? oA : oBf) * 4)) return;

    f16* ZT = XT;   // after k_zt2, XT region holds ZT

    k_xt<<<2048, 256, 0, stream>>>(x, XT, xl);
    k_xt2<<<dim3(16, 4, 8), 256, 0, stream>>>(x, xT2);
    k_wcvt<<<128, 256, 0, stream>>>(kw, qw, kwl, kwb);
    k_tkq<<<2048, 256, 0, stream>>>(kwl, nv1, nv2, kb, qb, tkq);
    k_acvt<<<dim3(16, 16, 2), 256, 0, stream>>>(sup, aT);

    k_kqgemm<<<dim3(8, 1, 32), 256, 0, stream>>>(xT2, kwb, tkq, keysT);

    for (int h = 0; h < 2; h++)
        for (int bh = 0; bh < 2; bh++) {
            k_scoregemm<<<dim3(8, 8, 4), 256, 0, stream>>>(keysT, scT, h, bh);
            k_softmax2<<<1024, 256, 0, stream>>>(scT, aT, attT, h, bh);
        }

    k_colsum1<0><<<dim3(16, 34), 256, 0, stream>>>(aT, attT, ra, ratt, partial);
    k_colsum2<0><<<34, 256, 0, stream>>>(partial, ra, ratt);
    k_colsum1<1><<<dim3(16, 34), 256, 0, stream>>>(aT, attT, ra, ratt, partial);
    k_colsum2<1><<<34, 256, 0, stream>>>(partial, ra, ratt);
    k_feat13<<<512, 256, 0, stream>>>(xl, ra, ratt, feats);
    k_gate<<<8, 64, 0, stream>>>(feats, aw, ab, gate);

    // ---- phase B: project to o-domain, propagate, gated output ----
    k_zt2<<<dim3(8, 12, 8), 256, 0, stream>>>(XT, fw);

    if (mega) {
        k_prop1m<<<dim3(8, 6, 48), 256, 0, stream>>>(ZT, aT, attT, P1all);
        k_prop2m<<<dim3(8, 6, 48), 256, 0, stream>>>(P1all, aT, attT, P2all);
        k_out<<<2048, 256, 0, stream>>>(ZT, P1all, P2all, gate, fb, hout);
    } else {
        k_hinit2<<<3072, 256, 0, stream>>>(ZT, gate, haccf);
        for (int s = 0; s < 2; s++)
            for (int kind = 0; kind < 3; kind++) {
                const f16* B0;
                size_t bsB;
                if (kind == 0) { B0 = aT + (size_t)s * 1048576; bsB = 0; }
                else { B0 = attT + (size_t)((s * 2 + kind - 1) * 8) * 1048576; bsB = 1048576; }
                int g1 = 1 + s * 6 + 2 * kind;
                k_prop1g<<<dim3(8, 6, 8), 256, 0, stream>>>(ZT, B0, bsB, P1f);
                k_prop2g<<<dim3(8, 6, 8), 256, 0, stream>>>(P1f, B0, bsB, haccf, gate, g1);
            }
        k_biasout<<<2048, 256, 0, stream>>>(haccf, fb, hout);
    }
}

// Round 9
// 381.018 us; speedup vs baseline: 11.1630x; 1.2182x over previous
//
#include <hip/hip_runtime.h>
#include <hip/hip_bf16.h>

#define BB 8
#define DD 64
#define NNODE 1024
#define LLL 12
#define EE 128
#define NEGV -9.0e15f

typedef _Float16 f16;
typedef _Float16 f16x4 __attribute__((ext_vector_type(4)));
typedef _Float16 f16x8 __attribute__((ext_vector_type(8)));
typedef float f32x4 __attribute__((ext_vector_type(4)));

// ================= GEMM core helpers (128x128 tile, BK=64, 4 waves) =========

__device__ __forceinline__ void stage_tile(const char* g, int ld, char* lds, int t) {
    int wid = t >> 6, lane = t & 63;
#pragma unroll
    for (int it = 0; it < 4; it++) {
        int cbase = it * 256 + wid * 64;          // wave-uniform chunk base
        int c = cbase + lane;
        int row = c >> 3, p = c & 7;
        int gch = p ^ (row & 7);                  // inverse swizzle on SOURCE
        const char* src = g + (size_t)row * ld + gch * 16;
        char* dst = lds + (size_t)cbase * 16;     // wave-uniform; lane*16 implicit
        __builtin_amdgcn_global_load_lds(
            (const __attribute__((address_space(1))) unsigned int*)src,
            (__attribute__((address_space(3))) unsigned int*)dst, 16, 0, 0);
    }
}

__device__ __forceinline__ void mma_tile(const char* As, const char* Bs, int t,
                                         f32x4 acc[4][4]) {
    int lane = t & 63, wid = t >> 6;
    int wr = (wid >> 1) * 64, wc = (wid & 1) * 64;
    int lrow = lane & 15, lk = lane >> 4;
#pragma unroll
    for (int kk = 0; kk < 2; kk++) {
        f16x8 af[4], bf[4];
#pragma unroll
        for (int m = 0; m < 4; m++) {
            int row = wr + m * 16 + lrow;
            int p = (kk * 4 + lk) ^ (row & 7);    // swizzled read
            af[m] = *(const f16x8*)(As + row * 128 + p * 16);
        }
#pragma unroll
        for (int n = 0; n < 4; n++) {
            int row = wc + n * 16 + lrow;
            int p = (kk * 4 + lk) ^ (row & 7);
            bf[n] = *(const f16x8*)(Bs + row * 128 + p * 16);
        }
#pragma unroll
        for (int m = 0; m < 4; m++)
#pragma unroll
            for (int n = 0; n < 4; n++)
                acc[m][n] = __builtin_amdgcn_mfma_f32_16x16x32_f16(
                    af[m], bf[n], acc[m][n], 0, 0, 0);
    }
}

__device__ __forceinline__ void zero_acc(f32x4 acc[4][4]) {
#pragma unroll
    for (int m = 0; m < 4; m++)
#pragma unroll
        for (int n = 0; n < 4; n++)
#pragma unroll
            for (int q = 0; q < 4; q++) acc[m][n][q] = 0.f;
}

// Map pair index j (0..5) to its B matrix base (aT shared over b, attT per b).
__device__ __forceinline__ const f16* pair_B(const f16* aT, const f16* attT,
                                             int j, int b) {
    if (j == 0) return aT;
    if (j == 3) return aT + 1048576;
    int idx = (j < 3) ? (j - 1) : (j - 2);        // att slot 0..3
    return attT + (size_t)idx * 8388608 + (size_t)b * 1048576;
}

// ================= prep kernels =============================================

// XT[b][(d,l)][v] f16 + xl[b,d,v] = sum_l x
__global__ void k_xt(const float* __restrict__ x, f16* __restrict__ XT,
                     float* __restrict__ xl) {
    int i = blockIdx.x * 256 + threadIdx.x;       // (b,d,v)
    int v = i & 1023, d = (i >> 10) & 63, b = i >> 16;
    const float4* p = reinterpret_cast<const float4*>(x + (size_t)i * 12);
    float4 a = p[0], c = p[1], e = p[2];
    float vv[12] = {a.x, a.y, a.z, a.w, c.x, c.y, c.z, c.w, e.x, e.y, e.z, e.w};
    float ssum = 0.f;
    size_t base = ((size_t)b * 768) * 1024 + v;
    int r0 = d * 12;
#pragma unroll
    for (int l = 0; l < 12; l++) {
        ssum += vv[l];
        XT[base + (size_t)(r0 + l) * 1024] = (f16)vv[l];
    }
    xl[i] = ssum;
}

// xT2[b][n][(d,l)] f16 via LDS transpose of 16d x 64n tiles
__global__ __launch_bounds__(256) void k_xt2(const float* __restrict__ x,
                                             f16* __restrict__ xT2) {
    __shared__ f16 Ls[64][208];
    int b = blockIdx.z, d0 = blockIdx.y * 16, n0 = blockIdx.x * 64, t = threadIdx.x;
    for (int f = t; f < 3072; f += 256) {
        int dd = f / 192, rem = f - dd * 192, j = rem / 3, q = rem - j * 3;
        float4 v = *reinterpret_cast<const float4*>(
            x + (((size_t)(b * 64 + d0 + dd) * 1024) + n0 + j) * 12 + q * 4);
        f16* dst = &Ls[j][dd * 12 + q * 4];
        dst[0] = (f16)v.x; dst[1] = (f16)v.y; dst[2] = (f16)v.z; dst[3] = (f16)v.w;
    }
    __syncthreads();
    for (int c = t; c < 1536; c += 256) {
        int j = c / 24, p = c - j * 24;
        *reinterpret_cast<f16x8*>(
            xT2 + ((size_t)(b * 1024) + n0 + j) * 768 + d0 * 12 + p * 8) =
            *reinterpret_cast<const f16x8*>(&Ls[j][p * 8]);
    }
}

// kwb[var][e][768] f16, kwl[var][e][d] = sum_l w
__global__ void k_wcvt(const float* __restrict__ kw, const float* __restrict__ qw,
                       float* __restrict__ kwl, f16* __restrict__ kwb) {
    int i = blockIdx.x * 256 + threadIdx.x;       // (var,e,d)
    int d = i & 63, e = (i >> 6) & 127, var = i >> 13;
    const float* src = (var < 2 ? kw + (size_t)var * 98304
                                : qw + (size_t)(var - 2) * 98304) +
                       ((size_t)e * 64 + d) * 12;
    f16* dst = kwb + ((size_t)var * 128 + e) * 768 + d * 12;
    float ssum = 0.f;
#pragma unroll
    for (int l = 0; l < 12; l++) {
        float v = src[l];
        ssum += v;
        dst[l] = (f16)v;
    }
    kwl[i] = ssum;
}

// tkq[var][n][e] = sum_d kwl[var][e][d]*nv + bias[var][e]
__global__ void k_tkq(const float* __restrict__ kwl, const float* __restrict__ nv1,
                      const float* __restrict__ nv2, const float* __restrict__ kb,
                      const float* __restrict__ qb, float* __restrict__ tkq) {
    int i = blockIdx.x * 256 + threadIdx.x;       // (var,n,e)
    int e = i & 127, n = (i >> 7) & 1023, var = i >> 17;
    float ssum = (var < 2) ? kb[var * 128 + e] : qb[(var - 2) * 128 + e];
    const float* wl = kwl + ((size_t)var * 128 + e) * 64;
    if (var < 2) {
        const float* nvp = nv1 + (size_t)n * 64;
#pragma unroll 8
        for (int d = 0; d < 64; d++) ssum += wl[d] * nvp[d];
    } else {
#pragma unroll 8
        for (int d = 0; d < 64; d++) ssum += wl[d] * nv2[(size_t)d * 1024 + n];
    }
    tkq[i] = ssum;
}

// aT[s][w][v] f16 (transpose of support)
__global__ void k_acvt(const float* __restrict__ sup, f16* __restrict__ aT) {
    __shared__ float Ls[64][65];
    int s = blockIdx.z, v0 = blockIdx.y * 64, w0 = blockIdx.x * 64, t = threadIdx.x;
    int j = t & 63, i0 = t >> 6;
    for (int i = i0; i < 64; i += 4)
        Ls[i][j] = sup[((size_t)s * 1024 + v0 + i) * 1024 + w0 + j];
    __syncthreads();
    for (int i = i0; i < 64; i += 4)
        aT[((size_t)s * 1024 + w0 + i) * 1024 + v0 + j] = (f16)Ls[j][i];
}

// ================= MFMA GEMM kernels ========================================

// keysT[var][b][n][e] = sum_dl xT2[b][n][dl]*kwb[var][e][dl] + tkq[var][n][e]
__global__ __launch_bounds__(256) void k_kqgemm(const f16* __restrict__ xT2,
                                                const f16* __restrict__ kwb,
                                                const float* __restrict__ tkq,
                                                f16* __restrict__ keysT) {
    __shared__ char As[16384], Bs[16384];
    int z = blockIdx.z, var = z >> 3, b = z & 7;
    int nt = blockIdx.x, t = threadIdx.x;
    const char* Ag = (const char*)(xT2 + ((size_t)b * 1024 + nt * 128) * 768);
    const char* Bg = (const char*)(kwb + (size_t)var * 128 * 768);
    f32x4 acc[4][4];
    zero_acc(acc);
    for (int kt = 0; kt < 12; kt++) {
        stage_tile(Ag + kt * 128, 1536, As, t);
        stage_tile(Bg + kt * 128, 1536, Bs, t);
        __syncthreads();
        mma_tile(As, Bs, t, acc);
        __syncthreads();
    }
    int lane = t & 63, wid = t >> 6;
    int wr = (wid >> 1) * 64, wc = (wid & 1) * 64;
    int cn = lane & 15, rq = (lane >> 4) * 4;
#pragma unroll
    for (int m = 0; m < 4; m++)
#pragma unroll
        for (int q = 0; q < 4; q++) {
            int n_g = nt * 128 + wr + m * 16 + rq + q;
#pragma unroll
            for (int nn = 0; nn < 4; nn++) {
                int e = wc + nn * 16 + cn;
                float v = acc[m][nn][q] + tkq[((size_t)var * 1024 + n_g) * 128 + e];
                keysT[(((size_t)var * 8 + b) * 1024 + n_g) * 128 + e] = (f16)v;
            }
        }
}

// scTall[h][b][w][v] = relu(sum_e query[w,e]*keys[v,e]) — one launch, z=h*8+b
__global__ __launch_bounds__(256) void k_scoregemm2(const f16* __restrict__ keysT,
                                                    float* __restrict__ scTall) {
    __shared__ char As[16384], Bs[16384];
    int z = blockIdx.z, h = z >> 3, b = z & 7;
    int wt = blockIdx.y, vt = blockIdx.x, t = threadIdx.x;
    const char* Ag = (const char*)(keysT + (((size_t)(2 + h) * 8 + b) * 1024 + wt * 128) * 128);
    const char* Bg = (const char*)(keysT + (((size_t)h * 8 + b) * 1024 + vt * 128) * 128);
    f32x4 acc[4][4];
    zero_acc(acc);
    for (int kt = 0; kt < 2; kt++) {
        stage_tile(Ag + kt * 128, 256, As, t);
        stage_tile(Bg + kt * 128, 256, Bs, t);
        __syncthreads();
        mma_tile(As, Bs, t, acc);
        __syncthreads();
    }
    int lane = t & 63, wid = t >> 6;
    int wr = (wid >> 1) * 64, wc = (wid & 1) * 64;
    int cn = lane & 15, rq = (lane >> 4) * 4;
#pragma unroll
    for (int m = 0; m < 4; m++)
#pragma unroll
        for (int q = 0; q < 4; q++) {
            int w = wt * 128 + wr + m * 16 + rq + q;
#pragma unroll
            for (int nn = 0; nn < 4; nn++) {
                int v = vt * 128 + wc + nn * 16 + cn;
                scTall[((size_t)z * 1024 + w) * 1024 + v] = fmaxf(acc[m][nn][q], 0.f);
            }
        }
}

// ---- mega prop order-1 (XCD-chunk swizzled 1D grid, 2304 blocks) ----
__global__ __launch_bounds__(256) void k_prop1m(const f16* __restrict__ ZT,
                                                const f16* __restrict__ aT,
                                                const f16* __restrict__ attT,
                                                f16* __restrict__ P1all) {
    __shared__ char As[16384], Bs[16384];
    int bid = blockIdx.x;
    int swz = (bid & 7) * 288 + (bid >> 3);       // bijective: 2304 % 8 == 0
    int wt = swz & 7, rt = (swz >> 3) % 6, z = swz / 48;
    int j = z >> 3, b = z & 7;
    int t = threadIdx.x;
    const char* Ag = (const char*)(ZT + ((size_t)b * 768 + rt * 128) * 1024);
    const char* Bg = (const char*)(pair_B(aT, attT, j, b) + (size_t)wt * 128 * 1024);
    f32x4 acc[4][4];
    zero_acc(acc);
    for (int kt = 0; kt < 16; kt++) {
        stage_tile(Ag + kt * 128, 2048, As, t);
        stage_tile(Bg + kt * 128, 2048, Bs, t);
        __syncthreads();
        mma_tile(As, Bs, t, acc);
        __syncthreads();
    }
    f16* P1 = P1all + (size_t)j * 6291456;
    int lane = t & 63, wid = t >> 6;
    int wr = (wid >> 1) * 64, wc = (wid & 1) * 64;
    int cn = lane & 15, rq = (lane >> 4) * 4;
#pragma unroll
    for (int m = 0; m < 4; m++)
#pragma unroll
        for (int q = 0; q < 4; q++) {
            int r = rt * 128 + wr + m * 16 + rq + q;
            size_t pbase = ((size_t)b * 768 + r) * 1024;
#pragma unroll
            for (int nn = 0; nn < 4; nn++) {
                int w = wt * 128 + wc + nn * 16 + cn;
                P1[pbase + w] = (f16)acc[m][nn][q];
            }
        }
}

// ---- mega prop order-2 (XCD-chunk swizzled) ----
__global__ __launch_bounds__(256) void k_prop2m(const f16* __restrict__ P1all,
                                                const f16* __restrict__ aT,
                                                const f16* __restrict__ attT,
                                                f16* __restrict__ P2all) {
    __shared__ char As[16384], Bs[16384];
    int bid = blockIdx.x;
    int swz = (bid & 7) * 288 + (bid >> 3);
    int wt = swz & 7, rt = (swz >> 3) % 6, z = swz / 48;
    int j = z >> 3, b = z & 7;
    int t = threadIdx.x;
    const char* Ag = (const char*)(P1all + (size_t)j * 6291456 +
                                   ((size_t)b * 768 + rt * 128) * 1024);
    const char* Bg = (const char*)(pair_B(aT, attT, j, b) + (size_t)wt * 128 * 1024);
    f32x4 acc[4][4];
    zero_acc(acc);
    for (int kt = 0; kt < 16; kt++) {
        stage_tile(Ag + kt * 128, 2048, As, t);
        stage_tile(Bg + kt * 128, 2048, Bs, t);
        __syncthreads();
        mma_tile(As, Bs, t, acc);
        __syncthreads();
    }
    f16* P2 = P2all + (size_t)j * 6291456;
    int lane = t & 63, wid = t >> 6;
    int wr = (wid >> 1) * 64, wc = (wid & 1) * 64;
    int cn = lane & 15, rq = (lane >> 4) * 4;
#pragma unroll
    for (int m = 0; m < 4; m++)
#pragma unroll
        for (int q = 0; q < 4; q++) {
            int r = rt * 128 + wr + m * 16 + rq + q;
            size_t pbase = ((size_t)b * 768 + r) * 1024;
#pragma unroll
            for (int nn = 0; nn < 4; nn++) {
                int w = wt * 128 + wc + nn * 16 + cn;
                P2[pbase + w] = (f16)acc[m][nn][q];
            }
        }
}

// ---- fallback sequential props (used if workspace too small) ----
__global__ __launch_bounds__(256) void k_prop1g(const f16* __restrict__ A0,
                                                const f16* __restrict__ B0, size_t bsB,
                                                f16* __restrict__ P1) {
    __shared__ char As[16384], Bs[16384];
    int b = blockIdx.z, rt = blockIdx.y, wt = blockIdx.x, t = threadIdx.x;
    const char* Ag = (const char*)(A0 + ((size_t)b * 768 + rt * 128) * 1024);
    const char* Bg = (const char*)(B0 + (size_t)b * bsB + (size_t)wt * 128 * 1024);
    f32x4 acc[4][4];
    zero_acc(acc);
    for (int kt = 0; kt < 16; kt++) {
        stage_tile(Ag + kt * 128, 2048, As, t);
        stage_tile(Bg + kt * 128, 2048, Bs, t);
        __syncthreads();
        mma_tile(As, Bs, t, acc);
        __syncthreads();
    }
    int lane = t & 63, wid = t >> 6;
    int wr = (wid >> 1) * 64, wc = (wid & 1) * 64;
    int cn = lane & 15, rq = (lane >> 4) * 4;
#pragma unroll
    for (int m = 0; m < 4; m++)
#pragma unroll
        for (int q = 0; q < 4; q++) {
            int r = rt * 128 + wr + m * 16 + rq + q;
            size_t pbase = ((size_t)b * 768 + r) * 1024;
#pragma unroll
            for (int nn = 0; nn < 4; nn++) {
                int w = wt * 128 + wc + nn * 16 + cn;
                P1[pbase + w] = (f16)acc[m][nn][q];
            }
        }
}

__global__ __launch_bounds__(256) void k_prop2g(const f16* __restrict__ P1,
                                                const f16* __restrict__ B0, size_t bsB,
                                                f16* __restrict__ hacc,
                                                const float* __restrict__ gate, int gidx) {
    __shared__ char As[16384], Bs[16384];
    int b = blockIdx.z, rt = blockIdx.y, wt = blockIdx.x, t = threadIdx.x;
    const char* Ag = (const char*)(P1 + ((size_t)b * 768 + rt * 128) * 1024);
    const char* Bg = (const char*)(B0 + (size_t)b * bsB + (size_t)wt * 128 * 1024);
    f32x4 acc[4][4];
    zero_acc(acc);
    for (int kt = 0; kt < 16; kt++) {
        stage_tile(Ag + kt * 128, 2048, As, t);
        stage_tile(Bg + kt * 128, 2048, Bs, t);
        __syncthreads();
        mma_tile(As, Bs, t, acc);
        __syncthreads();
    }
    float g1 = gate[b * 13 + gidx], g2 = gate[b * 13 + gidx + 1];
    int lane = t & 63, wid = t >> 6;
    int wr = (wid >> 1) * 64, wc = (wid & 1) * 64;
    int cn = lane & 15, rq = (lane >> 4) * 4;
#pragma unroll
    for (int m = 0; m < 4; m++)
#pragma unroll
        for (int q = 0; q < 4; q++) {
            int r = rt * 128 + wr + m * 16 + rq + q;
            size_t pbase = ((size_t)b * 768 + r) * 1024;
#pragma unroll
            for (int nn = 0; nn < 4; nn++) {
                int w = wt * 128 + wc + nn * 16 + cn;
                float p1v = (float)P1[pbase + w];
                float hv = (float)hacc[pbase + w];
                hacc[pbase + w] = (f16)(hv + g1 * p1v + g2 * acc[m][nn][q]);
            }
        }
}

// ================= softmax / stats / gate ===================================

// one launch over all (h,b,w); fused both supports
__global__ void k_softmax3(const float* __restrict__ scTall, const f16* __restrict__ aT,
                           f16* __restrict__ attT) {
    int gw = blockIdx.x * 4 + (threadIdx.x >> 6);  // (hb)*1024 + w, gw in [0,16384)
    int w = gw & 1023, hb = gw >> 10;
    int h = hb >> 3, b = hb & 7;
    int lane = threadIdx.x & 63;
    const float* sp = scTall + (size_t)gw * 1024;
    float e[16];
#pragma unroll
    for (int k = 0; k < 16; k++) e[k] = sp[k * 64 + lane];
#pragma unroll
    for (int s = 0; s < 2; s++) {
        const f16* ap = aT + ((size_t)s * 1024 + w) * 1024;
        float xx[16];
        float m = NEGV;
#pragma unroll
        for (int k = 0; k < 16; k++) {
            int v = k * 64 + lane;
            xx[k] = ((float)ap[v] > 0.f) ? e[k] : NEGV;
            m = fmaxf(m, xx[k]);
        }
#pragma unroll
        for (int off = 1; off < 64; off <<= 1) m = fmaxf(m, __shfl_xor(m, off));
        float ssum = 0.f;
#pragma unroll
        for (int k = 0; k < 16; k++) {
            xx[k] = __expf(xx[k] - m);
            ssum += xx[k];
        }
#pragma unroll
        for (int off = 1; off < 64; off <<= 1) ssum += __shfl_xor(ssum, off);
        float inv = 1.f / ssum;
        f16* op = attT + (size_t)(s * 2 + h) * 8388608 +
                  ((size_t)b * 1024 + w) * 1024;
#pragma unroll
        for (int k = 0; k < 16; k++) op[k * 64 + lane] = (f16)(xx[k] * inv);
    }
}

template <int ORDER>
__global__ __launch_bounds__(256) void k_colsum1(
    const f16* __restrict__ aT, const f16* __restrict__ attT,
    const float* __restrict__ ra, const float* __restrict__ ratt,
    float* __restrict__ partial) {
    int u = blockIdx.y, rc = blockIdx.x;          // rc 0..15
    int t = threadIdx.x;
    int lane7 = t & 127, rh = t >> 7;
    int v0 = lane7 * 8;
    const f16* M = (u < 2) ? aT + (size_t)u * 1048576
                           : attT + (size_t)(u - 2) * 1048576;
    const float* rin = nullptr;
    if (ORDER) rin = (u < 2) ? ra + (size_t)u * 2048 : ratt + (size_t)(u - 2) * 2048;
    float acc[8] = {};
    int row0 = rc * 64 + rh * 32;
#pragma unroll 4
    for (int i = 0; i < 32; i++) {
        int row = row0 + i;
        f16x8 mv = *reinterpret_cast<const f16x8*>(M + (size_t)row * 1024 + v0);
        float sc = ORDER ? rin[row] : 1.f;
#pragma unroll
        for (int j = 0; j < 8; j++) acc[j] += (float)mv[j] * sc;
    }
    float* pp = partial + ((size_t)u * 32 + rc * 2 + rh) * 1024 + v0;
#pragma unroll
    for (int j = 0; j < 8; j++) pp[j] = acc[j];
}

template <int ORDER>
__global__ void k_colsum2(const float* __restrict__ partial, float* __restrict__ ra,
                          float* __restrict__ ratt) {
    int u = blockIdx.x, t = threadIdx.x;
    for (int v = t; v < 1024; v += 256) {
        float s = 0.f;
#pragma unroll
        for (int k = 0; k < 32; k++) s += partial[((size_t)u * 32 + k) * 1024 + v];
        float* out = (u < 2) ? ra + (size_t)u * 2048 : ratt + (size_t)(u - 2) * 2048;
        out[ORDER * 1024 + v] = s;
    }
}

__global__ void k_feat13(const float* __restrict__ xl, const float* __restrict__ ra,
                         const float* __restrict__ ratt, float* __restrict__ feats) {
    int bd = blockIdx.x;
    int b = bd >> 6, d = bd & 63;
    const float* xp = xl + (size_t)bd * 1024;
    int t = threadIdx.x;
    float s[13];
#pragma unroll
    for (int i = 0; i < 13; i++) s[i] = 0.f;
    for (int v = t; v < 1024; v += 256) {
        float xv = xp[v];
        s[0] += xv;
#pragma unroll
        for (int ss = 0; ss < 2; ss++) {
            s[1 + ss * 6 + 0] += xv * ra[ss * 2048 + v];
            s[1 + ss * 6 + 1] += xv * ra[ss * 2048 + 1024 + v];
#pragma unroll
            for (int hh = 0; hh < 2; hh++) {
                const float* rb = ratt + (((size_t)(ss * 2 + hh) * 8 + b)) * 2048;
                s[1 + ss * 6 + 2 + hh * 2] += xv * rb[v];
                s[1 + ss * 6 + 3 + hh * 2] += xv * rb[1024 + v];
            }
        }
    }
    int wid = t >> 6, lane = t & 63;
#pragma unroll
    for (int i = 0; i < 13; i++)
#pragma unroll
        for (int off = 1; off < 64; off <<= 1) s[i] += __shfl_xor(s[i], off);
    __shared__ float red[13][4];
    if (lane == 0)
#pragma unroll
        for (int i = 0; i < 13; i++) red[i][wid] = s[i];
    __syncthreads();
    if (t < 13) {
        float tot = red[t][0] + red[t][1] + red[t][2] + red[t][3];
        feats[(size_t)b * 832 + t * 64 + d] = tot * (1.f / (1024.f * 12.f));
    }
}

__global__ void k_gate(const float* __restrict__ feats, const float* __restrict__ aw,
                       const float* __restrict__ ab, float* __restrict__ gate) {
    int b = blockIdx.x, t = threadIdx.x;
    __shared__ float lg[13];
    if (t < 13) {
        float s = ab[t];
        const float* f = feats + (size_t)b * 832;
        const float* w = aw + (size_t)t * 832;
        for (int k = 0; k < 832; k++) s += f[k] * w[k];
        lg[t] = s;
    }
    __syncthreads();
    if (t == 0) {
        float m = lg[0];
        for (int j = 1; j < 13; j++) m = fmaxf(m, lg[j]);
        float ss = 0.f;
        for (int j = 0; j < 13; j++) ss += __expf(lg[j] - m);
        float inv = 1.f / ss;
        for (int j = 0; j < 13; j++) gate[b * 13 + j] = __expf(lg[j] - m) * inv;
    }
}

// ---------- z-projection, in place on XT, LDS-staged ----------
__global__ __launch_bounds__(256) void k_zt2(f16* __restrict__ XT,
                                             const float* __restrict__ fw) {
    __shared__ f16 xs[64][136];     // 64 d-rows x 128 n (pad 8 f16)
    __shared__ float fws[64][64];   // fws[o][d] = fw[o][d]
    int nt = blockIdx.x, l = blockIdx.y, b = blockIdx.z;
    int t = threadIdx.x;
    f16* base = XT + (size_t)b * 786432 + (size_t)l * 1024 + nt * 128;
#pragma unroll
    for (int it = 0; it < 4; it++) {
        int idx = it * 256 + t;
        int row = idx >> 4, c = idx & 15;
        *reinterpret_cast<f16x8*>(&xs[row][c * 8]) =
            *reinterpret_cast<const f16x8*>(base + (size_t)row * 12288 + c * 8);
    }
    for (int i = t; i < 4096; i += 256) ((float*)fws)[i] = fw[i];
    __syncthreads();
    int nl = t & 31, og = t >> 5;   // n-quad, o-group (8 o each)
    float acc[8][4];
#pragma unroll
    for (int oo = 0; oo < 8; oo++)
#pragma unroll
        for (int j = 0; j < 4; j++) acc[oo][j] = 0.f;
#pragma unroll 4
    for (int d = 0; d < 64; d++) {
        f16x4 xv = *reinterpret_cast<const f16x4*>(&xs[d][nl * 4]);
        float x0 = (float)xv[0], x1 = (float)xv[1], x2 = (float)xv[2], x3 = (float)xv[3];
#pragma unroll
        for (int oo = 0; oo < 8; oo++) {
            float w = fws[og * 8 + oo][d];
            acc[oo][0] += w * x0; acc[oo][1] += w * x1;
            acc[oo][2] += w * x2; acc[oo][3] += w * x3;
        }
    }
#pragma unroll
    for (int oo = 0; oo < 8; oo++) {
        int o = og * 8 + oo;
        f16x4 ov;
        ov[0] = (f16)acc[oo][0]; ov[1] = (f16)acc[oo][1];
        ov[2] = (f16)acc[oo][2]; ov[3] = (f16)acc[oo][3];
        *reinterpret_cast<f16x4*>(base + (size_t)o * 12288 + nl * 4) = ov;
    }
}

// ---- mega final: out = fb + g0*Z + sum_j (g1j*P1[j] + g2j*P2[j]), layout fix ----
__global__ void k_out(const f16* __restrict__ ZT, const f16* __restrict__ P1all,
                      const f16* __restrict__ P2all, const float* __restrict__ gate,
                      const float* __restrict__ fb, float* __restrict__ out) {
    int idx = blockIdx.x * 256 + threadIdx.x;     // (b,o,n), n fastest
    int n = idx & 1023, o = (idx >> 10) & 63, b = idx >> 16;
    const float* g = gate + b * 13;
    size_t rowbase = ((size_t)b * 768 + o * 12) * 1024 + n;
    float v[12];
    float g0 = g[0], fbv = fb[o];
#pragma unroll
    for (int l = 0; l < 12; l++)
        v[l] = fbv + g0 * (float)ZT[rowbase + (size_t)l * 1024];
#pragma unroll
    for (int j = 0; j < 6; j++) {
        float g1 = g[1 + 2 * j], g2 = g[2 + 2 * j];
        const f16* p1 = P1all + (size_t)j * 6291456 + rowbase;
        const f16* p2 = P2all + (size_t)j * 6291456 + rowbase;
#pragma unroll
        for (int l = 0; l < 12; l++)
            v[l] += g1 * (float)p1[(size_t)l * 1024] + g2 * (float)p2[(size_t)l * 1024];
    }
    float4* dst = reinterpret_cast<float4*>(out + (((size_t)b * 64 + o) * 1024 + n) * 12);
    float4 o0 = {v[0], v[1], v[2], v[3]};
    float4 o1 = {v[4], v[5], v[6], v[7]};
    float4 o2 = {v[8], v[9], v[10], v[11]};
    dst[0] = o0; dst[1] = o1; dst[2] = o2;
}

// ---- fallback final pieces ----
__global__ void k_hinit2(const f16* __restrict__ ZT, const float* __restrict__ gate,
                         f16* __restrict__ hacc) {
    size_t i8 = (size_t)blockIdx.x * 256 + threadIdx.x;
    int b = (int)(i8 / 98304);
    float g = gate[b * 13];
    f16x8 v = *reinterpret_cast<const f16x8*>(ZT + i8 * 8);
    f16x8 o;
#pragma unroll
    for (int j = 0; j < 8; j++) o[j] = (f16)(g * (float)v[j]);
    *reinterpret_cast<f16x8*>(hacc + i8 * 8) = o;
}

__global__ void k_biasout(const f16* __restrict__ hacc, const float* __restrict__ fb,
                          float* __restrict__ out) {
    int idx = blockIdx.x * 256 + threadIdx.x;
    int n = idx & 1023, o = (idx >> 10) & 63, b = idx >> 16;
    float fbv = fb[o];
    float v[12];
#pragma unroll
    for (int l = 0; l < 12; l++)
        v[l] = (float)hacc[((size_t)b * 768 + o * 12 + l) * 1024 + n] + fbv;
    float4* dst = reinterpret_cast<float4*>(out + (((size_t)b * 64 + o) * 1024 + n) * 12);
    float4 o0 = {v[0], v[1], v[2], v[3]};
    float4 o1 = {v[4], v[5], v[6], v[7]};
    float4 o2 = {v[8], v[9], v[10], v[11]};
    dst[0] = o0; dst[1] = o1; dst[2] = o2;
}

// ================= launch ===================================================

extern "C" void kernel_launch(void* const* d_in, const int* in_sizes, int n_in,
                              void* d_out, int out_size, void* d_ws, size_t ws_size,
                              hipStream_t stream) {
    const float* x   = (const float*)d_in[0];
    const float* sup = (const float*)d_in[1];
    const float* nv1 = (const float*)d_in[2];
    const float* nv2 = (const float*)d_in[3];
    const float* kw  = (const float*)d_in[4];
    const float* kb  = (const float*)d_in[5];
    const float* qw  = (const float*)d_in[6];
    const float* qb  = (const float*)d_in[7];
    const float* aw  = (const float*)d_in[8];
    const float* ab  = (const float*)d_in[9];
    const float* fw  = (const float*)d_in[10];
    const float* fb  = (const float*)d_in[11];
    float* hout = (float*)d_out;

    float* wsf = (float*)d_ws;
    size_t o = 0;
    f16*   XT     = (f16*)(wsf + o);  o += 3145728;   // [8][768][1024] f16 (becomes ZT)
    float* attReg = wsf + o;          o += 16777216;  // attT [4][8][1024][1024] f16
    f16*   attT   = (f16*)attReg;
    f16*   xT2    = (f16*)attReg;                     // overlay (dead before attT)
    f16*   aT     = (f16*)(wsf + o);  o += 1048576;   // [2][1024][1024] f16
    float* gate   = wsf + o;          o += 128;
    size_t rc = o;                                    // phase-union region
    // ---- phase A (through k_gate) ----
    size_t oA = rc;
    float* scTall = wsf + oA;          oA += 16777216; // [2][8][1024][1024] f32
    f16*   keysT  = (f16*)(wsf + oA);  oA += 2097152;
    f16*   kwb    = (f16*)(wsf + oA);  oA += 196608;
    float* kwl    = wsf + oA;          oA += 32768;
    float* tkq    = wsf + oA;          oA += 524288;
    float* xl     = wsf + oA;          oA += 524288;
    float* ra     = wsf + oA;          oA += 4096;
    float* ratt   = wsf + oA;          oA += 65536;
    float* feats  = wsf + oA;          oA += 6656;
    float* partial= wsf + oA;          oA += 1114112;
    // ---- phase B mega (preferred): P1all + P2all, 6 pairs ----
    size_t oBm = rc;
    f16*   P1all  = (f16*)(wsf + oBm); oBm += 18874368; // 6*[8][768][1024] f16
    f16*   P2all  = (f16*)(wsf + oBm); oBm += 18874368;
    // ---- phase B fallback ----
    size_t oBf = rc;
    f16*   P1f    = (f16*)(wsf + oBf); oBf += 3145728;
    f16*   haccf  = (f16*)(wsf + oBf); oBf += 3145728;
    size_t needMega = (oA > oBm ? oA : oBm) * 4;
    size_t needFall = (oA > oBf ? oA : oBf) * 4;
    bool mega = ws_size >= needMega;
    if (!mega && ws_size < needFall) return;

    f16* ZT = XT;   // after k_zt2, XT region holds ZT

    k_xt<<<2048, 256, 0, stream>>>(x, XT, xl);
    k_xt2<<<dim3(16, 4, 8), 256, 0, stream>>>(x, xT2);
    k_wcvt<<<128, 256, 0, stream>>>(kw, qw, kwl, kwb);
    k_tkq<<<2048, 256, 0, stream>>>(kwl, nv1, nv2, kb, qb, tkq);
    k_acvt<<<dim3(16, 16, 2), 256, 0, stream>>>(sup, aT);

    k_kqgemm<<<dim3(8, 1, 32), 256, 0, stream>>>(xT2, kwb, tkq, keysT);

    k_scoregemm2<<<dim3(8, 8, 16), 256, 0, stream>>>(keysT, scTall);
    k_softmax3<<<4096, 256, 0, stream>>>(scTall, aT, attT);

    k_colsum1<0><<<dim3(16, 34), 256, 0, stream>>>(aT, attT, ra, ratt, partial);
    k_colsum2<0><<<34, 256, 0, stream>>>(partial, ra, ratt);
    k_colsum1<1><<<dim3(16, 34), 256, 0, stream>>>(aT, attT, ra, ratt, partial);
    k_colsum2<1><<<34, 256, 0, stream>>>(partial, ra, ratt);
    k_feat13<<<512, 256, 0, stream>>>(xl, ra, ratt, feats);
    k_gate<<<8, 64, 0, stream>>>(feats, aw, ab, gate);

    // ---- phase B: project to o-domain, propagate, gated output ----
    k_zt2<<<dim3(8, 12, 8), 256, 0, stream>>>(XT, fw);

    if (mega) {
        k_prop1m<<<2304, 256, 0, stream>>>(ZT, aT, attT, P1all);
        k_prop2m<<<2304, 256, 0, stream>>>(P1all, aT, attT, P2all);
        k_out<<<2048, 256, 0, stream>>>(ZT, P1all, P2all, gate, fb, hout);
    } else {
        k_hinit2<<<3072, 256, 0, stream>>>(ZT, gate, haccf);
        for (int s = 0; s < 2; s++)
            for (int kind = 0; kind < 3; kind++) {
                const f16* B0;
                size_t bsB;
                if (kind == 0) { B0 = aT + (size_t)s * 1048576; bsB = 0; }
                else { B0 = attT + (size_t)((s * 2 + kind - 1) * 8) * 1048576; bsB = 1048576; }
                int g1 = 1 + s * 6 + 2 * kind;
                k_prop1g<<<dim3(8, 6, 8), 256, 0, stream>>>(ZT, B0, bsB, P1f);
                k_prop2g<<<dim3(8, 6, 8), 256, 0, stream>>>(P1f, B0, bsB, haccf, gate, g1);
            }
        k_biasout<<<2048, 256, 0, stream>>>(haccf, fb, hout);
    }
}